// Round 4
// baseline (951.031 us; speedup 1.0000x reference)
//
#include <hip/hip_runtime.h>

typedef _Float16 f16;
typedef _Float16 f16x8 __attribute__((ext_vector_type(8)));
typedef _Float16 f16x4 __attribute__((ext_vector_type(4)));
typedef _Float16 h2 __attribute__((ext_vector_type(2)));
typedef float f32x4 __attribute__((ext_vector_type(4)));
typedef unsigned short u16;
typedef unsigned int u32;

#define DEVI __device__ __forceinline__

DEVI u16 f2h(float f) { f16 h = (f16)f; return __builtin_bit_cast(u16, h); }
DEVI float h2f(u16 u) { f16 h = __builtin_bit_cast(f16, u); return (float)h; }

// ============================ weight prep ============================
// conv weights (OCT,64,5,5) -> frag-ordered fp16 split planes:
// dst[(((tap*2+icc)*2+pl)*NF + f)*512 + lane*8 + j]
__launch_bounds__(256)
__global__ void prep_wconv_k(const float* __restrict__ src, u16* __restrict__ dst, int nf_sh) {
    int i = blockIdx.x * 256 + threadIdx.x;
    int j = i & 7, lane = (i >> 3) & 63;
    int q = i >> 9;
    int f = q & ((1 << nf_sh) - 1); q >>= nf_sh;
    int pl = q & 1; q >>= 1;
    int icc = q & 1; int tap = q >> 1;
    int oc = (f << 4) + (lane & 15);
    int ic = icc * 32 + ((lane >> 4) << 3) + j;
    float w = src[(oc * 64 + ic) * 25 + tap];
    if (pl == 0) dst[i] = f2h(w);
    else         dst[i] = f2h((w - h2f(f2h(w))) * 4096.f);
}
// deconv weights (ICT,64,4,4) -> plain fp16 frag order
__launch_bounds__(256)
__global__ void prep_wdec_k(const float* __restrict__ src, u16* __restrict__ dst, int icc_sh) {
    int i = blockIdx.x * 256 + threadIdx.x;
    int j = i & 7, lane = (i >> 3) & 63;
    int f = (i >> 9) & 3;
    int q = i >> 11;
    int icc = q & ((1 << icc_sh) - 1); int tap = q >> icc_sh;
    int oc = (f << 4) + (lane & 15);
    int ic = icc * 32 + ((lane >> 4) << 3) + j;
    dst[i] = f2h(src[(ic * 64 + oc) * 16 + tap]);
}
// codebook (1024,256) -> split fp16 frag order
__launch_bounds__(256)
__global__ void prep_cb_k(const float* __restrict__ cb, u16* __restrict__ dst) {
    int i = blockIdx.x * 256 + threadIdx.x;   // 524288
    int j = i & 7, lane = (i >> 3) & 63;
    int f = (i >> 9) & 63;
    int q = i >> 15;
    int pl = q & 1; int ks = q >> 1;
    int n = (f << 4) + (lane & 15);
    int k = ks * 32 + ((lane >> 4) << 3) + j;
    float w = cb[n * 256 + k];
    if (pl == 0) dst[i] = f2h(w);
    else         dst[i] = f2h((w - h2f(f2h(w))) * 4096.f);
}
__launch_bounds__(256)
__global__ void prep_cbn_k(const float* __restrict__ cb, float* __restrict__ cbn) {
    int row = blockIdx.x * 256 + threadIdx.x;          // 1024
    float s = 0.f;
    for (int c = 0; c < 256; c += 4) {
        f32x4 v = *(const f32x4*)&cb[row * 256 + c];
        s = fmaf(v.x, v.x, s); s = fmaf(v.y, v.y, s);
        s = fmaf(v.z, v.z, s); s = fmaf(v.w, v.w, s);
    }
    cbn[row] = s;
}

// ============================ conv1: 1->64, 5x5 s2 p2, relu, split-fp16 out ============================
__launch_bounds__(256)
__global__ void conv1_k(const float* __restrict__ x, const float* __restrict__ w,
                        const float* __restrict__ b, u16* __restrict__ oh, u16* __restrict__ ol) {
    __shared__ float wl[25 * 64];
    __shared__ float bl[64];
    int t = threadIdx.x;
    for (int i = t; i < 1600; i += 256) wl[(i % 25) * 64 + i / 25] = w[i];
    if (t < 64) bl[t] = b[t];
    __syncthreads();
    int p = blockIdx.x * 256 + t;                       // 262144 pixels
    int ox = p & 63, oy = (p >> 6) & 63, n = p >> 12;
    f32x4 acc[16];
    #pragma unroll
    for (int c = 0; c < 16; ++c) acc[c] = *(f32x4*)&bl[c * 4];
    for (int dy = 0; dy < 5; ++dy) {
        int iy = 2 * oy - 2 + dy;
        if ((unsigned)iy >= 128u) continue;
        for (int dx = 0; dx < 5; ++dx) {
            int ix = 2 * ox - 2 + dx;
            if ((unsigned)ix >= 128u) continue;
            float v = x[(n * 128 + iy) * 128 + ix];
            const float* wp = &wl[(dy * 5 + dx) * 64];
            #pragma unroll
            for (int c = 0; c < 16; ++c) {
                f32x4 w4 = *(const f32x4*)&wp[c * 4];
                acc[c].x = fmaf(v, w4.x, acc[c].x); acc[c].y = fmaf(v, w4.y, acc[c].y);
                acc[c].z = fmaf(v, w4.z, acc[c].z); acc[c].w = fmaf(v, w4.w, acc[c].w);
            }
        }
    }
    #pragma unroll
    for (int c = 0; c < 16; ++c) {
        ushort4 uh, ul;
        float vv[4] = {acc[c].x, acc[c].y, acc[c].z, acc[c].w};
        u16 rh[4], rl[4];
        #pragma unroll
        for (int k = 0; k < 4; ++k) {
            float v = fmaxf(vv[k], 0.f);
            f16 hh = (f16)v;
            rh[k] = __builtin_bit_cast(u16, hh);
            rl[k] = f2h((v - (float)hh) * 4096.f);
        }
        uh.x = rh[0]; uh.y = rh[1]; uh.z = rh[2]; uh.w = rh[3];
        ul.x = rl[0]; ul.y = rl[1]; ul.z = rl[2]; ul.w = rl[3];
        *(ushort4*)&oh[p * 64 + c * 4] = uh;
        *(ushort4*)&ol[p * 64 + c * 4] = ul;
    }
}

// ============================ split-fp16 MFMA 5x5 conv ============================
// LDS layout: pixel pair P=pp>>1 owns a 64-half line; chunk c of pixel parity r
// sits at slot s=(P+2c+r)&7 -> bank group s*4 (P-independent) -> balanced reads
// for both S=1 (2-way, free) and S=2 (same-parity taps), balanced writes.
template<int S, int OCT, int NI, bool RELU>
__launch_bounds__(256)
__global__ void conv5_k(const u16* __restrict__ Ah_g, const u16* __restrict__ Al_g,
                        const u16* __restrict__ wBf, const float* __restrict__ bias,
                        u16* __restrict__ Oh, u16* __restrict__ Ol,
                        int IH, int IW, int OH, int OW) {
    constexpr int PATCH = 7 * S + 5;
    constexpr int NPIX = PATCH * PATCH;
    constexpr int NPAIR = (NPIX + 1) / 2;
    constexpr int PLSZ = NPAIR * 64;
    constexpr int NF = OCT / 16;
    constexpr int BN = NI * 32;
    constexpr int OCB = OCT / BN;
    __shared__ u16 patch[2 * PLSZ];

    int t = threadIdx.x, l = t & 63, wv = t >> 6;
    int wm = wv >> 1, wn = wv & 1, g = l >> 4;

    int bi = blockIdx.x;
    int ocb = bi % OCB; int rest = bi / OCB;
    int tw = OW >> 3, th = OH >> 3;
    int txi = rest % tw; rest /= tw;
    int tyi = rest % th; int n = rest / th;
    int iy0 = S * (tyi << 3) - 2, ix0 = S * (txi << 3) - 2;

    // per-mi base input-pixel index (tap dy=dx=0)
    int ppb[2];
    #pragma unroll
    for (int mi = 0; mi < 2; ++mi) {
        int m = wm * 32 + mi * 16 + (l & 15);
        int py = m >> 3, px = m & 7;
        ppb[mi] = (S * py) * PATCH + S * px;
    }

    f32x4 ahh[2][NI], ahl[2][NI], alh[2][NI];
    f32x4 z4 = {0.f, 0.f, 0.f, 0.f};
    #pragma unroll
    for (int mi = 0; mi < 2; ++mi)
        #pragma unroll
        for (int ni = 0; ni < NI; ++ni) { ahh[mi][ni] = z4; ahl[mi][ni] = z4; alh[mi][ni] = z4; }

    for (int icc = 0; icc < 2; ++icc) {
        __syncthreads();
        for (int i = t; i < NPIX * 8; i += 256) {
            int c = i & 3; int r2 = i >> 2;
            int pl = (r2 >= NPIX); int pp = r2 - pl * NPIX;
            int py = pp / PATCH, px = pp - py * PATCH;
            int iy = iy0 + py, ix = ix0 + px;
            uint4 v = make_uint4(0u, 0u, 0u, 0u);
            if ((unsigned)iy < (unsigned)IH && (unsigned)ix < (unsigned)IW)
                v = *(const uint4*)&(pl ? Al_g : Ah_g)[(((n * IH + iy) * IW + ix)) * 64 + icc * 32 + c * 8];
            int P = pp >> 1, r = pp & 1;
            *(uint4*)&patch[pl * PLSZ + (P << 6) + (((P + (c << 1) + r) & 7) << 3)] = v;
        }
        __syncthreads();
        for (int tap = 0; tap < 25; ++tap) {
            int dy = tap / 5, dx = tap - 5 * dy;
            int tadd = dy * PATCH + dx;
            f16x8 Bh[NI], Bl[NI];
            #pragma unroll
            for (int ni = 0; ni < NI; ++ni) {
                int fg = ocb * (BN / 16) + wn * NI + ni;
                Bh[ni] = *(const f16x8*)&wBf[(size_t)(((tap * 2 + icc) * 2 + 0) * NF + fg) * 512 + l * 8];
                Bl[ni] = *(const f16x8*)&wBf[(size_t)(((tap * 2 + icc) * 2 + 1) * NF + fg) * 512 + l * 8];
            }
            #pragma unroll
            for (int mi = 0; mi < 2; ++mi) {
                int pp = ppb[mi] + tadd;
                int P = pp >> 1, r = pp & 1;
                int offs = (P << 6) + (((P + (g << 1) + r) & 7) << 3);
                f16x8 ah = *(const f16x8*)&patch[offs];
                f16x8 al = *(const f16x8*)&patch[PLSZ + offs];
                #pragma unroll
                for (int ni = 0; ni < NI; ++ni) {
                    ahh[mi][ni] = __builtin_amdgcn_mfma_f32_16x16x32_f16(ah, Bh[ni], ahh[mi][ni], 0, 0, 0);
                    ahl[mi][ni] = __builtin_amdgcn_mfma_f32_16x16x32_f16(ah, Bl[ni], ahl[mi][ni], 0, 0, 0);
                    alh[mi][ni] = __builtin_amdgcn_mfma_f32_16x16x32_f16(al, Bh[ni], alh[mi][ni], 0, 0, 0);
                }
            }
        }
    }
    #pragma unroll
    for (int mi = 0; mi < 2; ++mi)
        #pragma unroll
        for (int ni = 0; ni < NI; ++ni) {
            int oc = ocb * BN + wn * (NI * 16) + ni * 16 + (l & 15);
            float bv = bias[oc];
            #pragma unroll
            for (int reg = 0; reg < 4; ++reg) {
                float v = ahh[mi][ni][reg] + (ahl[mi][ni][reg] + alh[mi][ni][reg]) * (1.f / 4096.f) + bv;
                if (RELU) v = fmaxf(v, 0.f);
                int pix = wm * 32 + mi * 16 + g * 4 + reg;
                int oy = (tyi << 3) + (pix >> 3), ox = (txi << 3) + (pix & 7);
                int idx = ((n * OH + oy) * OW + ox) * OCT + oc;
                f16 hh = (f16)v;
                Oh[idx] = __builtin_bit_cast(u16, hh);
                Ol[idx] = f2h((v - (float)hh) * 4096.f);
            }
        }
}

// ============================ quantize: split-fp16 MFMA dists + exact top-1 ============================
__launch_bounds__(256)
__global__ void quant_k(const u16* __restrict__ zh, const u16* __restrict__ zl,
                        const u16* __restrict__ cbf, const float* __restrict__ cbn,
                        const float* __restrict__ cb, u16* __restrict__ e,
                        float* __restrict__ diff) {
    constexpr int PZ = 264;
    __shared__ u16 zs[2 * 32 * PZ];
    __shared__ float znp[256];
    __shared__ float zn[32];
    __shared__ float rbd[4][32];
    __shared__ int   rbc[4][32];
    __shared__ int   widx[32];

    int t = threadIdx.x, l = t & 63, wv = t >> 6, g = l >> 4;
    int row0 = blockIdx.x * 32;

    for (int i = t; i < 2048; i += 256) {
        int c = i & 31, r = (i >> 5) & 31, pl = i >> 10;
        uint4 v = *(const uint4*)&(pl ? zl : zh)[(row0 + r) * 256 + c * 8];
        *(uint4*)&zs[pl * 32 * PZ + r * PZ + c * 8] = v;
    }
    __syncthreads();
    {
        int r = t >> 3, part = t & 7;
        float s = 0.f;
        for (int k = part * 32; k < part * 32 + 32; ++k) {
            float v = h2f(zs[r * PZ + k]) + h2f(zs[32 * PZ + r * PZ + k]) * (1.f / 4096.f);
            s = fmaf(v, v, s);
        }
        znp[t] = s;
    }
    __syncthreads();
    if (t < 32) {
        float s = 0.f;
        for (int q = 0; q < 8; ++q) s += znp[t * 8 + q];
        zn[t] = s;
    }

    float rd[8]; int rc[8];
    #pragma unroll
    for (int s = 0; s < 8; ++s) { rd[s] = 1e30f; rc[s] = 0; }

    for (int no = 0; no < 8; ++no) {
        int n0 = wv * 256 + no * 32;
        f32x4 ahh[2][2], ahl[2][2], alh[2][2];
        f32x4 z4 = {0.f, 0.f, 0.f, 0.f};
        #pragma unroll
        for (int mi = 0; mi < 2; ++mi)
            #pragma unroll
            for (int nf = 0; nf < 2; ++nf) { ahh[mi][nf] = z4; ahl[mi][nf] = z4; alh[mi][nf] = z4; }
        for (int ks = 0; ks < 8; ++ks) {
            f16x8 Bh[2], Bl[2];
            #pragma unroll
            for (int nf = 0; nf < 2; ++nf) {
                int fg = (n0 >> 4) + nf;
                Bh[nf] = *(const f16x8*)&cbf[(size_t)((ks * 2 + 0) * 64 + fg) * 512 + l * 8];
                Bl[nf] = *(const f16x8*)&cbf[(size_t)((ks * 2 + 1) * 64 + fg) * 512 + l * 8];
            }
            #pragma unroll
            for (int mi = 0; mi < 2; ++mi) {
                f16x8 ah = *(const f16x8*)&zs[(mi * 16 + (l & 15)) * PZ + ks * 32 + g * 8];
                f16x8 al = *(const f16x8*)&zs[32 * PZ + (mi * 16 + (l & 15)) * PZ + ks * 32 + g * 8];
                #pragma unroll
                for (int nf = 0; nf < 2; ++nf) {
                    ahh[mi][nf] = __builtin_amdgcn_mfma_f32_16x16x32_f16(ah, Bh[nf], ahh[mi][nf], 0, 0, 0);
                    ahl[mi][nf] = __builtin_amdgcn_mfma_f32_16x16x32_f16(ah, Bl[nf], ahl[mi][nf], 0, 0, 0);
                    alh[mi][nf] = __builtin_amdgcn_mfma_f32_16x16x32_f16(al, Bh[nf], alh[mi][nf], 0, 0, 0);
                }
            }
        }
        #pragma unroll
        for (int mi = 0; mi < 2; ++mi)
            #pragma unroll
            for (int nf = 0; nf < 2; ++nf) {
                int col = n0 + nf * 16 + (l & 15);
                float cn = cbn[col];
                #pragma unroll
                for (int reg = 0; reg < 4; ++reg) {
                    float d = cn - 2.f * (ahh[mi][nf][reg] +
                              (ahl[mi][nf][reg] + alh[mi][nf][reg]) * (1.f / 4096.f));
                    int slot = mi * 4 + reg;
                    if (d < rd[slot]) { rd[slot] = d; rc[slot] = col; }
                }
            }
    }
    #pragma unroll
    for (int step = 1; step < 16; step <<= 1) {
        #pragma unroll
        for (int s = 0; s < 8; ++s) {
            float od = __shfl_xor(rd[s], step);
            int ocl = __shfl_xor(rc[s], step);
            if (od < rd[s] || (od == rd[s] && ocl < rc[s])) { rd[s] = od; rc[s] = ocl; }
        }
    }
    if ((l & 15) == 0) {
        #pragma unroll
        for (int s = 0; s < 8; ++s) {
            int mi = s >> 2, reg = s & 3;
            int row = mi * 16 + g * 4 + reg;
            rbd[wv][row] = rd[s]; rbc[wv][row] = rc[s];
        }
    }
    __syncthreads();
    if (t < 64) {
        float dval = 0.f;
        if (t < 32) {
            float bd = rbd[0][t]; int bc = rbc[0][t];
            #pragma unroll
            for (int w2 = 1; w2 < 4; ++w2) {
                float od = rbd[w2][t]; int ocl = rbc[w2][t];
                if (od < bd || (od == bd && ocl < bc)) { bd = od; bc = ocl; }
            }
            widx[t] = bc;
            dval = bd + zn[t];
        }
        #pragma unroll
        for (int step = 1; step < 32; step <<= 1) dval += __shfl_xor(dval, step);
        if (t == 0) atomicAdd(diff, dval * (1.f / 16777216.f));
    }
    __syncthreads();
    for (int r = 0; r < 32; ++r) {
        int wi = widx[r];
        e[(row0 + r) * 256 + t] = f2h(cb[wi * 256 + t]);
    }
}

// ============================ plain-fp16 MFMA deconv k4 s2 p1 (per-parity) ============================
template<int ICT>
__launch_bounds__(256)
__global__ void deconv4_k(const u16* __restrict__ in, const u16* __restrict__ wdf,
                          const float* __restrict__ bias, u16* __restrict__ out,
                          int IH, int IW) {
    constexpr int RST = 40;
    constexpr int ICC = ICT / 32;
    constexpr int PLSZ = 81 * RST;
    __shared__ u16 patch[PLSZ];

    int t = threadIdx.x, l = t & 63, wv = t >> 6;
    int wm = wv >> 1, wn = wv & 1, g = l >> 4;

    int bi = blockIdx.x;
    int par = bi & 3; int ry = par >> 1, rx = par & 1;
    int rest = bi >> 2;
    int tw = IW >> 3, th = IH >> 3;
    int txi = rest % tw; rest /= tw;
    int tyi = rest % th; int n = rest / th;
    int a0 = tyi << 3, b0 = txi << 3;
    int by0 = ry ? 0 : -1, bx0 = rx ? 0 : -1;
    int OH = IH << 1, OW = IW << 1;

    int pb0[2];
    #pragma unroll
    for (int mi = 0; mi < 2; ++mi) {
        int m = wm * 32 + mi * 16 + (l & 15);
        int pa = m >> 3, pb_ = m & 7;
        pb0[mi] = (pa * 9 + pb_) * RST + g * 8;
    }

    f32x4 acc[2][2];
    f32x4 z4 = {0.f, 0.f, 0.f, 0.f};
    #pragma unroll
    for (int mi = 0; mi < 2; ++mi)
        #pragma unroll
        for (int ni = 0; ni < 2; ++ni) acc[mi][ni] = z4;

    for (int icc = 0; icc < ICC; ++icc) {
        __syncthreads();
        for (int i = t; i < 324; i += 256) {
            int c = i & 3; int pp = i >> 2;
            int pr = pp / 9, pc = pp - pr * 9;
            int ar = a0 + by0 + pr, ac = b0 + bx0 + pc;
            uint4 v = make_uint4(0u, 0u, 0u, 0u);
            if ((unsigned)ar < (unsigned)IH && (unsigned)ac < (unsigned)IW)
                v = *(const uint4*)&in[((n * IH + ar) * IW + ac) * ICT + icc * 32 + c * 8];
            *(uint4*)&patch[(pr * 9 + pc) * RST + c * 8] = v;
        }
        __syncthreads();
        #pragma unroll
        for (int tt = 0; tt < 4; ++tt) {
            int tty = tt >> 1, ttx = tt & 1;
            int ky = 1 - ry + 2 * tty, kx = 1 - rx + 2 * ttx;
            int tap = ky * 4 + kx;
            int shift = ((1 - tty) * 9 + (1 - ttx)) * RST;
            f16x8 B[2];
            #pragma unroll
            for (int ni = 0; ni < 2; ++ni)
                B[ni] = *(const f16x8*)&wdf[(size_t)((tap * ICC + icc) * 4 + wn * 2 + ni) * 512 + l * 8];
            #pragma unroll
            for (int mi = 0; mi < 2; ++mi) {
                f16x8 a = *(const f16x8*)&patch[pb0[mi] + shift];
                #pragma unroll
                for (int ni = 0; ni < 2; ++ni)
                    acc[mi][ni] = __builtin_amdgcn_mfma_f32_16x16x32_f16(a, B[ni], acc[mi][ni], 0, 0, 0);
            }
        }
    }
    #pragma unroll
    for (int mi = 0; mi < 2; ++mi)
        #pragma unroll
        for (int ni = 0; ni < 2; ++ni) {
            int oc = wn * 32 + ni * 16 + (l & 15);
            float bv = bias[oc];
            #pragma unroll
            for (int reg = 0; reg < 4; ++reg) {
                float v = fmaxf(acc[mi][ni][reg] + bv, 0.f);
                int pix = wm * 32 + mi * 16 + g * 4 + reg;
                int oy = ((a0 + (pix >> 3)) << 1) + ry;
                int ox = ((b0 + (pix & 7)) << 1) + rx;
                out[((n * OH + oy) * OW + ox) * 64 + oc] = f2h(v);
            }
        }
}

// ============================ final conv 3x3 64->1, p1, tanh (LDS-tiled, v_dot2) ============================
__launch_bounds__(256)
__global__ void conv3x3_tanh_k(const u16* __restrict__ in, const float* __restrict__ w,
                               const float* __restrict__ b, float* __restrict__ out) {
    __shared__ u16 tile[18 * 18 * 72];
    __shared__ u32 wpk[288];   // [tap][icp] half2-packed weights
    int t = threadIdx.x;
    int bi = blockIdx.x;
    int n = bi >> 6;
    int tile6 = bi & 63;
    int ty0 = (tile6 >> 3) << 4, tx0 = (tile6 & 7) << 4;

    for (int i = t; i < 288; i += 256) {     // FIX: 288 entries, 256 threads -> loop
        int tap = i >> 5, icp = i & 31;
        h2 p;
        p.x = (f16)w[(2 * icp) * 9 + tap];
        p.y = (f16)w[(2 * icp + 1) * 9 + tap];
        wpk[tap * 32 + icp] = __builtin_bit_cast(u32, p);
    }
    for (int i = t; i < 2592; i += 256) {
        int ch = i & 7, pix = i >> 3;
        int pr = pix / 18, pc = pix - pr * 18;
        int gy = ty0 - 1 + pr, gx = tx0 - 1 + pc;
        uint4 v = make_uint4(0u, 0u, 0u, 0u);
        if ((unsigned)gy < 128u && (unsigned)gx < 128u)
            v = *(const uint4*)&in[(((n << 7) + gy) * 128 + gx) * 64 + ch * 8];
        *(uint4*)&tile[pix * 72 + ch * 8] = v;
    }
    __syncthreads();

    int ty = t >> 4, tx = t & 15;
    float acc = b[0];
    #pragma unroll
    for (int dy = 0; dy < 3; ++dy) {
        #pragma unroll
        for (int dx = 0; dx < 3; ++dx) {
            int base = ((ty + dy) * 18 + (tx + dx)) * 72;
            const u32* wp = &wpk[(dy * 3 + dx) * 32];
            #pragma unroll
            for (int c8 = 0; c8 < 8; ++c8) {
                uint4 v = *(const uint4*)&tile[base + c8 * 8];
                acc = __builtin_amdgcn_fdot2(__builtin_bit_cast(h2, v.x),
                        __builtin_bit_cast(h2, wp[c8 * 4 + 0]), acc, false);
                acc = __builtin_amdgcn_fdot2(__builtin_bit_cast(h2, v.y),
                        __builtin_bit_cast(h2, wp[c8 * 4 + 1]), acc, false);
                acc = __builtin_amdgcn_fdot2(__builtin_bit_cast(h2, v.z),
                        __builtin_bit_cast(h2, wp[c8 * 4 + 2]), acc, false);
                acc = __builtin_amdgcn_fdot2(__builtin_bit_cast(h2, v.w),
                        __builtin_bit_cast(h2, wp[c8 * 4 + 3]), acc, false);
            }
        }
    }
    int oy = ty0 + ty, ox = tx0 + tx;
    out[(n << 14) + (oy << 7) + ox] = tanhf(acc);
}

extern "C" void kernel_launch(void* const* d_in, const int* in_sizes, int n_in,
                              void* d_out, int out_size, void* d_ws, size_t ws_size,
                              hipStream_t stream) {
    (void)in_sizes; (void)n_in; (void)out_size; (void)ws_size;
    const float* x   = (const float*)d_in[0];
    const float* ew1 = (const float*)d_in[1];
    const float* eb1 = (const float*)d_in[2];
    const float* ew2 = (const float*)d_in[3];
    const float* eb2 = (const float*)d_in[4];
    const float* ew3 = (const float*)d_in[5];
    const float* eb3 = (const float*)d_in[6];
    const float* cb  = (const float*)d_in[7];
    const float* dw1 = (const float*)d_in[8];
    const float* db1 = (const float*)d_in[9];
    const float* dw2 = (const float*)d_in[10];
    const float* db2 = (const float*)d_in[11];
    const float* dw3 = (const float*)d_in[12];
    const float* db3 = (const float*)d_in[13];
    float* out = (float*)d_out;

    u16* ws = (u16*)d_ws;
    u16* a1h = ws;             u16* a1l = ws + 16777216;
    u16* zh  = ws;             u16* zl  = ws + 16777216;
    u16* a2h = ws + 33554432;  u16* a2l = ws + 50331648;
    u16* e   = ws + 33554432;
    u16* y1  = ws + 67108864;
    u16* y2  = ws;
    u16* wBf2 = ws + 83886080;          // 204800
    u16* wBf3 = wBf2 + 204800;          // 819200
    u16* wd1f = wBf3 + 819200;          // 262144
    u16* wd2f = wd1f + 262144;          // 65536
    u16* cbf  = wd2f + 65536;           // 524288
    float* cbn = (float*)(cbf + 524288);

    hipMemsetAsync(out + 1048576, 0, 4, stream);  // diff accumulator

    prep_wconv_k<<<800, 256, 0, stream>>>(ew2, wBf2, 2);   // NF=4
    prep_wconv_k<<<3200, 256, 0, stream>>>(ew3, wBf3, 4);  // NF=16
    prep_wdec_k<<<1024, 256, 0, stream>>>(dw1, wd1f, 3);   // ICC=8
    prep_wdec_k<<<256, 256, 0, stream>>>(dw2, wd2f, 1);    // ICC=2
    prep_cb_k<<<2048, 256, 0, stream>>>(cb, cbf);
    prep_cbn_k<<<4, 256, 0, stream>>>(cb, cbn);

    conv1_k<<<1024, 256, 0, stream>>>(x, ew1, eb1, a1h, a1l);
    conv5_k<1, 64, 2, true><<<4096, 256, 0, stream>>>(a1h, a1l, wBf2, eb2, a2h, a2l, 64, 64, 64, 64);
    conv5_k<2, 256, 4, false><<<2048, 256, 0, stream>>>(a2h, a2l, wBf3, eb3, zh, zl, 64, 64, 32, 32);
    quant_k<<<2048, 256, 0, stream>>>(zh, zl, cbf, cbn, cb, e, out + 1048576);
    deconv4_k<256><<<4096, 256, 0, stream>>>(e, wd1f, db1, y1, 32, 32);
    deconv4_k<64><<<16384, 256, 0, stream>>>(y1, wd2f, db2, y2, 64, 64);
    conv3x3_tanh_k<<<4096, 256, 0, stream>>>(y2, dw3, db3, out);
}

// Round 5
// 857.839 us; speedup vs baseline: 1.1086x; 1.1086x over previous
//
#include <hip/hip_runtime.h>

typedef _Float16 f16;
typedef _Float16 f16x8 __attribute__((ext_vector_type(8)));
typedef _Float16 f16x4 __attribute__((ext_vector_type(4)));
typedef _Float16 h2 __attribute__((ext_vector_type(2)));
typedef float f32x4 __attribute__((ext_vector_type(4)));
typedef unsigned short u16;
typedef unsigned int u32;

#define DEVI __device__ __forceinline__

DEVI u16 f2h(float f) { f16 h = (f16)f; return __builtin_bit_cast(u16, h); }
DEVI float h2f(u16 u) { f16 h = __builtin_bit_cast(f16, u); return (float)h; }

// ============================ weight prep ============================
// conv weights (OCT,64,5,5) -> frag-ordered fp16 split planes:
// dst[(((tap*2+icc)*2+pl)*NF + f)*512 + lane*8 + j]
__launch_bounds__(256)
__global__ void prep_wconv_k(const float* __restrict__ src, u16* __restrict__ dst, int nf_sh) {
    int i = blockIdx.x * 256 + threadIdx.x;
    int j = i & 7, lane = (i >> 3) & 63;
    int q = i >> 9;
    int f = q & ((1 << nf_sh) - 1); q >>= nf_sh;
    int pl = q & 1; q >>= 1;
    int icc = q & 1; int tap = q >> 1;
    int oc = (f << 4) + (lane & 15);
    int ic = icc * 32 + ((lane >> 4) << 3) + j;
    float w = src[(oc * 64 + ic) * 25 + tap];
    if (pl == 0) dst[i] = f2h(w);
    else         dst[i] = f2h((w - h2f(f2h(w))) * 4096.f);
}
// deconv weights (ICT,64,4,4) -> plain fp16 frag order
__launch_bounds__(256)
__global__ void prep_wdec_k(const float* __restrict__ src, u16* __restrict__ dst, int icc_sh) {
    int i = blockIdx.x * 256 + threadIdx.x;
    int j = i & 7, lane = (i >> 3) & 63;
    int f = (i >> 9) & 3;
    int q = i >> 11;
    int icc = q & ((1 << icc_sh) - 1); int tap = q >> icc_sh;
    int oc = (f << 4) + (lane & 15);
    int ic = icc * 32 + ((lane >> 4) << 3) + j;
    dst[i] = f2h(src[(ic * 64 + oc) * 16 + tap]);
}
// codebook (1024,256) -> split fp16 frag order
__launch_bounds__(256)
__global__ void prep_cb_k(const float* __restrict__ cb, u16* __restrict__ dst) {
    int i = blockIdx.x * 256 + threadIdx.x;   // 524288
    int j = i & 7, lane = (i >> 3) & 63;
    int f = (i >> 9) & 63;
    int q = i >> 15;
    int pl = q & 1; int ks = q >> 1;
    int n = (f << 4) + (lane & 15);
    int k = ks * 32 + ((lane >> 4) << 3) + j;
    float w = cb[n * 256 + k];
    if (pl == 0) dst[i] = f2h(w);
    else         dst[i] = f2h((w - h2f(f2h(w))) * 4096.f);
}
__launch_bounds__(256)
__global__ void prep_cbn_k(const float* __restrict__ cb, float* __restrict__ cbn) {
    int row = blockIdx.x * 256 + threadIdx.x;          // 1024
    float s = 0.f;
    for (int c = 0; c < 256; c += 4) {
        f32x4 v = *(const f32x4*)&cb[row * 256 + c];
        s = fmaf(v.x, v.x, s); s = fmaf(v.y, v.y, s);
        s = fmaf(v.z, v.z, s); s = fmaf(v.w, v.w, s);
    }
    cbn[row] = s;
}

// ============================ conv1: 1->64, 5x5 s2 p2, relu, split-fp16 out ============================
__launch_bounds__(256)
__global__ void conv1_k(const float* __restrict__ x, const float* __restrict__ w,
                        const float* __restrict__ b, u16* __restrict__ oh, u16* __restrict__ ol) {
    __shared__ float wl[25 * 64];
    __shared__ float bl[64];
    int t = threadIdx.x;
    for (int i = t; i < 1600; i += 256) wl[(i % 25) * 64 + i / 25] = w[i];
    if (t < 64) bl[t] = b[t];
    __syncthreads();
    int p = blockIdx.x * 256 + t;                       // 262144 pixels
    int ox = p & 63, oy = (p >> 6) & 63, n = p >> 12;
    f32x4 acc[16];
    #pragma unroll
    for (int c = 0; c < 16; ++c) acc[c] = *(f32x4*)&bl[c * 4];
    for (int dy = 0; dy < 5; ++dy) {
        int iy = 2 * oy - 2 + dy;
        if ((unsigned)iy >= 128u) continue;
        for (int dx = 0; dx < 5; ++dx) {
            int ix = 2 * ox - 2 + dx;
            if ((unsigned)ix >= 128u) continue;
            float v = x[(n * 128 + iy) * 128 + ix];
            const float* wp = &wl[(dy * 5 + dx) * 64];
            #pragma unroll
            for (int c = 0; c < 16; ++c) {
                f32x4 w4 = *(const f32x4*)&wp[c * 4];
                acc[c].x = fmaf(v, w4.x, acc[c].x); acc[c].y = fmaf(v, w4.y, acc[c].y);
                acc[c].z = fmaf(v, w4.z, acc[c].z); acc[c].w = fmaf(v, w4.w, acc[c].w);
            }
        }
    }
    #pragma unroll
    for (int c = 0; c < 16; ++c) {
        ushort4 uh, ul;
        float vv[4] = {acc[c].x, acc[c].y, acc[c].z, acc[c].w};
        u16 rh[4], rl[4];
        #pragma unroll
        for (int k = 0; k < 4; ++k) {
            float v = fmaxf(vv[k], 0.f);
            f16 hh = (f16)v;
            rh[k] = __builtin_bit_cast(u16, hh);
            rl[k] = f2h((v - (float)hh) * 4096.f);
        }
        uh.x = rh[0]; uh.y = rh[1]; uh.z = rh[2]; uh.w = rh[3];
        ul.x = rl[0]; ul.y = rl[1]; ul.z = rl[2]; ul.w = rl[3];
        *(ushort4*)&oh[p * 64 + c * 4] = uh;
        *(ushort4*)&ol[p * 64 + c * 4] = ul;
    }
}

// ============================ split-fp16 MFMA 5x5 conv ============================
// LDS: pixel pair P=pp>>1 owns a 64-half line; chunk c of parity r at slot (P+2c+r)&7.
// Per-block tap/icc rotation decorrelates the (block-identical) weight-fragment
// address stream across CUs -> spreads load over all L2 slices.
template<int S, int OCT, int NI, bool RELU>
__launch_bounds__(256)
__global__ void conv5_k(const u16* __restrict__ Ah_g, const u16* __restrict__ Al_g,
                        const u16* __restrict__ wBf, const float* __restrict__ bias,
                        u16* __restrict__ Oh, u16* __restrict__ Ol,
                        int IH, int IW, int OH, int OW) {
    constexpr int PATCH = 7 * S + 5;
    constexpr int NPIX = PATCH * PATCH;
    constexpr int NPAIR = (NPIX + 1) / 2;
    constexpr int PLSZ = NPAIR * 64;
    constexpr int NF = OCT / 16;
    constexpr int BN = NI * 32;
    constexpr int OCB = OCT / BN;
    __shared__ u16 patch[2 * PLSZ];

    int t = threadIdx.x, l = t & 63, wv = t >> 6;
    int wm = wv >> 1, wn = wv & 1, g = l >> 4;

    int bi = blockIdx.x;
    int ocb = bi % OCB; int rest = bi / OCB;
    int tw = OW >> 3, th = OH >> 3;
    int txi = rest % tw; rest /= tw;
    int tyi = rest % th; int n = rest / th;
    int iy0 = S * (tyi << 3) - 2, ix0 = S * (txi << 3) - 2;

    // per-mi base input-pixel index (tap dy=dx=0)
    int ppb[2];
    #pragma unroll
    for (int mi = 0; mi < 2; ++mi) {
        int m = wm * 32 + mi * 16 + (l & 15);
        int py = m >> 3, px = m & 7;
        ppb[mi] = (S * py) * PATCH + S * px;
    }

    f32x4 ahh[2][NI], ahl[2][NI], alh[2][NI];
    f32x4 z4 = {0.f, 0.f, 0.f, 0.f};
    #pragma unroll
    for (int mi = 0; mi < 2; ++mi)
        #pragma unroll
        for (int ni = 0; ni < NI; ++ni) { ahh[mi][ni] = z4; ahl[mi][ni] = z4; alh[mi][ni] = z4; }

    int tap0 = bi % 25;
    int iccr = bi & 1;
    for (int icci = 0; icci < 2; ++icci) {
        int icc = icci ^ iccr;                 // rotated icc order
        __syncthreads();
        for (int i = t; i < NPIX * 8; i += 256) {
            int c = i & 3; int r2 = i >> 2;
            int pl = (r2 >= NPIX); int pp = r2 - pl * NPIX;
            int py = pp / PATCH, px = pp - py * PATCH;
            int iy = iy0 + py, ix = ix0 + px;
            uint4 v = make_uint4(0u, 0u, 0u, 0u);
            if ((unsigned)iy < (unsigned)IH && (unsigned)ix < (unsigned)IW)
                v = *(const uint4*)&(pl ? Al_g : Ah_g)[(((n * IH + iy) * IW + ix)) * 64 + icc * 32 + c * 8];
            int P = pp >> 1, r = pp & 1;
            *(uint4*)&patch[pl * PLSZ + (P << 6) + (((P + (c << 1) + r) & 7) << 3)] = v;
        }
        __syncthreads();
        for (int tapi = 0; tapi < 25; ++tapi) {
            int tap = tap0 + tapi; if (tap >= 25) tap -= 25;   // rotated tap order
            int dy = tap / 5, dx = tap - 5 * dy;
            int tadd = dy * PATCH + dx;
            f16x8 Bh[NI], Bl[NI];
            #pragma unroll
            for (int ni = 0; ni < NI; ++ni) {
                int fg = ocb * (BN / 16) + wn * NI + ni;
                Bh[ni] = *(const f16x8*)&wBf[(size_t)(((tap * 2 + icc) * 2 + 0) * NF + fg) * 512 + l * 8];
                Bl[ni] = *(const f16x8*)&wBf[(size_t)(((tap * 2 + icc) * 2 + 1) * NF + fg) * 512 + l * 8];
            }
            #pragma unroll
            for (int mi = 0; mi < 2; ++mi) {
                int pp = ppb[mi] + tadd;
                int P = pp >> 1, r = pp & 1;
                int offs = (P << 6) + (((P + (g << 1) + r) & 7) << 3);
                f16x8 ah = *(const f16x8*)&patch[offs];
                f16x8 al = *(const f16x8*)&patch[PLSZ + offs];
                #pragma unroll
                for (int ni = 0; ni < NI; ++ni) {
                    ahh[mi][ni] = __builtin_amdgcn_mfma_f32_16x16x32_f16(ah, Bh[ni], ahh[mi][ni], 0, 0, 0);
                    ahl[mi][ni] = __builtin_amdgcn_mfma_f32_16x16x32_f16(ah, Bl[ni], ahl[mi][ni], 0, 0, 0);
                    alh[mi][ni] = __builtin_amdgcn_mfma_f32_16x16x32_f16(al, Bh[ni], alh[mi][ni], 0, 0, 0);
                }
            }
        }
    }
    #pragma unroll
    for (int mi = 0; mi < 2; ++mi)
        #pragma unroll
        for (int ni = 0; ni < NI; ++ni) {
            int oc = ocb * BN + wn * (NI * 16) + ni * 16 + (l & 15);
            float bv = bias[oc];
            #pragma unroll
            for (int reg = 0; reg < 4; ++reg) {
                float v = ahh[mi][ni][reg] + (ahl[mi][ni][reg] + alh[mi][ni][reg]) * (1.f / 4096.f) + bv;
                if (RELU) v = fmaxf(v, 0.f);
                int pix = wm * 32 + mi * 16 + g * 4 + reg;
                int oy = (tyi << 3) + (pix >> 3), ox = (txi << 3) + (pix & 7);
                int idx = ((n * OH + oy) * OW + ox) * OCT + oc;
                f16 hh = (f16)v;
                Oh[idx] = __builtin_bit_cast(u16, hh);
                Ol[idx] = f2h((v - (float)hh) * 4096.f);
            }
        }
}

// ============================ quantize: split-fp16 MFMA dists + exact top-1 ============================
__launch_bounds__(256)
__global__ void quant_k(const u16* __restrict__ zh, const u16* __restrict__ zl,
                        const u16* __restrict__ cbf, const float* __restrict__ cbn,
                        const float* __restrict__ cb, u16* __restrict__ e,
                        float* __restrict__ diff) {
    constexpr int PZ = 264;
    __shared__ u16 zs[2 * 32 * PZ];
    __shared__ float znp[256];
    __shared__ float zn[32];
    __shared__ float rbd[4][32];
    __shared__ int   rbc[4][32];
    __shared__ int   widx[32];

    int t = threadIdx.x, l = t & 63, wv = t >> 6, g = l >> 4;
    int bi = blockIdx.x;
    int row0 = bi * 32;

    for (int i = t; i < 2048; i += 256) {
        int c = i & 31, r = (i >> 5) & 31, pl = i >> 10;
        uint4 v = *(const uint4*)&(pl ? zl : zh)[(row0 + r) * 256 + c * 8];
        *(uint4*)&zs[pl * 32 * PZ + r * PZ + c * 8] = v;
    }
    __syncthreads();
    {
        int r = t >> 3, part = t & 7;
        float s = 0.f;
        for (int k = part * 32; k < part * 32 + 32; ++k) {
            float v = h2f(zs[r * PZ + k]) + h2f(zs[32 * PZ + r * PZ + k]) * (1.f / 4096.f);
            s = fmaf(v, v, s);
        }
        znp[t] = s;
    }
    __syncthreads();
    if (t < 32) {
        float s = 0.f;
        for (int q = 0; q < 8; ++q) s += znp[t * 8 + q];
        zn[t] = s;
    }

    float rd[8]; int rc[8];
    #pragma unroll
    for (int s = 0; s < 8; ++s) { rd[s] = 1e30f; rc[s] = 0; }

    for (int noi = 0; noi < 8; ++noi) {
        int no = (noi + bi) & 7;                       // rotated column-block order
        int n0 = wv * 256 + no * 32;
        f32x4 ahh[2][2], ahl[2][2], alh[2][2];
        f32x4 z4 = {0.f, 0.f, 0.f, 0.f};
        #pragma unroll
        for (int mi = 0; mi < 2; ++mi)
            #pragma unroll
            for (int nf = 0; nf < 2; ++nf) { ahh[mi][nf] = z4; ahl[mi][nf] = z4; alh[mi][nf] = z4; }
        for (int ksi = 0; ksi < 8; ++ksi) {
            int ks = (ksi + (bi >> 3)) & 7;            // rotated k-chunk order
            f16x8 Bh[2], Bl[2];
            #pragma unroll
            for (int nf = 0; nf < 2; ++nf) {
                int fg = (n0 >> 4) + nf;
                Bh[nf] = *(const f16x8*)&cbf[(size_t)((ks * 2 + 0) * 64 + fg) * 512 + l * 8];
                Bl[nf] = *(const f16x8*)&cbf[(size_t)((ks * 2 + 1) * 64 + fg) * 512 + l * 8];
            }
            #pragma unroll
            for (int mi = 0; mi < 2; ++mi) {
                f16x8 ah = *(const f16x8*)&zs[(mi * 16 + (l & 15)) * PZ + ks * 32 + g * 8];
                f16x8 al = *(const f16x8*)&zs[32 * PZ + (mi * 16 + (l & 15)) * PZ + ks * 32 + g * 8];
                #pragma unroll
                for (int nf = 0; nf < 2; ++nf) {
                    ahh[mi][nf] = __builtin_amdgcn_mfma_f32_16x16x32_f16(ah, Bh[nf], ahh[mi][nf], 0, 0, 0);
                    ahl[mi][nf] = __builtin_amdgcn_mfma_f32_16x16x32_f16(ah, Bl[nf], ahl[mi][nf], 0, 0, 0);
                    alh[mi][nf] = __builtin_amdgcn_mfma_f32_16x16x32_f16(al, Bh[nf], alh[mi][nf], 0, 0, 0);
                }
            }
        }
        #pragma unroll
        for (int mi = 0; mi < 2; ++mi)
            #pragma unroll
            for (int nf = 0; nf < 2; ++nf) {
                int col = n0 + nf * 16 + (l & 15);
                float cn = cbn[col];
                #pragma unroll
                for (int reg = 0; reg < 4; ++reg) {
                    float d = cn - 2.f * (ahh[mi][nf][reg] +
                              (ahl[mi][nf][reg] + alh[mi][nf][reg]) * (1.f / 4096.f));
                    int slot = mi * 4 + reg;
                    // order-independent tie-break on lowest column index
                    if (d < rd[slot] || (d == rd[slot] && col < rc[slot])) { rd[slot] = d; rc[slot] = col; }
                }
            }
    }
    #pragma unroll
    for (int step = 1; step < 16; step <<= 1) {
        #pragma unroll
        for (int s = 0; s < 8; ++s) {
            float od = __shfl_xor(rd[s], step);
            int ocl = __shfl_xor(rc[s], step);
            if (od < rd[s] || (od == rd[s] && ocl < rc[s])) { rd[s] = od; rc[s] = ocl; }
        }
    }
    if ((l & 15) == 0) {
        #pragma unroll
        for (int s = 0; s < 8; ++s) {
            int mi = s >> 2, reg = s & 3;
            int row = mi * 16 + g * 4 + reg;
            rbd[wv][row] = rd[s]; rbc[wv][row] = rc[s];
        }
    }
    __syncthreads();
    if (t < 64) {
        float dval = 0.f;
        if (t < 32) {
            float bd = rbd[0][t]; int bc = rbc[0][t];
            #pragma unroll
            for (int w2 = 1; w2 < 4; ++w2) {
                float od = rbd[w2][t]; int ocl = rbc[w2][t];
                if (od < bd || (od == bd && ocl < bc)) { bd = od; bc = ocl; }
            }
            widx[t] = bc;
            dval = bd + zn[t];
        }
        #pragma unroll
        for (int step = 1; step < 32; step <<= 1) dval += __shfl_xor(dval, step);
        if (t == 0) atomicAdd(diff, dval * (1.f / 16777216.f));
    }
    __syncthreads();
    for (int r = 0; r < 32; ++r) {
        int wi = widx[r];
        e[(row0 + r) * 256 + t] = f2h(cb[wi * 256 + t]);
    }
}

// ============================ plain-fp16 MFMA deconv k4 s2 p1 (per-parity) ============================
template<int ICT>
__launch_bounds__(256)
__global__ void deconv4_k(const u16* __restrict__ in, const u16* __restrict__ wdf,
                          const float* __restrict__ bias, u16* __restrict__ out,
                          int IH, int IW) {
    constexpr int RST = 40;
    constexpr int ICC = ICT / 32;
    constexpr int PLSZ = 81 * RST;
    __shared__ u16 patch[PLSZ];

    int t = threadIdx.x, l = t & 63, wv = t >> 6;
    int wm = wv >> 1, wn = wv & 1, g = l >> 4;

    int bi = blockIdx.x;
    int par = bi & 3; int ry = par >> 1, rx = par & 1;
    int rest = bi >> 2;
    int tw = IW >> 3, th = IH >> 3;
    int txi = rest % tw; rest /= tw;
    int tyi = rest % th; int n = rest / th;
    int a0 = tyi << 3, b0 = txi << 3;
    int by0 = ry ? 0 : -1, bx0 = rx ? 0 : -1;
    int OH = IH << 1, OW = IW << 1;

    int pb0[2];
    #pragma unroll
    for (int mi = 0; mi < 2; ++mi) {
        int m = wm * 32 + mi * 16 + (l & 15);
        int pa = m >> 3, pb_ = m & 7;
        pb0[mi] = (pa * 9 + pb_) * RST + g * 8;
    }

    f32x4 acc[2][2];
    f32x4 z4 = {0.f, 0.f, 0.f, 0.f};
    #pragma unroll
    for (int mi = 0; mi < 2; ++mi)
        #pragma unroll
        for (int ni = 0; ni < 2; ++ni) acc[mi][ni] = z4;

    for (int icci = 0; icci < ICC; ++icci) {
        int icc = (icci + (bi >> 2)) & (ICC - 1);      // rotated icc order
        __syncthreads();
        for (int i = t; i < 324; i += 256) {
            int c = i & 3; int pp = i >> 2;
            int pr = pp / 9, pc = pp - pr * 9;
            int ar = a0 + by0 + pr, ac = b0 + bx0 + pc;
            uint4 v = make_uint4(0u, 0u, 0u, 0u);
            if ((unsigned)ar < (unsigned)IH && (unsigned)ac < (unsigned)IW)
                v = *(const uint4*)&in[((n * IH + ar) * IW + ac) * ICT + icc * 32 + c * 8];
            *(uint4*)&patch[(pr * 9 + pc) * RST + c * 8] = v;
        }
        __syncthreads();
        #pragma unroll
        for (int tti = 0; tti < 4; ++tti) {
            int tt = (tti + bi) & 3;                   // rotated tap order
            int tty = tt >> 1, ttx = tt & 1;
            int ky = 1 - ry + 2 * tty, kx = 1 - rx + 2 * ttx;
            int tap = ky * 4 + kx;
            int shift = ((1 - tty) * 9 + (1 - ttx)) * RST;
            f16x8 B[2];
            #pragma unroll
            for (int ni = 0; ni < 2; ++ni)
                B[ni] = *(const f16x8*)&wdf[(size_t)((tap * ICC + icc) * 4 + wn * 2 + ni) * 512 + l * 8];
            #pragma unroll
            for (int mi = 0; mi < 2; ++mi) {
                f16x8 a = *(const f16x8*)&patch[pb0[mi] + shift];
                #pragma unroll
                for (int ni = 0; ni < 2; ++ni)
                    acc[mi][ni] = __builtin_amdgcn_mfma_f32_16x16x32_f16(a, B[ni], acc[mi][ni], 0, 0, 0);
            }
        }
    }
    #pragma unroll
    for (int mi = 0; mi < 2; ++mi)
        #pragma unroll
        for (int ni = 0; ni < 2; ++ni) {
            int oc = wn * 32 + ni * 16 + (l & 15);
            float bv = bias[oc];
            #pragma unroll
            for (int reg = 0; reg < 4; ++reg) {
                float v = fmaxf(acc[mi][ni][reg] + bv, 0.f);
                int pix = wm * 32 + mi * 16 + g * 4 + reg;
                int oy = ((a0 + (pix >> 3)) << 1) + ry;
                int ox = ((b0 + (pix & 7)) << 1) + rx;
                out[((n * OH + oy) * OW + ox) * 64 + oc] = f2h(v);
            }
        }
}

// ============================ final conv 3x3 64->1, p1, tanh (LDS-tiled, v_dot2) ============================
__launch_bounds__(256)
__global__ void conv3x3_tanh_k(const u16* __restrict__ in, const float* __restrict__ w,
                               const float* __restrict__ b, float* __restrict__ out) {
    __shared__ u16 tile[18 * 18 * 72];
    __shared__ u32 wpk[288];   // [tap][icp] half2-packed weights
    int t = threadIdx.x;
    int bi = blockIdx.x;
    int n = bi >> 6;
    int tile6 = bi & 63;
    int ty0 = (tile6 >> 3) << 4, tx0 = (tile6 & 7) << 4;

    for (int i = t; i < 288; i += 256) {
        int tap = i >> 5, icp = i & 31;
        h2 p;
        p.x = (f16)w[(2 * icp) * 9 + tap];
        p.y = (f16)w[(2 * icp + 1) * 9 + tap];
        wpk[tap * 32 + icp] = __builtin_bit_cast(u32, p);
    }
    for (int i = t; i < 2592; i += 256) {
        int ch = i & 7, pix = i >> 3;
        int pr = pix / 18, pc = pix - pr * 18;
        int gy = ty0 - 1 + pr, gx = tx0 - 1 + pc;
        uint4 v = make_uint4(0u, 0u, 0u, 0u);
        if ((unsigned)gy < 128u && (unsigned)gx < 128u)
            v = *(const uint4*)&in[(((n << 7) + gy) * 128 + gx) * 64 + ch * 8];
        *(uint4*)&tile[pix * 72 + ch * 8] = v;
    }
    __syncthreads();

    int ty = t >> 4, tx = t & 15;
    float acc = b[0];
    #pragma unroll
    for (int dy = 0; dy < 3; ++dy) {
        #pragma unroll
        for (int dx = 0; dx < 3; ++dx) {
            int base = ((ty + dy) * 18 + (tx + dx)) * 72;
            const u32* wp = &wpk[(dy * 3 + dx) * 32];
            #pragma unroll
            for (int c8 = 0; c8 < 8; ++c8) {
                uint4 v = *(const uint4*)&tile[base + c8 * 8];
                acc = __builtin_amdgcn_fdot2(__builtin_bit_cast(h2, v.x),
                        __builtin_bit_cast(h2, wp[c8 * 4 + 0]), acc, false);
                acc = __builtin_amdgcn_fdot2(__builtin_bit_cast(h2, v.y),
                        __builtin_bit_cast(h2, wp[c8 * 4 + 1]), acc, false);
                acc = __builtin_amdgcn_fdot2(__builtin_bit_cast(h2, v.z),
                        __builtin_bit_cast(h2, wp[c8 * 4 + 2]), acc, false);
                acc = __builtin_amdgcn_fdot2(__builtin_bit_cast(h2, v.w),
                        __builtin_bit_cast(h2, wp[c8 * 4 + 3]), acc, false);
            }
        }
    }
    int oy = ty0 + ty, ox = tx0 + tx;
    out[(n << 14) + (oy << 7) + ox] = tanhf(acc);
}

extern "C" void kernel_launch(void* const* d_in, const int* in_sizes, int n_in,
                              void* d_out, int out_size, void* d_ws, size_t ws_size,
                              hipStream_t stream) {
    (void)in_sizes; (void)n_in; (void)out_size; (void)ws_size;
    const float* x   = (const float*)d_in[0];
    const float* ew1 = (const float*)d_in[1];
    const float* eb1 = (const float*)d_in[2];
    const float* ew2 = (const float*)d_in[3];
    const float* eb2 = (const float*)d_in[4];
    const float* ew3 = (const float*)d_in[5];
    const float* eb3 = (const float*)d_in[6];
    const float* cb  = (const float*)d_in[7];
    const float* dw1 = (const float*)d_in[8];
    const float* db1 = (const float*)d_in[9];
    const float* dw2 = (const float*)d_in[10];
    const float* db2 = (const float*)d_in[11];
    const float* dw3 = (const float*)d_in[12];
    const float* db3 = (const float*)d_in[13];
    float* out = (float*)d_out;

    u16* ws = (u16*)d_ws;
    u16* a1h = ws;             u16* a1l = ws + 16777216;
    u16* zh  = ws;             u16* zl  = ws + 16777216;
    u16* a2h = ws + 33554432;  u16* a2l = ws + 50331648;
    u16* e   = ws + 33554432;
    u16* y1  = ws + 67108864;
    u16* y2  = ws;
    u16* wBf2 = ws + 83886080;          // 204800
    u16* wBf3 = wBf2 + 204800;          // 819200
    u16* wd1f = wBf3 + 819200;          // 262144
    u16* wd2f = wd1f + 262144;          // 65536
    u16* cbf  = wd2f + 65536;           // 524288
    float* cbn = (float*)(cbf + 524288);

    hipMemsetAsync(out + 1048576, 0, 4, stream);  // diff accumulator

    prep_wconv_k<<<800, 256, 0, stream>>>(ew2, wBf2, 2);   // NF=4
    prep_wconv_k<<<3200, 256, 0, stream>>>(ew3, wBf3, 4);  // NF=16
    prep_wdec_k<<<1024, 256, 0, stream>>>(dw1, wd1f, 3);   // ICC=8
    prep_wdec_k<<<256, 256, 0, stream>>>(dw2, wd2f, 1);    // ICC=2
    prep_cb_k<<<2048, 256, 0, stream>>>(cb, cbf);
    prep_cbn_k<<<4, 256, 0, stream>>>(cb, cbn);

    conv1_k<<<1024, 256, 0, stream>>>(x, ew1, eb1, a1h, a1l);
    conv5_k<1, 64, 2, true><<<4096, 256, 0, stream>>>(a1h, a1l, wBf2, eb2, a2h, a2l, 64, 64, 64, 64);
    conv5_k<2, 256, 4, false><<<2048, 256, 0, stream>>>(a2h, a2l, wBf3, eb3, zh, zl, 64, 64, 32, 32);
    quant_k<<<2048, 256, 0, stream>>>(zh, zl, cbf, cbn, cb, e, out + 1048576);
    deconv4_k<256><<<4096, 256, 0, stream>>>(e, wd1f, db1, y1, 32, 32);
    deconv4_k<64><<<16384, 256, 0, stream>>>(y1, wd2f, db2, y2, 64, 64);
    conv3x3_tanh_k<<<4096, 256, 0, stream>>>(y2, dw3, db3, out);
}

// Round 6
// 806.463 us; speedup vs baseline: 1.1793x; 1.0637x over previous
//
#include <hip/hip_runtime.h>

typedef _Float16 f16;
typedef _Float16 f16x8 __attribute__((ext_vector_type(8)));
typedef _Float16 f16x4 __attribute__((ext_vector_type(4)));
typedef _Float16 h2 __attribute__((ext_vector_type(2)));
typedef float f32x4 __attribute__((ext_vector_type(4)));
typedef unsigned short u16;
typedef unsigned int u32;

#define DEVI __device__ __forceinline__

DEVI u16 f2h(float f) { f16 h = (f16)f; return __builtin_bit_cast(u16, h); }
DEVI float h2f(u16 u) { f16 h = __builtin_bit_cast(f16, u); return (float)h; }

// ============================ weight prep ============================
// conv weights (OCT,64,5,5) -> frag-ordered fp16 split planes:
// dst[(((tap*2+icc)*2+pl)*NF + f)*512 + lane*8 + j]
__launch_bounds__(256)
__global__ void prep_wconv_k(const float* __restrict__ src, u16* __restrict__ dst, int nf_sh) {
    int i = blockIdx.x * 256 + threadIdx.x;
    int j = i & 7, lane = (i >> 3) & 63;
    int q = i >> 9;
    int f = q & ((1 << nf_sh) - 1); q >>= nf_sh;
    int pl = q & 1; q >>= 1;
    int icc = q & 1; int tap = q >> 1;
    int oc = (f << 4) + (lane & 15);
    int ic = icc * 32 + ((lane >> 4) << 3) + j;
    float w = src[(oc * 64 + ic) * 25 + tap];
    if (pl == 0) dst[i] = f2h(w);
    else         dst[i] = f2h((w - h2f(f2h(w))) * 4096.f);
}
// deconv weights (ICT,64,4,4) -> plain fp16 frag order
__launch_bounds__(256)
__global__ void prep_wdec_k(const float* __restrict__ src, u16* __restrict__ dst, int icc_sh) {
    int i = blockIdx.x * 256 + threadIdx.x;
    int j = i & 7, lane = (i >> 3) & 63;
    int f = (i >> 9) & 3;
    int q = i >> 11;
    int icc = q & ((1 << icc_sh) - 1); int tap = q >> icc_sh;
    int oc = (f << 4) + (lane & 15);
    int ic = icc * 32 + ((lane >> 4) << 3) + j;
    dst[i] = f2h(src[(ic * 64 + oc) * 16 + tap]);
}
// codebook (1024,256) -> split fp16 frag order
__launch_bounds__(256)
__global__ void prep_cb_k(const float* __restrict__ cb, u16* __restrict__ dst) {
    int i = blockIdx.x * 256 + threadIdx.x;   // 524288
    int j = i & 7, lane = (i >> 3) & 63;
    int f = (i >> 9) & 63;
    int q = i >> 15;
    int pl = q & 1; int ks = q >> 1;
    int n = (f << 4) + (lane & 15);
    int k = ks * 32 + ((lane >> 4) << 3) + j;
    float w = cb[n * 256 + k];
    if (pl == 0) dst[i] = f2h(w);
    else         dst[i] = f2h((w - h2f(f2h(w))) * 4096.f);
}
__launch_bounds__(256)
__global__ void prep_cbn_k(const float* __restrict__ cb, float* __restrict__ cbn) {
    int row = blockIdx.x * 256 + threadIdx.x;          // 1024
    float s = 0.f;
    for (int c = 0; c < 256; c += 4) {
        f32x4 v = *(const f32x4*)&cb[row * 256 + c];
        s = fmaf(v.x, v.x, s); s = fmaf(v.y, v.y, s);
        s = fmaf(v.z, v.z, s); s = fmaf(v.w, v.w, s);
    }
    cbn[row] = s;
}

// ============================ conv1: 1->64, 5x5 s2 p2, relu, split-fp16 out ============================
__launch_bounds__(256)
__global__ void conv1_k(const float* __restrict__ x, const float* __restrict__ w,
                        const float* __restrict__ b, u16* __restrict__ oh, u16* __restrict__ ol) {
    __shared__ float wl[25 * 64];
    __shared__ float bl[64];
    int t = threadIdx.x;
    for (int i = t; i < 1600; i += 256) wl[(i % 25) * 64 + i / 25] = w[i];
    if (t < 64) bl[t] = b[t];
    __syncthreads();
    int p = blockIdx.x * 256 + t;                       // 262144 pixels
    int ox = p & 63, oy = (p >> 6) & 63, n = p >> 12;
    f32x4 acc[16];
    #pragma unroll
    for (int c = 0; c < 16; ++c) acc[c] = *(f32x4*)&bl[c * 4];
    for (int dy = 0; dy < 5; ++dy) {
        int iy = 2 * oy - 2 + dy;
        if ((unsigned)iy >= 128u) continue;
        for (int dx = 0; dx < 5; ++dx) {
            int ix = 2 * ox - 2 + dx;
            if ((unsigned)ix >= 128u) continue;
            float v = x[(n * 128 + iy) * 128 + ix];
            const float* wp = &wl[(dy * 5 + dx) * 64];
            #pragma unroll
            for (int c = 0; c < 16; ++c) {
                f32x4 w4 = *(const f32x4*)&wp[c * 4];
                acc[c].x = fmaf(v, w4.x, acc[c].x); acc[c].y = fmaf(v, w4.y, acc[c].y);
                acc[c].z = fmaf(v, w4.z, acc[c].z); acc[c].w = fmaf(v, w4.w, acc[c].w);
            }
        }
    }
    #pragma unroll
    for (int c = 0; c < 16; ++c) {
        ushort4 uh, ul;
        float vv[4] = {acc[c].x, acc[c].y, acc[c].z, acc[c].w};
        u16 rh[4], rl[4];
        #pragma unroll
        for (int k = 0; k < 4; ++k) {
            float v = fmaxf(vv[k], 0.f);
            f16 hh = (f16)v;
            rh[k] = __builtin_bit_cast(u16, hh);
            rl[k] = f2h((v - (float)hh) * 4096.f);
        }
        uh.x = rh[0]; uh.y = rh[1]; uh.z = rh[2]; uh.w = rh[3];
        ul.x = rl[0]; ul.y = rl[1]; ul.z = rl[2]; ul.w = rl[3];
        *(ushort4*)&oh[p * 64 + c * 4] = uh;
        *(ushort4*)&ol[p * 64 + c * 4] = ul;
    }
}

// ============================ split-fp16 MFMA 5x5 conv ============================
// LDS: pixel pair P=pp>>1 owns a 64-half line; chunk c of parity r at slot (P+2c+r)&7.
// Per-block tap/icc rotation decorrelates the weight-fragment stream across CUs.
template<int S, int OCT, int NI, bool RELU>
__launch_bounds__(256)
__global__ void conv5_k(const u16* __restrict__ Ah_g, const u16* __restrict__ Al_g,
                        const u16* __restrict__ wBf, const float* __restrict__ bias,
                        u16* __restrict__ Oh, u16* __restrict__ Ol,
                        int IH, int IW, int OH, int OW) {
    constexpr int PATCH = 7 * S + 5;
    constexpr int NPIX = PATCH * PATCH;
    constexpr int NPAIR = (NPIX + 1) / 2;
    constexpr int PLSZ = NPAIR * 64;
    constexpr int NF = OCT / 16;
    constexpr int BN = NI * 32;
    constexpr int OCB = OCT / BN;
    __shared__ u16 patch[2 * PLSZ];

    int t = threadIdx.x, l = t & 63, wv = t >> 6;
    int wm = wv >> 1, wn = wv & 1, g = l >> 4;

    int bi = blockIdx.x;
    int ocb = bi % OCB; int rest = bi / OCB;
    int tw = OW >> 3, th = OH >> 3;
    int txi = rest % tw; rest /= tw;
    int tyi = rest % th; int n = rest / th;
    int iy0 = S * (tyi << 3) - 2, ix0 = S * (txi << 3) - 2;

    int ppb[2];
    #pragma unroll
    for (int mi = 0; mi < 2; ++mi) {
        int m = wm * 32 + mi * 16 + (l & 15);
        int py = m >> 3, px = m & 7;
        ppb[mi] = (S * py) * PATCH + S * px;
    }

    f32x4 ahh[2][NI], ahl[2][NI], alh[2][NI];
    f32x4 z4 = {0.f, 0.f, 0.f, 0.f};
    #pragma unroll
    for (int mi = 0; mi < 2; ++mi)
        #pragma unroll
        for (int ni = 0; ni < NI; ++ni) { ahh[mi][ni] = z4; ahl[mi][ni] = z4; alh[mi][ni] = z4; }

    int tap0 = bi % 25;
    int iccr = bi & 1;
    for (int icci = 0; icci < 2; ++icci) {
        int icc = icci ^ iccr;
        __syncthreads();
        for (int i = t; i < NPIX * 8; i += 256) {
            int c = i & 3; int r2 = i >> 2;
            int pl = (r2 >= NPIX); int pp = r2 - pl * NPIX;
            int py = pp / PATCH, px = pp - py * PATCH;
            int iy = iy0 + py, ix = ix0 + px;
            uint4 v = make_uint4(0u, 0u, 0u, 0u);
            if ((unsigned)iy < (unsigned)IH && (unsigned)ix < (unsigned)IW)
                v = *(const uint4*)&(pl ? Al_g : Ah_g)[(((n * IH + iy) * IW + ix)) * 64 + icc * 32 + c * 8];
            int P = pp >> 1, r = pp & 1;
            *(uint4*)&patch[pl * PLSZ + (P << 6) + (((P + (c << 1) + r) & 7) << 3)] = v;
        }
        __syncthreads();
        for (int tapi = 0; tapi < 25; ++tapi) {
            int tap = tap0 + tapi; if (tap >= 25) tap -= 25;
            int dy = tap / 5, dx = tap - 5 * dy;
            int tadd = dy * PATCH + dx;
            f16x8 Bh[NI], Bl[NI];
            #pragma unroll
            for (int ni = 0; ni < NI; ++ni) {
                int fg = ocb * (BN / 16) + wn * NI + ni;
                Bh[ni] = *(const f16x8*)&wBf[(size_t)(((tap * 2 + icc) * 2 + 0) * NF + fg) * 512 + l * 8];
                Bl[ni] = *(const f16x8*)&wBf[(size_t)(((tap * 2 + icc) * 2 + 1) * NF + fg) * 512 + l * 8];
            }
            #pragma unroll
            for (int mi = 0; mi < 2; ++mi) {
                int pp = ppb[mi] + tadd;
                int P = pp >> 1, r = pp & 1;
                int offs = (P << 6) + (((P + (g << 1) + r) & 7) << 3);
                f16x8 ah = *(const f16x8*)&patch[offs];
                f16x8 al = *(const f16x8*)&patch[PLSZ + offs];
                #pragma unroll
                for (int ni = 0; ni < NI; ++ni) {
                    ahh[mi][ni] = __builtin_amdgcn_mfma_f32_16x16x32_f16(ah, Bh[ni], ahh[mi][ni], 0, 0, 0);
                    ahl[mi][ni] = __builtin_amdgcn_mfma_f32_16x16x32_f16(ah, Bl[ni], ahl[mi][ni], 0, 0, 0);
                    alh[mi][ni] = __builtin_amdgcn_mfma_f32_16x16x32_f16(al, Bh[ni], alh[mi][ni], 0, 0, 0);
                }
            }
        }
    }
    #pragma unroll
    for (int mi = 0; mi < 2; ++mi)
        #pragma unroll
        for (int ni = 0; ni < NI; ++ni) {
            int oc = ocb * BN + wn * (NI * 16) + ni * 16 + (l & 15);
            float bv = bias[oc];
            #pragma unroll
            for (int reg = 0; reg < 4; ++reg) {
                float v = ahh[mi][ni][reg] + (ahl[mi][ni][reg] + alh[mi][ni][reg]) * (1.f / 4096.f) + bv;
                if (RELU) v = fmaxf(v, 0.f);
                int pix = wm * 32 + mi * 16 + g * 4 + reg;
                int oy = (tyi << 3) + (pix >> 3), ox = (txi << 3) + (pix & 7);
                int idx = ((n * OH + oy) * OW + ox) * OCT + oc;
                f16 hh = (f16)v;
                Oh[idx] = __builtin_bit_cast(u16, hh);
                Ol[idx] = f2h((v - (float)hh) * 4096.f);
            }
        }
}

// ============================ quantize v3: M=64, prefetched B, split-fp16 MFMA ============================
// 1024 blocks x 64 rows. Each wave owns 256 cols (8 chunks of 32), ks=8 k-steps.
// B fragments prefetched one (no,ks) step ahead; 24 independent MFMAs per step.
__launch_bounds__(256)
__global__ void quant_k(const u16* __restrict__ zh, const u16* __restrict__ zl,
                        const u16* __restrict__ cbf, const float* __restrict__ cbn,
                        const float* __restrict__ cb, u16* __restrict__ e,
                        float* __restrict__ diff) {
    constexpr int PZ = 264;
    constexpr int PLSZ = 64 * PZ;
    __shared__ u16 zs[2 * PLSZ];
    __shared__ float znp[256];
    __shared__ float zn[64];
    __shared__ float rbd[4][64];
    __shared__ int   rbc[4][64];
    __shared__ int   widx[64];

    int t = threadIdx.x, l = t & 63, wv = t >> 6, g = l >> 4;
    int bi = blockIdx.x;
    int row0 = bi << 6;

    // stage 64 rows x 256 k x 2 planes
    for (int i = t; i < 4096; i += 256) {
        int c = i & 31, r = (i >> 5) & 63, pl = i >> 11;
        uint4 v = *(const uint4*)&(pl ? zl : zh)[(size_t)(row0 + r) * 256 + c * 8];
        *(uint4*)&zs[pl * PLSZ + r * PZ + c * 8] = v;
    }
    __syncthreads();
    {
        int r = t >> 2, part = t & 3;
        float s = 0.f;
        for (int k = part * 64; k < part * 64 + 64; ++k) {
            float v = h2f(zs[r * PZ + k]) + h2f(zs[PLSZ + r * PZ + k]) * (1.f / 4096.f);
            s = fmaf(v, v, s);
        }
        znp[t] = s;
    }
    __syncthreads();
    if (t < 64) zn[t] = znp[t * 4] + znp[t * 4 + 1] + znp[t * 4 + 2] + znp[t * 4 + 3];

    float rd[16]; int rc[16];
    #pragma unroll
    for (int s = 0; s < 16; ++s) { rd[s] = 1e30f; rc[s] = 0; }

    int rot_no = bi & 7, rot_ks = (bi >> 3) & 7;
    f16x8 Bh0[2], Bl0[2], Bh1[2], Bl1[2];
    {   // initial prefetch (noi=0, ksi=0)
        int no2 = rot_no, ks = rot_ks;
        int fgb = wv * 16 + no2 * 2;
        #pragma unroll
        for (int nf = 0; nf < 2; ++nf) {
            Bh0[nf] = *(const f16x8*)&cbf[(size_t)((ks * 2 + 0) * 64 + fgb + nf) * 512 + l * 8];
            Bl0[nf] = *(const f16x8*)&cbf[(size_t)((ks * 2 + 1) * 64 + fgb + nf) * 512 + l * 8];
        }
    }

    for (int noi = 0; noi < 8; ++noi) {
        int no2 = (noi + rot_no) & 7;
        f32x4 ahh[4][2], ahl[4][2], alh[4][2];
        f32x4 z4 = {0.f, 0.f, 0.f, 0.f};
        #pragma unroll
        for (int mi = 0; mi < 4; ++mi)
            #pragma unroll
            for (int nf = 0; nf < 2; ++nf) { ahh[mi][nf] = z4; ahl[mi][nf] = z4; alh[mi][nf] = z4; }

        #pragma unroll 2
        for (int ksi = 0; ksi < 8; ++ksi) {
            int ks = (ksi + rot_ks) & 7;
            // prefetch next step's B fragments
            if (!(noi == 7 && ksi == 7)) {
                int nno = (ksi == 7) ? noi + 1 : noi;
                int nks = (ksi == 7) ? 0 : ksi + 1;
                int no2n = (nno + rot_no) & 7;
                int ksn = (nks + rot_ks) & 7;
                int fgb = wv * 16 + no2n * 2;
                #pragma unroll
                for (int nf = 0; nf < 2; ++nf) {
                    Bh1[nf] = *(const f16x8*)&cbf[(size_t)((ksn * 2 + 0) * 64 + fgb + nf) * 512 + l * 8];
                    Bl1[nf] = *(const f16x8*)&cbf[(size_t)((ksn * 2 + 1) * 64 + fgb + nf) * 512 + l * 8];
                }
            }
            #pragma unroll
            for (int mi = 0; mi < 4; ++mi) {
                int ao = (mi * 16 + (l & 15)) * PZ + ks * 32 + g * 8;
                f16x8 ah = *(const f16x8*)&zs[ao];
                f16x8 al = *(const f16x8*)&zs[PLSZ + ao];
                #pragma unroll
                for (int nf = 0; nf < 2; ++nf) {
                    ahh[mi][nf] = __builtin_amdgcn_mfma_f32_16x16x32_f16(ah, Bh0[nf], ahh[mi][nf], 0, 0, 0);
                    ahl[mi][nf] = __builtin_amdgcn_mfma_f32_16x16x32_f16(ah, Bl0[nf], ahl[mi][nf], 0, 0, 0);
                    alh[mi][nf] = __builtin_amdgcn_mfma_f32_16x16x32_f16(al, Bh0[nf], alh[mi][nf], 0, 0, 0);
                }
            }
            #pragma unroll
            for (int nf = 0; nf < 2; ++nf) { Bh0[nf] = Bh1[nf]; Bl0[nf] = Bl1[nf]; }
        }
        // flush this 32-col chunk into per-row running (d, col) minima
        int n0 = wv * 256 + no2 * 32;
        #pragma unroll
        for (int nf = 0; nf < 2; ++nf) {
            int col = n0 + nf * 16 + (l & 15);
            float cn = cbn[col];
            #pragma unroll
            for (int mi = 0; mi < 4; ++mi)
                #pragma unroll
                for (int reg = 0; reg < 4; ++reg) {
                    float d = cn - 2.f * (ahh[mi][nf][reg] +
                              (ahl[mi][nf][reg] + alh[mi][nf][reg]) * (1.f / 4096.f));
                    int slot = mi * 4 + reg;
                    if (d < rd[slot] || (d == rd[slot] && col < rc[slot])) { rd[slot] = d; rc[slot] = col; }
                }
        }
    }

    #pragma unroll
    for (int step = 1; step < 16; step <<= 1) {
        #pragma unroll
        for (int s = 0; s < 16; ++s) {
            float od = __shfl_xor(rd[s], step);
            int ocl = __shfl_xor(rc[s], step);
            if (od < rd[s] || (od == rd[s] && ocl < rc[s])) { rd[s] = od; rc[s] = ocl; }
        }
    }
    if ((l & 15) == 0) {
        #pragma unroll
        for (int s = 0; s < 16; ++s) {
            int row = (s >> 2) * 16 + g * 4 + (s & 3);
            rbd[wv][row] = rd[s]; rbc[wv][row] = rc[s];
        }
    }
    __syncthreads();
    if (t < 64) {
        float bd = rbd[0][t]; int bc = rbc[0][t];
        #pragma unroll
        for (int w2 = 1; w2 < 4; ++w2) {
            float od = rbd[w2][t]; int ocl = rbc[w2][t];
            if (od < bd || (od == bd && ocl < bc)) { bd = od; bc = ocl; }
        }
        widx[t] = bc;
        float dval = bd + zn[t];
        #pragma unroll
        for (int step = 1; step < 64; step <<= 1) dval += __shfl_xor(dval, step);
        if (t == 0) atomicAdd(diff, dval * (1.f / 16777216.f));
    }
    __syncthreads();
    for (int r = 0; r < 64; ++r) {
        int wi = widx[r];
        e[(size_t)(row0 + r) * 256 + t] = f2h(cb[wi * 256 + t]);
    }
}

// ============================ plain-fp16 MFMA deconv k4 s2 p1 (per-parity) ============================
template<int ICT>
__launch_bounds__(256)
__global__ void deconv4_k(const u16* __restrict__ in, const u16* __restrict__ wdf,
                          const float* __restrict__ bias, u16* __restrict__ out,
                          int IH, int IW) {
    constexpr int RST = 40;
    constexpr int ICC = ICT / 32;
    constexpr int PLSZ = 81 * RST;
    __shared__ u16 patch[PLSZ];

    int t = threadIdx.x, l = t & 63, wv = t >> 6;
    int wm = wv >> 1, wn = wv & 1, g = l >> 4;

    int bi = blockIdx.x;
    int par = bi & 3; int ry = par >> 1, rx = par & 1;
    int rest = bi >> 2;
    int tw = IW >> 3, th = IH >> 3;
    int txi = rest % tw; rest /= tw;
    int tyi = rest % th; int n = rest / th;
    int a0 = tyi << 3, b0 = txi << 3;
    int by0 = ry ? 0 : -1, bx0 = rx ? 0 : -1;
    int OH = IH << 1, OW = IW << 1;

    int pb0[2];
    #pragma unroll
    for (int mi = 0; mi < 2; ++mi) {
        int m = wm * 32 + mi * 16 + (l & 15);
        int pa = m >> 3, pb_ = m & 7;
        pb0[mi] = (pa * 9 + pb_) * RST + g * 8;
    }

    f32x4 acc[2][2];
    f32x4 z4 = {0.f, 0.f, 0.f, 0.f};
    #pragma unroll
    for (int mi = 0; mi < 2; ++mi)
        #pragma unroll
        for (int ni = 0; ni < 2; ++ni) acc[mi][ni] = z4;

    for (int icci = 0; icci < ICC; ++icci) {
        int icc = (icci + (bi >> 2)) & (ICC - 1);
        __syncthreads();
        for (int i = t; i < 324; i += 256) {
            int c = i & 3; int pp = i >> 2;
            int pr = pp / 9, pc = pp - pr * 9;
            int ar = a0 + by0 + pr, ac = b0 + bx0 + pc;
            uint4 v = make_uint4(0u, 0u, 0u, 0u);
            if ((unsigned)ar < (unsigned)IH && (unsigned)ac < (unsigned)IW)
                v = *(const uint4*)&in[((n * IH + ar) * IW + ac) * ICT + icc * 32 + c * 8];
            *(uint4*)&patch[(pr * 9 + pc) * RST + c * 8] = v;
        }
        __syncthreads();
        #pragma unroll
        for (int tti = 0; tti < 4; ++tti) {
            int tt = (tti + bi) & 3;
            int tty = tt >> 1, ttx = tt & 1;
            int ky = 1 - ry + 2 * tty, kx = 1 - rx + 2 * ttx;
            int tap = ky * 4 + kx;
            int shift = ((1 - tty) * 9 + (1 - ttx)) * RST;
            f16x8 B[2];
            #pragma unroll
            for (int ni = 0; ni < 2; ++ni)
                B[ni] = *(const f16x8*)&wdf[(size_t)((tap * ICC + icc) * 4 + wn * 2 + ni) * 512 + l * 8];
            #pragma unroll
            for (int mi = 0; mi < 2; ++mi) {
                f16x8 a = *(const f16x8*)&patch[pb0[mi] + shift];
                #pragma unroll
                for (int ni = 0; ni < 2; ++ni)
                    acc[mi][ni] = __builtin_amdgcn_mfma_f32_16x16x32_f16(a, B[ni], acc[mi][ni], 0, 0, 0);
            }
        }
    }
    #pragma unroll
    for (int mi = 0; mi < 2; ++mi)
        #pragma unroll
        for (int ni = 0; ni < 2; ++ni) {
            int oc = wn * 32 + ni * 16 + (l & 15);
            float bv = bias[oc];
            #pragma unroll
            for (int reg = 0; reg < 4; ++reg) {
                float v = fmaxf(acc[mi][ni][reg] + bv, 0.f);
                int pix = wm * 32 + mi * 16 + g * 4 + reg;
                int oy = ((a0 + (pix >> 3)) << 1) + ry;
                int ox = ((b0 + (pix & 7)) << 1) + rx;
                out[((n * OH + oy) * OW + ox) * 64 + oc] = f2h(v);
            }
        }
}

// ============================ final conv 3x3 64->1, p1, tanh (LDS-tiled, v_dot2) ============================
__launch_bounds__(256)
__global__ void conv3x3_tanh_k(const u16* __restrict__ in, const float* __restrict__ w,
                               const float* __restrict__ b, float* __restrict__ out) {
    __shared__ u16 tile[18 * 18 * 72];
    __shared__ u32 wpk[288];   // [tap][icp] half2-packed weights
    int t = threadIdx.x;
    int bi = blockIdx.x;
    int n = bi >> 6;
    int tile6 = bi & 63;
    int ty0 = (tile6 >> 3) << 4, tx0 = (tile6 & 7) << 4;

    for (int i = t; i < 288; i += 256) {
        int tap = i >> 5, icp = i & 31;
        h2 p;
        p.x = (f16)w[(2 * icp) * 9 + tap];
        p.y = (f16)w[(2 * icp + 1) * 9 + tap];
        wpk[tap * 32 + icp] = __builtin_bit_cast(u32, p);
    }
    for (int i = t; i < 2592; i += 256) {
        int ch = i & 7, pix = i >> 3;
        int pr = pix / 18, pc = pix - pr * 18;
        int gy = ty0 - 1 + pr, gx = tx0 - 1 + pc;
        uint4 v = make_uint4(0u, 0u, 0u, 0u);
        if ((unsigned)gy < 128u && (unsigned)gx < 128u)
            v = *(const uint4*)&in[(((n << 7) + gy) * 128 + gx) * 64 + ch * 8];
        *(uint4*)&tile[pix * 72 + ch * 8] = v;
    }
    __syncthreads();

    int ty = t >> 4, tx = t & 15;
    float acc = b[0];
    #pragma unroll
    for (int dy = 0; dy < 3; ++dy) {
        #pragma unroll
        for (int dx = 0; dx < 3; ++dx) {
            int base = ((ty + dy) * 18 + (tx + dx)) * 72;
            const u32* wp = &wpk[(dy * 3 + dx) * 32];
            #pragma unroll
            for (int c8 = 0; c8 < 8; ++c8) {
                uint4 v = *(const uint4*)&tile[base + c8 * 8];
                acc = __builtin_amdgcn_fdot2(__builtin_bit_cast(h2, v.x),
                        __builtin_bit_cast(h2, wp[c8 * 4 + 0]), acc, false);
                acc = __builtin_amdgcn_fdot2(__builtin_bit_cast(h2, v.y),
                        __builtin_bit_cast(h2, wp[c8 * 4 + 1]), acc, false);
                acc = __builtin_amdgcn_fdot2(__builtin_bit_cast(h2, v.z),
                        __builtin_bit_cast(h2, wp[c8 * 4 + 2]), acc, false);
                acc = __builtin_amdgcn_fdot2(__builtin_bit_cast(h2, v.w),
                        __builtin_bit_cast(h2, wp[c8 * 4 + 3]), acc, false);
            }
        }
    }
    int oy = ty0 + ty, ox = tx0 + tx;
    out[(n << 14) + (oy << 7) + ox] = tanhf(acc);
}

extern "C" void kernel_launch(void* const* d_in, const int* in_sizes, int n_in,
                              void* d_out, int out_size, void* d_ws, size_t ws_size,
                              hipStream_t stream) {
    (void)in_sizes; (void)n_in; (void)out_size; (void)ws_size;
    const float* x   = (const float*)d_in[0];
    const float* ew1 = (const float*)d_in[1];
    const float* eb1 = (const float*)d_in[2];
    const float* ew2 = (const float*)d_in[3];
    const float* eb2 = (const float*)d_in[4];
    const float* ew3 = (const float*)d_in[5];
    const float* eb3 = (const float*)d_in[6];
    const float* cb  = (const float*)d_in[7];
    const float* dw1 = (const float*)d_in[8];
    const float* db1 = (const float*)d_in[9];
    const float* dw2 = (const float*)d_in[10];
    const float* db2 = (const float*)d_in[11];
    const float* dw3 = (const float*)d_in[12];
    const float* db3 = (const float*)d_in[13];
    float* out = (float*)d_out;

    u16* ws = (u16*)d_ws;
    u16* a1h = ws;             u16* a1l = ws + 16777216;
    u16* zh  = ws;             u16* zl  = ws + 16777216;
    u16* a2h = ws + 33554432;  u16* a2l = ws + 50331648;
    u16* e   = ws + 33554432;
    u16* y1  = ws + 67108864;
    u16* y2  = ws;
    u16* wBf2 = ws + 83886080;          // 204800
    u16* wBf3 = wBf2 + 204800;          // 819200
    u16* wd1f = wBf3 + 819200;          // 262144
    u16* wd2f = wd1f + 262144;          // 65536
    u16* cbf  = wd2f + 65536;           // 524288
    float* cbn = (float*)(cbf + 524288);

    hipMemsetAsync(out + 1048576, 0, 4, stream);  // diff accumulator

    prep_wconv_k<<<800, 256, 0, stream>>>(ew2, wBf2, 2);   // NF=4
    prep_wconv_k<<<3200, 256, 0, stream>>>(ew3, wBf3, 4);  // NF=16
    prep_wdec_k<<<1024, 256, 0, stream>>>(dw1, wd1f, 3);   // ICC=8
    prep_wdec_k<<<256, 256, 0, stream>>>(dw2, wd2f, 1);    // ICC=2
    prep_cb_k<<<2048, 256, 0, stream>>>(cb, cbf);
    prep_cbn_k<<<4, 256, 0, stream>>>(cb, cbn);

    conv1_k<<<1024, 256, 0, stream>>>(x, ew1, eb1, a1h, a1l);
    conv5_k<1, 64, 2, true><<<4096, 256, 0, stream>>>(a1h, a1l, wBf2, eb2, a2h, a2l, 64, 64, 64, 64);
    conv5_k<2, 256, 4, false><<<2048, 256, 0, stream>>>(a2h, a2l, wBf3, eb3, zh, zl, 64, 64, 32, 32);
    quant_k<<<1024, 256, 0, stream>>>(zh, zl, cbf, cbn, cb, e, out + 1048576);
    deconv4_k<256><<<4096, 256, 0, stream>>>(e, wd1f, db1, y1, 32, 32);
    deconv4_k<64><<<16384, 256, 0, stream>>>(y1, wd2f, db2, y2, 64, 64);
    conv3x3_tanh_k<<<4096, 256, 0, stream>>>(y2, dw3, db3, out);
}

// Round 7
// 760.586 us; speedup vs baseline: 1.2504x; 1.0603x over previous
//
#include <hip/hip_runtime.h>

typedef _Float16 f16;
typedef _Float16 f16x8 __attribute__((ext_vector_type(8)));
typedef _Float16 f16x4 __attribute__((ext_vector_type(4)));
typedef _Float16 h2 __attribute__((ext_vector_type(2)));
typedef float f32x4 __attribute__((ext_vector_type(4)));
typedef unsigned short u16;
typedef unsigned int u32;

#define DEVI __device__ __forceinline__

DEVI u16 f2h(float f) { f16 h = (f16)f; return __builtin_bit_cast(u16, h); }
DEVI float h2f(u16 u) { f16 h = __builtin_bit_cast(f16, u); return (float)h; }

// ============================ weight prep ============================
// conv weights (OCT,64,5,5) -> frag-ordered fp16 split planes:
// dst[(((tap*2+icc)*2+pl)*NF + f)*512 + lane*8 + j]
__launch_bounds__(256)
__global__ void prep_wconv_k(const float* __restrict__ src, u16* __restrict__ dst, int nf_sh) {
    int i = blockIdx.x * 256 + threadIdx.x;
    int j = i & 7, lane = (i >> 3) & 63;
    int q = i >> 9;
    int f = q & ((1 << nf_sh) - 1); q >>= nf_sh;
    int pl = q & 1; q >>= 1;
    int icc = q & 1; int tap = q >> 1;
    int oc = (f << 4) + (lane & 15);
    int ic = icc * 32 + ((lane >> 4) << 3) + j;
    float w = src[(oc * 64 + ic) * 25 + tap];
    if (pl == 0) dst[i] = f2h(w);
    else         dst[i] = f2h((w - h2f(f2h(w))) * 4096.f);
}
// deconv weights (ICT,64,4,4) -> plain fp16 frag order
__launch_bounds__(256)
__global__ void prep_wdec_k(const float* __restrict__ src, u16* __restrict__ dst, int icc_sh) {
    int i = blockIdx.x * 256 + threadIdx.x;
    int j = i & 7, lane = (i >> 3) & 63;
    int f = (i >> 9) & 3;
    int q = i >> 11;
    int icc = q & ((1 << icc_sh) - 1); int tap = q >> icc_sh;
    int oc = (f << 4) + (lane & 15);
    int ic = icc * 32 + ((lane >> 4) << 3) + j;
    dst[i] = f2h(src[(ic * 64 + oc) * 16 + tap]);
}
// codebook (1024,256) -> split fp16 frag order
__launch_bounds__(256)
__global__ void prep_cb_k(const float* __restrict__ cb, u16* __restrict__ dst) {
    int i = blockIdx.x * 256 + threadIdx.x;   // 524288
    int j = i & 7, lane = (i >> 3) & 63;
    int f = (i >> 9) & 63;
    int q = i >> 15;
    int pl = q & 1; int ks = q >> 1;
    int n = (f << 4) + (lane & 15);
    int k = ks * 32 + ((lane >> 4) << 3) + j;
    float w = cb[n * 256 + k];
    if (pl == 0) dst[i] = f2h(w);
    else         dst[i] = f2h((w - h2f(f2h(w))) * 4096.f);
}
__launch_bounds__(256)
__global__ void prep_cbn_k(const float* __restrict__ cb, float* __restrict__ cbn) {
    int row = blockIdx.x * 256 + threadIdx.x;          // 1024
    float s = 0.f;
    for (int c = 0; c < 256; c += 4) {
        f32x4 v = *(const f32x4*)&cb[row * 256 + c];
        s = fmaf(v.x, v.x, s); s = fmaf(v.y, v.y, s);
        s = fmaf(v.z, v.z, s); s = fmaf(v.w, v.w, s);
    }
    cbn[row] = s;
}

// ============================ conv1: 1->64, 5x5 s2 p2, relu, split-fp16 out ============================
__launch_bounds__(256)
__global__ void conv1_k(const float* __restrict__ x, const float* __restrict__ w,
                        const float* __restrict__ b, u16* __restrict__ oh, u16* __restrict__ ol) {
    __shared__ float wl[25 * 64];
    __shared__ float bl[64];
    int t = threadIdx.x;
    for (int i = t; i < 1600; i += 256) wl[(i % 25) * 64 + i / 25] = w[i];
    if (t < 64) bl[t] = b[t];
    __syncthreads();
    int p = blockIdx.x * 256 + t;                       // 262144 pixels
    int ox = p & 63, oy = (p >> 6) & 63, n = p >> 12;
    f32x4 acc[16];
    #pragma unroll
    for (int c = 0; c < 16; ++c) acc[c] = *(f32x4*)&bl[c * 4];
    for (int dy = 0; dy < 5; ++dy) {
        int iy = 2 * oy - 2 + dy;
        if ((unsigned)iy >= 128u) continue;
        for (int dx = 0; dx < 5; ++dx) {
            int ix = 2 * ox - 2 + dx;
            if ((unsigned)ix >= 128u) continue;
            float v = x[(n * 128 + iy) * 128 + ix];
            const float* wp = &wl[(dy * 5 + dx) * 64];
            #pragma unroll
            for (int c = 0; c < 16; ++c) {
                f32x4 w4 = *(const f32x4*)&wp[c * 4];
                acc[c].x = fmaf(v, w4.x, acc[c].x); acc[c].y = fmaf(v, w4.y, acc[c].y);
                acc[c].z = fmaf(v, w4.z, acc[c].z); acc[c].w = fmaf(v, w4.w, acc[c].w);
            }
        }
    }
    #pragma unroll
    for (int c = 0; c < 16; ++c) {
        ushort4 uh, ul;
        float vv[4] = {acc[c].x, acc[c].y, acc[c].z, acc[c].w};
        u16 rh[4], rl[4];
        #pragma unroll
        for (int k = 0; k < 4; ++k) {
            float v = fmaxf(vv[k], 0.f);
            f16 hh = (f16)v;
            rh[k] = __builtin_bit_cast(u16, hh);
            rl[k] = f2h((v - (float)hh) * 4096.f);
        }
        uh.x = rh[0]; uh.y = rh[1]; uh.z = rh[2]; uh.w = rh[3];
        ul.x = rl[0]; ul.y = rl[1]; ul.z = rl[2]; ul.w = rl[3];
        *(ushort4*)&oh[p * 64 + c * 4] = uh;
        *(ushort4*)&ol[p * 64 + c * 4] = ul;
    }
}

// ============================ split-fp16 MFMA 5x5 conv ============================
// LDS: pixel pair P=pp>>1 owns a 64-half line; chunk c of parity r at slot (P+2c+r)&7.
// Per-block tap/icc rotation decorrelates the weight-fragment stream across CUs.
template<int S, int OCT, int NI, bool RELU>
__launch_bounds__(256)
__global__ void conv5_k(const u16* __restrict__ Ah_g, const u16* __restrict__ Al_g,
                        const u16* __restrict__ wBf, const float* __restrict__ bias,
                        u16* __restrict__ Oh, u16* __restrict__ Ol,
                        int IH, int IW, int OH, int OW) {
    constexpr int PATCH = 7 * S + 5;
    constexpr int NPIX = PATCH * PATCH;
    constexpr int NPAIR = (NPIX + 1) / 2;
    constexpr int PLSZ = NPAIR * 64;
    constexpr int NF = OCT / 16;
    constexpr int BN = NI * 32;
    constexpr int OCB = OCT / BN;
    __shared__ u16 patch[2 * PLSZ];

    int t = threadIdx.x, l = t & 63, wv = t >> 6;
    int wm = wv >> 1, wn = wv & 1, g = l >> 4;

    int bi = blockIdx.x;
    int ocb = bi % OCB; int rest = bi / OCB;
    int tw = OW >> 3, th = OH >> 3;
    int txi = rest % tw; rest /= tw;
    int tyi = rest % th; int n = rest / th;
    int iy0 = S * (tyi << 3) - 2, ix0 = S * (txi << 3) - 2;

    int ppb[2];
    #pragma unroll
    for (int mi = 0; mi < 2; ++mi) {
        int m = wm * 32 + mi * 16 + (l & 15);
        int py = m >> 3, px = m & 7;
        ppb[mi] = (S * py) * PATCH + S * px;
    }

    f32x4 ahh[2][NI], ahl[2][NI], alh[2][NI];
    f32x4 z4 = {0.f, 0.f, 0.f, 0.f};
    #pragma unroll
    for (int mi = 0; mi < 2; ++mi)
        #pragma unroll
        for (int ni = 0; ni < NI; ++ni) { ahh[mi][ni] = z4; ahl[mi][ni] = z4; alh[mi][ni] = z4; }

    int tap0 = bi % 25;
    int iccr = bi & 1;
    for (int icci = 0; icci < 2; ++icci) {
        int icc = icci ^ iccr;
        __syncthreads();
        for (int i = t; i < NPIX * 8; i += 256) {
            int c = i & 3; int r2 = i >> 2;
            int pl = (r2 >= NPIX); int pp = r2 - pl * NPIX;
            int py = pp / PATCH, px = pp - py * PATCH;
            int iy = iy0 + py, ix = ix0 + px;
            uint4 v = make_uint4(0u, 0u, 0u, 0u);
            if ((unsigned)iy < (unsigned)IH && (unsigned)ix < (unsigned)IW)
                v = *(const uint4*)&(pl ? Al_g : Ah_g)[(((n * IH + iy) * IW + ix)) * 64 + icc * 32 + c * 8];
            int P = pp >> 1, r = pp & 1;
            *(uint4*)&patch[pl * PLSZ + (P << 6) + (((P + (c << 1) + r) & 7) << 3)] = v;
        }
        __syncthreads();
        for (int tapi = 0; tapi < 25; ++tapi) {
            int tap = tap0 + tapi; if (tap >= 25) tap -= 25;
            int dy = tap / 5, dx = tap - 5 * dy;
            int tadd = dy * PATCH + dx;
            f16x8 Bh[NI], Bl[NI];
            #pragma unroll
            for (int ni = 0; ni < NI; ++ni) {
                int fg = ocb * (BN / 16) + wn * NI + ni;
                Bh[ni] = *(const f16x8*)&wBf[(size_t)(((tap * 2 + icc) * 2 + 0) * NF + fg) * 512 + l * 8];
                Bl[ni] = *(const f16x8*)&wBf[(size_t)(((tap * 2 + icc) * 2 + 1) * NF + fg) * 512 + l * 8];
            }
            #pragma unroll
            for (int mi = 0; mi < 2; ++mi) {
                int pp = ppb[mi] + tadd;
                int P = pp >> 1, r = pp & 1;
                int offs = (P << 6) + (((P + (g << 1) + r) & 7) << 3);
                f16x8 ah = *(const f16x8*)&patch[offs];
                f16x8 al = *(const f16x8*)&patch[PLSZ + offs];
                #pragma unroll
                for (int ni = 0; ni < NI; ++ni) {
                    ahh[mi][ni] = __builtin_amdgcn_mfma_f32_16x16x32_f16(ah, Bh[ni], ahh[mi][ni], 0, 0, 0);
                    ahl[mi][ni] = __builtin_amdgcn_mfma_f32_16x16x32_f16(ah, Bl[ni], ahl[mi][ni], 0, 0, 0);
                    alh[mi][ni] = __builtin_amdgcn_mfma_f32_16x16x32_f16(al, Bh[ni], alh[mi][ni], 0, 0, 0);
                }
            }
        }
    }
    #pragma unroll
    for (int mi = 0; mi < 2; ++mi)
        #pragma unroll
        for (int ni = 0; ni < NI; ++ni) {
            int oc = ocb * BN + wn * (NI * 16) + ni * 16 + (l & 15);
            float bv = bias[oc];
            #pragma unroll
            for (int reg = 0; reg < 4; ++reg) {
                float v = ahh[mi][ni][reg] + (ahl[mi][ni][reg] + alh[mi][ni][reg]) * (1.f / 4096.f) + bv;
                if (RELU) v = fmaxf(v, 0.f);
                int pix = wm * 32 + mi * 16 + g * 4 + reg;
                int oy = (tyi << 3) + (pix >> 3), ox = (txi << 3) + (pix & 7);
                int idx = ((n * OH + oy) * OW + ox) * OCT + oc;
                f16 hh = (f16)v;
                Oh[idx] = __builtin_bit_cast(u16, hh);
                Ol[idx] = f2h((v - (float)hh) * 4096.f);
            }
        }
}

// ============================ quantize v4: A-in-registers, B via LDS double-buffer ============================
// 512 blocks x 128 rows; wave owns 32 rows (2 mi), A (both planes) in VGPRs.
// B (codebook frags) staged cooperatively: 32-col chunks, 32 KB/chunk, double-buffered.
__launch_bounds__(256, 2)
__global__ void quant_k(const u16* __restrict__ zh, const u16* __restrict__ zl,
                        const u16* __restrict__ cbf, const float* __restrict__ cbn,
                        const float* __restrict__ cb, u16* __restrict__ e,
                        float* __restrict__ diff) {
    __shared__ u16 Bbuf[2 * 32 * 512];     // [buf][ks*4+pl*2+nf][lane*8]
    __shared__ float cbn_l[1024];
    __shared__ float zn_l[128];
    __shared__ float bd_l[128];
    __shared__ int   wi_l[128];

    int t = threadIdx.x, l = t & 63, wv = t >> 6, g = l >> 4;
    int bi = blockIdx.x;
    int row0 = bi << 7;

    // cbn -> LDS
    {
        f32x4 v = *(const f32x4*)&cbn[t * 4];
        *(f32x4*)&cbn_l[t * 4] = v;
    }

    // ---- A (32 rows/wave, both planes) into registers ----
    f16x8 Ah[2][8], Al[2][8];
    int rbase = row0 + wv * 32 + (l & 15);
    #pragma unroll
    for (int mi = 0; mi < 2; ++mi)
        #pragma unroll
        for (int ks = 0; ks < 8; ++ks) {
            size_t off = (size_t)(rbase + mi * 16) * 256 + ks * 32 + g * 8;
            Ah[mi][ks] = *(const f16x8*)&zh[off];
            Al[mi][ks] = *(const f16x8*)&zl[off];
        }

    // ---- per-row ||z||^2 from registers ----
    #pragma unroll
    for (int mi = 0; mi < 2; ++mi) {
        float s = 0.f;
        #pragma unroll
        for (int ks = 0; ks < 8; ++ks)
            #pragma unroll
            for (int j = 0; j < 8; ++j) {
                float v = (float)Ah[mi][ks][j] + (float)Al[mi][ks][j] * (1.f / 4096.f);
                s = fmaf(v, v, s);
            }
        s += __shfl_xor(s, 16);
        s += __shfl_xor(s, 32);
        if (g == 0) zn_l[wv * 32 + mi * 16 + (l & 15)] = s;
    }

    float rd[8]; int rc[8];
    #pragma unroll
    for (int s = 0; s < 8; ++s) { rd[s] = 1e30f; rc[s] = 0; }

    // ---- stage chunk 0 ----
    int fi = wv * 8;   // this wave stages fragments fi..fi+7
    {
        int no0 = bi & 31;
        #pragma unroll
        for (int q = 0; q < 8; ++q) {
            int f2 = fi + q;
            int ks = f2 >> 2, pl = (f2 >> 1) & 1, nf = f2 & 1;
            f16x8 v = *(const f16x8*)&cbf[(size_t)(((ks * 2 + pl) * 64) + no0 * 2 + nf) * 512 + l * 8];
            *(uint4*)&Bbuf[(size_t)f2 * 512 + l * 8] = __builtin_bit_cast(uint4, v);
        }
    }
    __syncthreads();

    for (int noi = 0; noi < 32; ++noi) {
        int b = noi & 1;
        int no_cur = (noi + bi) & 31;

        // prefetch next chunk's fragments into registers
        f16x8 pf[8];
        if (noi < 31) {
            int no_n = (noi + 1 + bi) & 31;
            #pragma unroll
            for (int q = 0; q < 8; ++q) {
                int f2 = fi + q;
                int ks = f2 >> 2, pl = (f2 >> 1) & 1, nf = f2 & 1;
                pf[q] = *(const f16x8*)&cbf[(size_t)(((ks * 2 + pl) * 64) + no_n * 2 + nf) * 512 + l * 8];
            }
        }

        // ---- compute: 96 MFMAs from Bbuf[b] ----
        f32x4 acc0[2][2], acc1[2][2];
        f32x4 z4 = {0.f, 0.f, 0.f, 0.f};
        #pragma unroll
        for (int mi = 0; mi < 2; ++mi)
            #pragma unroll
            for (int nf = 0; nf < 2; ++nf) { acc0[mi][nf] = z4; acc1[mi][nf] = z4; }

        #pragma unroll
        for (int ks = 0; ks < 8; ++ks) {
            const u16* bb = &Bbuf[(size_t)(b * 32 + ks * 4) * 512 + l * 8];
            f16x8 Bh0 = *(const f16x8*)&bb[0 * 512];
            f16x8 Bh1 = *(const f16x8*)&bb[1 * 512];
            f16x8 Bl0 = *(const f16x8*)&bb[2 * 512];
            f16x8 Bl1 = *(const f16x8*)&bb[3 * 512];
            #pragma unroll
            for (int mi = 0; mi < 2; ++mi) {
                acc0[mi][0] = __builtin_amdgcn_mfma_f32_16x16x32_f16(Ah[mi][ks], Bh0, acc0[mi][0], 0, 0, 0);
                acc0[mi][1] = __builtin_amdgcn_mfma_f32_16x16x32_f16(Ah[mi][ks], Bh1, acc0[mi][1], 0, 0, 0);
                acc1[mi][0] = __builtin_amdgcn_mfma_f32_16x16x32_f16(Ah[mi][ks], Bl0, acc1[mi][0], 0, 0, 0);
                acc1[mi][0] = __builtin_amdgcn_mfma_f32_16x16x32_f16(Al[mi][ks], Bh0, acc1[mi][0], 0, 0, 0);
                acc1[mi][1] = __builtin_amdgcn_mfma_f32_16x16x32_f16(Ah[mi][ks], Bl1, acc1[mi][1], 0, 0, 0);
                acc1[mi][1] = __builtin_amdgcn_mfma_f32_16x16x32_f16(Al[mi][ks], Bh1, acc1[mi][1], 0, 0, 0);
            }
        }

        // ---- flush argmin for this 32-col chunk ----
        #pragma unroll
        for (int nf = 0; nf < 2; ++nf) {
            int col = no_cur * 32 + nf * 16 + (l & 15);
            float cn = cbn_l[col];
            #pragma unroll
            for (int mi = 0; mi < 2; ++mi)
                #pragma unroll
                for (int reg = 0; reg < 4; ++reg) {
                    float d = cn - 2.f * (acc0[mi][nf][reg] + acc1[mi][nf][reg] * (1.f / 4096.f));
                    int slot = mi * 4 + reg;
                    if (d < rd[slot] || (d == rd[slot] && col < rc[slot])) { rd[slot] = d; rc[slot] = col; }
                }
        }

        // ---- publish next chunk ----
        if (noi < 31) {
            #pragma unroll
            for (int q = 0; q < 8; ++q)
                *(uint4*)&Bbuf[(size_t)((1 - b) * 32 + fi + q) * 512 + l * 8] = __builtin_bit_cast(uint4, pf[q]);
        }
        __syncthreads();
    }

    // ---- wave-private reduction over the 16 col-lanes ----
    #pragma unroll
    for (int step = 1; step < 16; step <<= 1) {
        #pragma unroll
        for (int s = 0; s < 8; ++s) {
            float od = __shfl_xor(rd[s], step);
            int ocl = __shfl_xor(rc[s], step);
            if (od < rd[s] || (od == rd[s] && ocl < rc[s])) { rd[s] = od; rc[s] = ocl; }
        }
    }
    if ((l & 15) == 0) {
        #pragma unroll
        for (int s = 0; s < 8; ++s) {
            int mi = s >> 2, reg = s & 3;
            int row = wv * 32 + mi * 16 + g * 4 + reg;
            bd_l[row] = rd[s]; wi_l[row] = rc[s];
        }
    }
    __syncthreads();
    if (t < 64) {
        float dval = (zn_l[t] + bd_l[t]) + (zn_l[t + 64] + bd_l[t + 64]);
        #pragma unroll
        for (int step = 1; step < 64; step <<= 1) dval += __shfl_xor(dval, step);
        if (t == 0) atomicAdd(diff, dval * (1.f / 16777216.f));
    }
    __syncthreads();
    for (int r = 0; r < 128; ++r) {
        int wi = wi_l[r];
        e[(size_t)(row0 + r) * 256 + t] = f2h(cb[wi * 256 + t]);
    }
}

// ============================ plain-fp16 MFMA deconv k4 s2 p1 (per-parity) ============================
template<int ICT>
__launch_bounds__(256)
__global__ void deconv4_k(const u16* __restrict__ in, const u16* __restrict__ wdf,
                          const float* __restrict__ bias, u16* __restrict__ out,
                          int IH, int IW) {
    constexpr int RST = 40;
    constexpr int ICC = ICT / 32;
    constexpr int PLSZ = 81 * RST;
    __shared__ u16 patch[PLSZ];

    int t = threadIdx.x, l = t & 63, wv = t >> 6;
    int wm = wv >> 1, wn = wv & 1, g = l >> 4;

    int bi = blockIdx.x;
    int par = bi & 3; int ry = par >> 1, rx = par & 1;
    int rest = bi >> 2;
    int tw = IW >> 3, th = IH >> 3;
    int txi = rest % tw; rest /= tw;
    int tyi = rest % th; int n = rest / th;
    int a0 = tyi << 3, b0 = txi << 3;
    int by0 = ry ? 0 : -1, bx0 = rx ? 0 : -1;
    int OH = IH << 1, OW = IW << 1;

    int pb0[2];
    #pragma unroll
    for (int mi = 0; mi < 2; ++mi) {
        int m = wm * 32 + mi * 16 + (l & 15);
        int pa = m >> 3, pb_ = m & 7;
        pb0[mi] = (pa * 9 + pb_) * RST + g * 8;
    }

    f32x4 acc[2][2];
    f32x4 z4 = {0.f, 0.f, 0.f, 0.f};
    #pragma unroll
    for (int mi = 0; mi < 2; ++mi)
        #pragma unroll
        for (int ni = 0; ni < 2; ++ni) acc[mi][ni] = z4;

    for (int icci = 0; icci < ICC; ++icci) {
        int icc = (icci + (bi >> 2)) & (ICC - 1);
        __syncthreads();
        for (int i = t; i < 324; i += 256) {
            int c = i & 3; int pp = i >> 2;
            int pr = pp / 9, pc = pp - pr * 9;
            int ar = a0 + by0 + pr, ac = b0 + bx0 + pc;
            uint4 v = make_uint4(0u, 0u, 0u, 0u);
            if ((unsigned)ar < (unsigned)IH && (unsigned)ac < (unsigned)IW)
                v = *(const uint4*)&in[((n * IH + ar) * IW + ac) * ICT + icc * 32 + c * 8];
            *(uint4*)&patch[(pr * 9 + pc) * RST + c * 8] = v;
        }
        __syncthreads();
        #pragma unroll
        for (int tti = 0; tti < 4; ++tti) {
            int tt = (tti + bi) & 3;
            int tty = tt >> 1, ttx = tt & 1;
            int ky = 1 - ry + 2 * tty, kx = 1 - rx + 2 * ttx;
            int tap = ky * 4 + kx;
            int shift = ((1 - tty) * 9 + (1 - ttx)) * RST;
            f16x8 B[2];
            #pragma unroll
            for (int ni = 0; ni < 2; ++ni)
                B[ni] = *(const f16x8*)&wdf[(size_t)((tap * ICC + icc) * 4 + wn * 2 + ni) * 512 + l * 8];
            #pragma unroll
            for (int mi = 0; mi < 2; ++mi) {
                f16x8 a = *(const f16x8*)&patch[pb0[mi] + shift];
                #pragma unroll
                for (int ni = 0; ni < 2; ++ni)
                    acc[mi][ni] = __builtin_amdgcn_mfma_f32_16x16x32_f16(a, B[ni], acc[mi][ni], 0, 0, 0);
            }
        }
    }
    #pragma unroll
    for (int mi = 0; mi < 2; ++mi)
        #pragma unroll
        for (int ni = 0; ni < 2; ++ni) {
            int oc = wn * 32 + ni * 16 + (l & 15);
            float bv = bias[oc];
            #pragma unroll
            for (int reg = 0; reg < 4; ++reg) {
                float v = fmaxf(acc[mi][ni][reg] + bv, 0.f);
                int pix = wm * 32 + mi * 16 + g * 4 + reg;
                int oy = ((a0 + (pix >> 3)) << 1) + ry;
                int ox = ((b0 + (pix & 7)) << 1) + rx;
                out[((n * OH + oy) * OW + ox) * 64 + oc] = f2h(v);
            }
        }
}

// ============================ final conv 3x3 64->1, p1, tanh (LDS-tiled, v_dot2) ============================
__launch_bounds__(256)
__global__ void conv3x3_tanh_k(const u16* __restrict__ in, const float* __restrict__ w,
                               const float* __restrict__ b, float* __restrict__ out) {
    __shared__ u16 tile[18 * 18 * 72];
    __shared__ u32 wpk[288];   // [tap][icp] half2-packed weights
    int t = threadIdx.x;
    int bi = blockIdx.x;
    int n = bi >> 6;
    int tile6 = bi & 63;
    int ty0 = (tile6 >> 3) << 4, tx0 = (tile6 & 7) << 4;

    for (int i = t; i < 288; i += 256) {
        int tap = i >> 5, icp = i & 31;
        h2 p;
        p.x = (f16)w[(2 * icp) * 9 + tap];
        p.y = (f16)w[(2 * icp + 1) * 9 + tap];
        wpk[tap * 32 + icp] = __builtin_bit_cast(u32, p);
    }
    for (int i = t; i < 2592; i += 256) {
        int ch = i & 7, pix = i >> 3;
        int pr = pix / 18, pc = pix - pr * 18;
        int gy = ty0 - 1 + pr, gx = tx0 - 1 + pc;
        uint4 v = make_uint4(0u, 0u, 0u, 0u);
        if ((unsigned)gy < 128u && (unsigned)gx < 128u)
            v = *(const uint4*)&in[(((n << 7) + gy) * 128 + gx) * 64 + ch * 8];
        *(uint4*)&tile[pix * 72 + ch * 8] = v;
    }
    __syncthreads();

    int ty = t >> 4, tx = t & 15;
    float acc = b[0];
    #pragma unroll
    for (int dy = 0; dy < 3; ++dy) {
        #pragma unroll
        for (int dx = 0; dx < 3; ++dx) {
            int base = ((ty + dy) * 18 + (tx + dx)) * 72;
            const u32* wp = &wpk[(dy * 3 + dx) * 32];
            #pragma unroll
            for (int c8 = 0; c8 < 8; ++c8) {
                uint4 v = *(const uint4*)&tile[base + c8 * 8];
                acc = __builtin_amdgcn_fdot2(__builtin_bit_cast(h2, v.x),
                        __builtin_bit_cast(h2, wp[c8 * 4 + 0]), acc, false);
                acc = __builtin_amdgcn_fdot2(__builtin_bit_cast(h2, v.y),
                        __builtin_bit_cast(h2, wp[c8 * 4 + 1]), acc, false);
                acc = __builtin_amdgcn_fdot2(__builtin_bit_cast(h2, v.z),
                        __builtin_bit_cast(h2, wp[c8 * 4 + 2]), acc, false);
                acc = __builtin_amdgcn_fdot2(__builtin_bit_cast(h2, v.w),
                        __builtin_bit_cast(h2, wp[c8 * 4 + 3]), acc, false);
            }
        }
    }
    int oy = ty0 + ty, ox = tx0 + tx;
    out[(n << 14) + (oy << 7) + ox] = tanhf(acc);
}

extern "C" void kernel_launch(void* const* d_in, const int* in_sizes, int n_in,
                              void* d_out, int out_size, void* d_ws, size_t ws_size,
                              hipStream_t stream) {
    (void)in_sizes; (void)n_in; (void)out_size; (void)ws_size;
    const float* x   = (const float*)d_in[0];
    const float* ew1 = (const float*)d_in[1];
    const float* eb1 = (const float*)d_in[2];
    const float* ew2 = (const float*)d_in[3];
    const float* eb2 = (const float*)d_in[4];
    const float* ew3 = (const float*)d_in[5];
    const float* eb3 = (const float*)d_in[6];
    const float* cb  = (const float*)d_in[7];
    const float* dw1 = (const float*)d_in[8];
    const float* db1 = (const float*)d_in[9];
    const float* dw2 = (const float*)d_in[10];
    const float* db2 = (const float*)d_in[11];
    const float* dw3 = (const float*)d_in[12];
    const float* db3 = (const float*)d_in[13];
    float* out = (float*)d_out;

    u16* ws = (u16*)d_ws;
    u16* a1h = ws;             u16* a1l = ws + 16777216;
    u16* zh  = ws;             u16* zl  = ws + 16777216;
    u16* a2h = ws + 33554432;  u16* a2l = ws + 50331648;
    u16* e   = ws + 33554432;
    u16* y1  = ws + 67108864;
    u16* y2  = ws;
    u16* wBf2 = ws + 83886080;          // 204800
    u16* wBf3 = wBf2 + 204800;          // 819200
    u16* wd1f = wBf3 + 819200;          // 262144
    u16* wd2f = wd1f + 262144;          // 65536
    u16* cbf  = wd2f + 65536;           // 524288
    float* cbn = (float*)(cbf + 524288);

    hipMemsetAsync(out + 1048576, 0, 4, stream);  // diff accumulator

    prep_wconv_k<<<800, 256, 0, stream>>>(ew2, wBf2, 2);   // NF=4
    prep_wconv_k<<<3200, 256, 0, stream>>>(ew3, wBf3, 4);  // NF=16
    prep_wdec_k<<<1024, 256, 0, stream>>>(dw1, wd1f, 3);   // ICC=8
    prep_wdec_k<<<256, 256, 0, stream>>>(dw2, wd2f, 1);    // ICC=2
    prep_cb_k<<<2048, 256, 0, stream>>>(cb, cbf);
    prep_cbn_k<<<4, 256, 0, stream>>>(cb, cbn);

    conv1_k<<<1024, 256, 0, stream>>>(x, ew1, eb1, a1h, a1l);
    conv5_k<1, 64, 2, true><<<4096, 256, 0, stream>>>(a1h, a1l, wBf2, eb2, a2h, a2l, 64, 64, 64, 64);
    conv5_k<2, 256, 4, false><<<2048, 256, 0, stream>>>(a2h, a2l, wBf3, eb3, zh, zl, 64, 64, 32, 32);
    quant_k<<<512, 256, 0, stream>>>(zh, zl, cbf, cbn, cb, e, out + 1048576);
    deconv4_k<256><<<4096, 256, 0, stream>>>(e, wd1f, db1, y1, 32, 32);
    deconv4_k<64><<<16384, 256, 0, stream>>>(y1, wd2f, db2, y2, 64, 64);
    conv3x3_tanh_k<<<4096, 256, 0, stream>>>(y2, dw3, db3, out);
}

// Round 8
// 735.113 us; speedup vs baseline: 1.2937x; 1.0347x over previous
//
#include <hip/hip_runtime.h>

typedef _Float16 f16;
typedef _Float16 f16x8 __attribute__((ext_vector_type(8)));
typedef _Float16 f16x4 __attribute__((ext_vector_type(4)));
typedef _Float16 h2 __attribute__((ext_vector_type(2)));
typedef float f32x4 __attribute__((ext_vector_type(4)));
typedef unsigned short u16;
typedef unsigned int u32;

#define DEVI __device__ __forceinline__

DEVI u16 f2h(float f) { f16 h = (f16)f; return __builtin_bit_cast(u16, h); }
DEVI float h2f(u16 u) { f16 h = __builtin_bit_cast(f16, u); return (float)h; }

// ============================ weight prep ============================
// conv weights (OCT,64,5,5) -> frag-ordered fp16 split planes:
// dst[((tap*4 + icc*2 + pl)*NF + f)*512 + lane*8 + j]
__launch_bounds__(256)
__global__ void prep_wconv_k(const float* __restrict__ src, u16* __restrict__ dst, int nf_sh) {
    int i = blockIdx.x * 256 + threadIdx.x;
    int j = i & 7, lane = (i >> 3) & 63;
    int q = i >> 9;
    int f = q & ((1 << nf_sh) - 1); q >>= nf_sh;
    int pl = q & 1; q >>= 1;
    int icc = q & 1; int tap = q >> 1;
    int oc = (f << 4) + (lane & 15);
    int ic = icc * 32 + ((lane >> 4) << 3) + j;
    float w = src[(oc * 64 + ic) * 25 + tap];
    if (pl == 0) dst[i] = f2h(w);
    else         dst[i] = f2h((w - h2f(f2h(w))) * 4096.f);
}
// deconv weights (ICT,64,4,4) -> plain fp16 frag order
__launch_bounds__(256)
__global__ void prep_wdec_k(const float* __restrict__ src, u16* __restrict__ dst, int icc_sh) {
    int i = blockIdx.x * 256 + threadIdx.x;
    int j = i & 7, lane = (i >> 3) & 63;
    int f = (i >> 9) & 3;
    int q = i >> 11;
    int icc = q & ((1 << icc_sh) - 1); int tap = q >> icc_sh;
    int oc = (f << 4) + (lane & 15);
    int ic = icc * 32 + ((lane >> 4) << 3) + j;
    dst[i] = f2h(src[(ic * 64 + oc) * 16 + tap]);
}
// codebook (1024,256) -> split fp16 frag order
__launch_bounds__(256)
__global__ void prep_cb_k(const float* __restrict__ cb, u16* __restrict__ dst) {
    int i = blockIdx.x * 256 + threadIdx.x;   // 524288
    int j = i & 7, lane = (i >> 3) & 63;
    int f = (i >> 9) & 63;
    int q = i >> 15;
    int pl = q & 1; int ks = q >> 1;
    int n = (f << 4) + (lane & 15);
    int k = ks * 32 + ((lane >> 4) << 3) + j;
    float w = cb[n * 256 + k];
    if (pl == 0) dst[i] = f2h(w);
    else         dst[i] = f2h((w - h2f(f2h(w))) * 4096.f);
}
__launch_bounds__(256)
__global__ void prep_cbn_k(const float* __restrict__ cb, float* __restrict__ cbn) {
    int row = blockIdx.x * 256 + threadIdx.x;          // 1024
    float s = 0.f;
    for (int c = 0; c < 256; c += 4) {
        f32x4 v = *(const f32x4*)&cb[row * 256 + c];
        s = fmaf(v.x, v.x, s); s = fmaf(v.y, v.y, s);
        s = fmaf(v.z, v.z, s); s = fmaf(v.w, v.w, s);
    }
    cbn[row] = s;
}

// ============================ conv1: 1->64, 5x5 s2 p2, relu, split-fp16 out ============================
__launch_bounds__(256)
__global__ void conv1_k(const float* __restrict__ x, const float* __restrict__ w,
                        const float* __restrict__ b, u16* __restrict__ oh, u16* __restrict__ ol) {
    __shared__ float wl[25 * 64];
    __shared__ float bl[64];
    int t = threadIdx.x;
    for (int i = t; i < 1600; i += 256) wl[(i % 25) * 64 + i / 25] = w[i];
    if (t < 64) bl[t] = b[t];
    __syncthreads();
    int p = blockIdx.x * 256 + t;                       // 262144 pixels
    int ox = p & 63, oy = (p >> 6) & 63, n = p >> 12;
    f32x4 acc[16];
    #pragma unroll
    for (int c = 0; c < 16; ++c) acc[c] = *(f32x4*)&bl[c * 4];
    for (int dy = 0; dy < 5; ++dy) {
        int iy = 2 * oy - 2 + dy;
        if ((unsigned)iy >= 128u) continue;
        for (int dx = 0; dx < 5; ++dx) {
            int ix = 2 * ox - 2 + dx;
            if ((unsigned)ix >= 128u) continue;
            float v = x[(n * 128 + iy) * 128 + ix];
            const float* wp = &wl[(dy * 5 + dx) * 64];
            #pragma unroll
            for (int c = 0; c < 16; ++c) {
                f32x4 w4 = *(const f32x4*)&wp[c * 4];
                acc[c].x = fmaf(v, w4.x, acc[c].x); acc[c].y = fmaf(v, w4.y, acc[c].y);
                acc[c].z = fmaf(v, w4.z, acc[c].z); acc[c].w = fmaf(v, w4.w, acc[c].w);
            }
        }
    }
    #pragma unroll
    for (int c = 0; c < 16; ++c) {
        ushort4 uh, ul;
        float vv[4] = {acc[c].x, acc[c].y, acc[c].z, acc[c].w};
        u16 rh[4], rl[4];
        #pragma unroll
        for (int k = 0; k < 4; ++k) {
            float v = fmaxf(vv[k], 0.f);
            f16 hh = (f16)v;
            rh[k] = __builtin_bit_cast(u16, hh);
            rl[k] = f2h((v - (float)hh) * 4096.f);
        }
        uh.x = rh[0]; uh.y = rh[1]; uh.z = rh[2]; uh.w = rh[3];
        ul.x = rl[0]; ul.y = rl[1]; ul.z = rl[2]; ul.w = rl[3];
        *(ushort4*)&oh[p * 64 + c * 4] = uh;
        *(ushort4*)&ol[p * 64 + c * 4] = ul;
    }
}

// ============================ split-fp16 MFMA 5x5 conv, B software-pipelined ============================
// LDS: pixel pair P=pp>>1 owns a 64-half line; chunk c of parity r at slot (P+2c+r)&7.
// B fragments register-double-buffered over the tap loop (affine pointer + wrap).
template<int S, int OCT, int NI, bool RELU>
__launch_bounds__(256)
__global__ void conv5_k(const u16* __restrict__ Ah_g, const u16* __restrict__ Al_g,
                        const u16* __restrict__ wBf, const float* __restrict__ bias,
                        u16* __restrict__ Oh, u16* __restrict__ Ol,
                        int IH, int IW, int OH, int OW) {
    constexpr int PATCH = 7 * S + 5;
    constexpr int NPIX = PATCH * PATCH;
    constexpr int NPAIR = (NPIX + 1) / 2;
    constexpr int PLSZ = NPAIR * 64;
    constexpr int NF = OCT / 16;
    constexpr int BN = NI * 32;
    constexpr int OCB = OCT / BN;
    __shared__ u16 patch[2 * PLSZ];

    int t = threadIdx.x, l = t & 63, wv = t >> 6;
    int wm = wv >> 1, wn = wv & 1, g = l >> 4;

    int bi = blockIdx.x;
    int ocb = bi % OCB; int rest = bi / OCB;
    int tw = OW >> 3, th = OH >> 3;
    int txi = rest % tw; rest /= tw;
    int tyi = rest % th; int n = rest / th;
    int iy0 = S * (tyi << 3) - 2, ix0 = S * (txi << 3) - 2;

    int ppb[2];
    #pragma unroll
    for (int mi = 0; mi < 2; ++mi) {
        int m = wm * 32 + mi * 16 + (l & 15);
        int py = m >> 3, px = m & 7;
        ppb[mi] = (S * py) * PATCH + S * px;
    }

    f32x4 acc0[2][NI], acc1[2][NI];
    f32x4 z4 = {0.f, 0.f, 0.f, 0.f};
    #pragma unroll
    for (int mi = 0; mi < 2; ++mi)
        #pragma unroll
        for (int ni = 0; ni < NI; ++ni) { acc0[mi][ni] = z4; acc1[mi][ni] = z4; }

    int tap0 = bi % 25;
    int dy0 = tap0 / 5, dx0 = tap0 - 5 * dy0;
    int iccr = bi & 1;
    int fg = ocb * (BN / 16) + wn * NI;
    const size_t tstride = (size_t)(4 * NF) * 512;

    for (int icci = 0; icci < 2; ++icci) {
        int icc = icci ^ iccr;
        __syncthreads();
        for (int i = t; i < NPIX * 8; i += 256) {
            int c = i & 3; int r2 = i >> 2;
            int pl = (r2 >= NPIX); int pp = r2 - pl * NPIX;
            int py = pp / PATCH, px = pp - py * PATCH;
            int iy = iy0 + py, ix = ix0 + px;
            uint4 v = make_uint4(0u, 0u, 0u, 0u);
            if ((unsigned)iy < (unsigned)IH && (unsigned)ix < (unsigned)IW)
                v = *(const uint4*)&(pl ? Al_g : Ah_g)[(((n * IH + iy) * IW + ix)) * 64 + icc * 32 + c * 8];
            int P = pp >> 1, r = pp & 1;
            *(uint4*)&patch[pl * PLSZ + (P << 6) + (((P + (c << 1) + r) & 7) << 3)] = v;
        }
        __syncthreads();

        const u16* pB = wBf + (size_t)((tap0 * 4 + icc * 2) * NF + fg) * 512 + l * 8;
        f16x8 Bh0[NI], Bl0[NI], Bh1[NI], Bl1[NI];
        #pragma unroll
        for (int ni = 0; ni < NI; ++ni) {
            Bh0[ni] = *(const f16x8*)&pB[ni * 512];
            Bl0[ni] = *(const f16x8*)&pB[(NF + ni) * 512];
        }
        int tap = tap0, dy = dy0, dx = dx0;
        int tadd = dy0 * PATCH + dx0;
        for (int tapi = 0; tapi < 25; ++tapi) {
            const u16* pBn = (tap == 24) ? (pB - 24 * tstride) : (pB + tstride);
            if (tapi < 24) {
                #pragma unroll
                for (int ni = 0; ni < NI; ++ni) {
                    Bh1[ni] = *(const f16x8*)&pBn[ni * 512];
                    Bl1[ni] = *(const f16x8*)&pBn[(NF + ni) * 512];
                }
            }
            #pragma unroll
            for (int mi = 0; mi < 2; ++mi) {
                int pp = ppb[mi] + tadd;
                int P = pp >> 1, r = pp & 1;
                int offs = (P << 6) + (((P + (g << 1) + r) & 7) << 3);
                f16x8 ah = *(const f16x8*)&patch[offs];
                f16x8 al = *(const f16x8*)&patch[PLSZ + offs];
                #pragma unroll
                for (int ni = 0; ni < NI; ++ni) {
                    acc0[mi][ni] = __builtin_amdgcn_mfma_f32_16x16x32_f16(ah, Bh0[ni], acc0[mi][ni], 0, 0, 0);
                    acc1[mi][ni] = __builtin_amdgcn_mfma_f32_16x16x32_f16(ah, Bl0[ni], acc1[mi][ni], 0, 0, 0);
                    acc1[mi][ni] = __builtin_amdgcn_mfma_f32_16x16x32_f16(al, Bh0[ni], acc1[mi][ni], 0, 0, 0);
                }
            }
            #pragma unroll
            for (int ni = 0; ni < NI; ++ni) { Bh0[ni] = Bh1[ni]; Bl0[ni] = Bl1[ni]; }
            pB = pBn;
            tap = (tap == 24) ? 0 : tap + 1;
            if (tap == 0) { dy = 0; dx = 0; tadd = 0; }
            else {
                dx++; tadd++;
                if (dx == 5) { dx = 0; dy++; tadd += PATCH - 5; }
            }
        }
    }
    #pragma unroll
    for (int mi = 0; mi < 2; ++mi)
        #pragma unroll
        for (int ni = 0; ni < NI; ++ni) {
            int oc = ocb * BN + wn * (NI * 16) + ni * 16 + (l & 15);
            float bv = bias[oc];
            #pragma unroll
            for (int reg = 0; reg < 4; ++reg) {
                float v = acc0[mi][ni][reg] + acc1[mi][ni][reg] * (1.f / 4096.f) + bv;
                if (RELU) v = fmaxf(v, 0.f);
                int pix = wm * 32 + mi * 16 + g * 4 + reg;
                int oy = (tyi << 3) + (pix >> 3), ox = (txi << 3) + (pix & 7);
                int idx = ((n * OH + oy) * OW + ox) * OCT + oc;
                f16 hh = (f16)v;
                Oh[idx] = __builtin_bit_cast(u16, hh);
                Ol[idx] = f2h((v - (float)hh) * 4096.f);
            }
        }
}

// ============================ quantize v4: A-in-registers, B via LDS double-buffer ============================
__launch_bounds__(256, 2)
__global__ void quant_k(const u16* __restrict__ zh, const u16* __restrict__ zl,
                        const u16* __restrict__ cbf, const float* __restrict__ cbn,
                        const float* __restrict__ cb, u16* __restrict__ e,
                        float* __restrict__ diff) {
    __shared__ u16 Bbuf[2 * 32 * 512];     // [buf][ks*4+pl*2+nf][lane*8]
    __shared__ float cbn_l[1024];
    __shared__ float zn_l[128];
    __shared__ float bd_l[128];
    __shared__ int   wi_l[128];

    int t = threadIdx.x, l = t & 63, wv = t >> 6, g = l >> 4;
    int bi = blockIdx.x;
    int row0 = bi << 7;

    {
        f32x4 v = *(const f32x4*)&cbn[t * 4];
        *(f32x4*)&cbn_l[t * 4] = v;
    }

    f16x8 Ah[2][8], Al[2][8];
    int rbase = row0 + wv * 32 + (l & 15);
    #pragma unroll
    for (int mi = 0; mi < 2; ++mi)
        #pragma unroll
        for (int ks = 0; ks < 8; ++ks) {
            size_t off = (size_t)(rbase + mi * 16) * 256 + ks * 32 + g * 8;
            Ah[mi][ks] = *(const f16x8*)&zh[off];
            Al[mi][ks] = *(const f16x8*)&zl[off];
        }

    #pragma unroll
    for (int mi = 0; mi < 2; ++mi) {
        float s = 0.f;
        #pragma unroll
        for (int ks = 0; ks < 8; ++ks)
            #pragma unroll
            for (int j = 0; j < 8; ++j) {
                float v = (float)Ah[mi][ks][j] + (float)Al[mi][ks][j] * (1.f / 4096.f);
                s = fmaf(v, v, s);
            }
        s += __shfl_xor(s, 16);
        s += __shfl_xor(s, 32);
        if (g == 0) zn_l[wv * 32 + mi * 16 + (l & 15)] = s;
    }

    float rd[8]; int rc[8];
    #pragma unroll
    for (int s = 0; s < 8; ++s) { rd[s] = 1e30f; rc[s] = 0; }

    int fi = wv * 8;
    {
        int no0 = bi & 31;
        #pragma unroll
        for (int q = 0; q < 8; ++q) {
            int f2 = fi + q;
            int ks = f2 >> 2, pl = (f2 >> 1) & 1, nf = f2 & 1;
            f16x8 v = *(const f16x8*)&cbf[(size_t)(((ks * 2 + pl) * 64) + no0 * 2 + nf) * 512 + l * 8];
            *(uint4*)&Bbuf[(size_t)f2 * 512 + l * 8] = __builtin_bit_cast(uint4, v);
        }
    }
    __syncthreads();

    for (int noi = 0; noi < 32; ++noi) {
        int b = noi & 1;
        int no_cur = (noi + bi) & 31;

        f16x8 pf[8];
        if (noi < 31) {
            int no_n = (noi + 1 + bi) & 31;
            #pragma unroll
            for (int q = 0; q < 8; ++q) {
                int f2 = fi + q;
                int ks = f2 >> 2, pl = (f2 >> 1) & 1, nf = f2 & 1;
                pf[q] = *(const f16x8*)&cbf[(size_t)(((ks * 2 + pl) * 64) + no_n * 2 + nf) * 512 + l * 8];
            }
        }

        f32x4 acc0[2][2], acc1[2][2];
        f32x4 z4 = {0.f, 0.f, 0.f, 0.f};
        #pragma unroll
        for (int mi = 0; mi < 2; ++mi)
            #pragma unroll
            for (int nf = 0; nf < 2; ++nf) { acc0[mi][nf] = z4; acc1[mi][nf] = z4; }

        #pragma unroll
        for (int ks = 0; ks < 8; ++ks) {
            const u16* bb = &Bbuf[(size_t)(b * 32 + ks * 4) * 512 + l * 8];
            f16x8 Bh0 = *(const f16x8*)&bb[0 * 512];
            f16x8 Bh1 = *(const f16x8*)&bb[1 * 512];
            f16x8 Bl0 = *(const f16x8*)&bb[2 * 512];
            f16x8 Bl1 = *(const f16x8*)&bb[3 * 512];
            #pragma unroll
            for (int mi = 0; mi < 2; ++mi) {
                acc0[mi][0] = __builtin_amdgcn_mfma_f32_16x16x32_f16(Ah[mi][ks], Bh0, acc0[mi][0], 0, 0, 0);
                acc0[mi][1] = __builtin_amdgcn_mfma_f32_16x16x32_f16(Ah[mi][ks], Bh1, acc0[mi][1], 0, 0, 0);
                acc1[mi][0] = __builtin_amdgcn_mfma_f32_16x16x32_f16(Ah[mi][ks], Bl0, acc1[mi][0], 0, 0, 0);
                acc1[mi][0] = __builtin_amdgcn_mfma_f32_16x16x32_f16(Al[mi][ks], Bh0, acc1[mi][0], 0, 0, 0);
                acc1[mi][1] = __builtin_amdgcn_mfma_f32_16x16x32_f16(Ah[mi][ks], Bl1, acc1[mi][1], 0, 0, 0);
                acc1[mi][1] = __builtin_amdgcn_mfma_f32_16x16x32_f16(Al[mi][ks], Bh1, acc1[mi][1], 0, 0, 0);
            }
        }

        #pragma unroll
        for (int nf = 0; nf < 2; ++nf) {
            int col = no_cur * 32 + nf * 16 + (l & 15);
            float cn = cbn_l[col];
            #pragma unroll
            for (int mi = 0; mi < 2; ++mi)
                #pragma unroll
                for (int reg = 0; reg < 4; ++reg) {
                    float d = cn - 2.f * (acc0[mi][nf][reg] + acc1[mi][nf][reg] * (1.f / 4096.f));
                    int slot = mi * 4 + reg;
                    if (d < rd[slot] || (d == rd[slot] && col < rc[slot])) { rd[slot] = d; rc[slot] = col; }
                }
        }

        if (noi < 31) {
            #pragma unroll
            for (int q = 0; q < 8; ++q)
                *(uint4*)&Bbuf[(size_t)((1 - b) * 32 + fi + q) * 512 + l * 8] = __builtin_bit_cast(uint4, pf[q]);
        }
        __syncthreads();
    }

    #pragma unroll
    for (int step = 1; step < 16; step <<= 1) {
        #pragma unroll
        for (int s = 0; s < 8; ++s) {
            float od = __shfl_xor(rd[s], step);
            int ocl = __shfl_xor(rc[s], step);
            if (od < rd[s] || (od == rd[s] && ocl < rc[s])) { rd[s] = od; rc[s] = ocl; }
        }
    }
    if ((l & 15) == 0) {
        #pragma unroll
        for (int s = 0; s < 8; ++s) {
            int mi = s >> 2, reg = s & 3;
            int row = wv * 32 + mi * 16 + g * 4 + reg;
            bd_l[row] = rd[s]; wi_l[row] = rc[s];
        }
    }
    __syncthreads();
    if (t < 64) {
        float dval = (zn_l[t] + bd_l[t]) + (zn_l[t + 64] + bd_l[t + 64]);
        #pragma unroll
        for (int step = 1; step < 64; step <<= 1) dval += __shfl_xor(dval, step);
        if (t == 0) atomicAdd(diff, dval * (1.f / 16777216.f));
    }
    __syncthreads();
    for (int r = 0; r < 128; ++r) {
        int wi = wi_l[r];
        e[(size_t)(row0 + r) * 256 + t] = f2h(cb[wi * 256 + t]);
    }
}

// ============================ plain-fp16 MFMA deconv k4 s2 p1, B prefetched ============================
template<int ICT>
__launch_bounds__(256)
__global__ void deconv4_k(const u16* __restrict__ in, const u16* __restrict__ wdf,
                          const float* __restrict__ bias, u16* __restrict__ out,
                          int IH, int IW) {
    constexpr int RST = 40;
    constexpr int ICC = ICT / 32;
    constexpr int PLSZ = 81 * RST;
    __shared__ u16 patch[PLSZ];

    int t = threadIdx.x, l = t & 63, wv = t >> 6;
    int wm = wv >> 1, wn = wv & 1, g = l >> 4;

    int bi = blockIdx.x;
    int par = bi & 3; int ry = par >> 1, rx = par & 1;
    int rest = bi >> 2;
    int tw = IW >> 3, th = IH >> 3;
    int txi = rest % tw; rest /= tw;
    int tyi = rest % th; int n = rest / th;
    int a0 = tyi << 3, b0 = txi << 3;
    int by0 = ry ? 0 : -1, bx0 = rx ? 0 : -1;
    int OH = IH << 1, OW = IW << 1;

    int pb0[2];
    #pragma unroll
    for (int mi = 0; mi < 2; ++mi) {
        int m = wm * 32 + mi * 16 + (l & 15);
        int pa = m >> 3, pb_ = m & 7;
        pb0[mi] = (pa * 9 + pb_) * RST + g * 8;
    }

    f32x4 acc[2][2];
    f32x4 z4 = {0.f, 0.f, 0.f, 0.f};
    #pragma unroll
    for (int mi = 0; mi < 2; ++mi)
        #pragma unroll
        for (int ni = 0; ni < 2; ++ni) acc[mi][ni] = z4;

    auto ldB = [&](int icc, int tt, f16x8* B) {
        int tty = tt >> 1, ttx = tt & 1;
        int ky = 1 - ry + 2 * tty, kx = 1 - rx + 2 * ttx;
        int tap = ky * 4 + kx;
        #pragma unroll
        for (int ni = 0; ni < 2; ++ni)
            B[ni] = *(const f16x8*)&wdf[(size_t)((tap * ICC + icc) * 4 + wn * 2 + ni) * 512 + l * 8];
    };

    f16x8 B0[2], B1[2];
    {
        int icc0 = (bi >> 2) & (ICC - 1);
        ldB(icc0, bi & 3, B0);
    }

    for (int icci = 0; icci < ICC; ++icci) {
        int icc = (icci + (bi >> 2)) & (ICC - 1);
        __syncthreads();
        for (int i = t; i < 324; i += 256) {
            int c = i & 3; int pp = i >> 2;
            int pr = pp / 9, pc = pp - pr * 9;
            int ar = a0 + by0 + pr, ac = b0 + bx0 + pc;
            uint4 v = make_uint4(0u, 0u, 0u, 0u);
            if ((unsigned)ar < (unsigned)IH && (unsigned)ac < (unsigned)IW)
                v = *(const uint4*)&in[((n * IH + ar) * IW + ac) * ICT + icc * 32 + c * 8];
            *(uint4*)&patch[(pr * 9 + pc) * RST + c * 8] = v;
        }
        __syncthreads();
        #pragma unroll
        for (int tti = 0; tti < 4; ++tti) {
            int tt = (tti + bi) & 3;
            if (!(icci == ICC - 1 && tti == 3)) {
                int nicci = (tti == 3) ? icci + 1 : icci;
                int ntti = (tti == 3) ? 0 : tti + 1;
                int nicc = (nicci + (bi >> 2)) & (ICC - 1);
                ldB(nicc, (ntti + bi) & 3, B1);
            }
            int tty = tt >> 1, ttx = tt & 1;
            int shift = ((1 - tty) * 9 + (1 - ttx)) * RST;
            #pragma unroll
            for (int mi = 0; mi < 2; ++mi) {
                f16x8 a = *(const f16x8*)&patch[pb0[mi] + shift];
                #pragma unroll
                for (int ni = 0; ni < 2; ++ni)
                    acc[mi][ni] = __builtin_amdgcn_mfma_f32_16x16x32_f16(a, B0[ni], acc[mi][ni], 0, 0, 0);
            }
            B0[0] = B1[0]; B0[1] = B1[1];
        }
    }
    #pragma unroll
    for (int mi = 0; mi < 2; ++mi)
        #pragma unroll
        for (int ni = 0; ni < 2; ++ni) {
            int oc = wn * 32 + ni * 16 + (l & 15);
            float bv = bias[oc];
            #pragma unroll
            for (int reg = 0; reg < 4; ++reg) {
                float v = fmaxf(acc[mi][ni][reg] + bv, 0.f);
                int pix = wm * 32 + mi * 16 + g * 4 + reg;
                int oy = ((a0 + (pix >> 3)) << 1) + ry;
                int ox = ((b0 + (pix & 7)) << 1) + rx;
                out[((n * OH + oy) * OW + ox) * 64 + oc] = f2h(v);
            }
        }
}

// ============================ final conv 3x3 64->1, p1, tanh (LDS-tiled, v_dot2) ============================
__launch_bounds__(256)
__global__ void conv3x3_tanh_k(const u16* __restrict__ in, const float* __restrict__ w,
                               const float* __restrict__ b, float* __restrict__ out) {
    __shared__ u16 tile[18 * 18 * 72];
    __shared__ u32 wpk[288];   // [tap][icp] half2-packed weights
    int t = threadIdx.x;
    int bi = blockIdx.x;
    int n = bi >> 6;
    int tile6 = bi & 63;
    int ty0 = (tile6 >> 3) << 4, tx0 = (tile6 & 7) << 4;

    for (int i = t; i < 288; i += 256) {
        int tap = i >> 5, icp = i & 31;
        h2 p;
        p.x = (f16)w[(2 * icp) * 9 + tap];
        p.y = (f16)w[(2 * icp + 1) * 9 + tap];
        wpk[tap * 32 + icp] = __builtin_bit_cast(u32, p);
    }
    for (int i = t; i < 2592; i += 256) {
        int ch = i & 7, pix = i >> 3;
        int pr = pix / 18, pc = pix - pr * 18;
        int gy = ty0 - 1 + pr, gx = tx0 - 1 + pc;
        uint4 v = make_uint4(0u, 0u, 0u, 0u);
        if ((unsigned)gy < 128u && (unsigned)gx < 128u)
            v = *(const uint4*)&in[(((n << 7) + gy) * 128 + gx) * 64 + ch * 8];
        *(uint4*)&tile[pix * 72 + ch * 8] = v;
    }
    __syncthreads();

    int ty = t >> 4, tx = t & 15;
    float acc = b[0];
    #pragma unroll
    for (int dy = 0; dy < 3; ++dy) {
        #pragma unroll
        for (int dx = 0; dx < 3; ++dx) {
            int base = ((ty + dy) * 18 + (tx + dx)) * 72;
            const u32* wp = &wpk[(dy * 3 + dx) * 32];
            #pragma unroll
            for (int c8 = 0; c8 < 8; ++c8) {
                uint4 v = *(const uint4*)&tile[base + c8 * 8];
                acc = __builtin_amdgcn_fdot2(__builtin_bit_cast(h2, v.x),
                        __builtin_bit_cast(h2, wp[c8 * 4 + 0]), acc, false);
                acc = __builtin_amdgcn_fdot2(__builtin_bit_cast(h2, v.y),
                        __builtin_bit_cast(h2, wp[c8 * 4 + 1]), acc, false);
                acc = __builtin_amdgcn_fdot2(__builtin_bit_cast(h2, v.z),
                        __builtin_bit_cast(h2, wp[c8 * 4 + 2]), acc, false);
                acc = __builtin_amdgcn_fdot2(__builtin_bit_cast(h2, v.w),
                        __builtin_bit_cast(h2, wp[c8 * 4 + 3]), acc, false);
            }
        }
    }
    int oy = ty0 + ty, ox = tx0 + tx;
    out[(n << 14) + (oy << 7) + ox] = tanhf(acc);
}

extern "C" void kernel_launch(void* const* d_in, const int* in_sizes, int n_in,
                              void* d_out, int out_size, void* d_ws, size_t ws_size,
                              hipStream_t stream) {
    (void)in_sizes; (void)n_in; (void)out_size; (void)ws_size;
    const float* x   = (const float*)d_in[0];
    const float* ew1 = (const float*)d_in[1];
    const float* eb1 = (const float*)d_in[2];
    const float* ew2 = (const float*)d_in[3];
    const float* eb2 = (const float*)d_in[4];
    const float* ew3 = (const float*)d_in[5];
    const float* eb3 = (const float*)d_in[6];
    const float* cb  = (const float*)d_in[7];
    const float* dw1 = (const float*)d_in[8];
    const float* db1 = (const float*)d_in[9];
    const float* dw2 = (const float*)d_in[10];
    const float* db2 = (const float*)d_in[11];
    const float* dw3 = (const float*)d_in[12];
    const float* db3 = (const float*)d_in[13];
    float* out = (float*)d_out;

    u16* ws = (u16*)d_ws;
    u16* a1h = ws;             u16* a1l = ws + 16777216;
    u16* zh  = ws;             u16* zl  = ws + 16777216;
    u16* a2h = ws + 33554432;  u16* a2l = ws + 50331648;
    u16* e   = ws + 33554432;
    u16* y1  = ws + 67108864;
    u16* y2  = ws;
    u16* wBf2 = ws + 83886080;          // 204800
    u16* wBf3 = wBf2 + 204800;          // 819200
    u16* wd1f = wBf3 + 819200;          // 262144
    u16* wd2f = wd1f + 262144;          // 65536
    u16* cbf  = wd2f + 65536;           // 524288
    float* cbn = (float*)(cbf + 524288);

    hipMemsetAsync(out + 1048576, 0, 4, stream);  // diff accumulator

    prep_wconv_k<<<800, 256, 0, stream>>>(ew2, wBf2, 2);   // NF=4
    prep_wconv_k<<<3200, 256, 0, stream>>>(ew3, wBf3, 4);  // NF=16
    prep_wdec_k<<<1024, 256, 0, stream>>>(dw1, wd1f, 3);   // ICC=8
    prep_wdec_k<<<256, 256, 0, stream>>>(dw2, wd2f, 1);    // ICC=2
    prep_cb_k<<<2048, 256, 0, stream>>>(cb, cbf);
    prep_cbn_k<<<4, 256, 0, stream>>>(cb, cbn);

    conv1_k<<<1024, 256, 0, stream>>>(x, ew1, eb1, a1h, a1l);
    conv5_k<1, 64, 2, true><<<4096, 256, 0, stream>>>(a1h, a1l, wBf2, eb2, a2h, a2l, 64, 64, 64, 64);
    conv5_k<2, 256, 4, false><<<2048, 256, 0, stream>>>(a2h, a2l, wBf3, eb3, zh, zl, 64, 64, 32, 32);
    quant_k<<<512, 256, 0, stream>>>(zh, zl, cbf, cbn, cb, e, out + 1048576);
    deconv4_k<256><<<4096, 256, 0, stream>>>(e, wd1f, db1, y1, 32, 32);
    deconv4_k<64><<<16384, 256, 0, stream>>>(y1, wd2f, db2, y2, 64, 64);
    conv3x3_tanh_k<<<4096, 256, 0, stream>>>(y2, dw3, db3, out);
}

// Round 9
// 720.560 us; speedup vs baseline: 1.3199x; 1.0202x over previous
//
#include <hip/hip_runtime.h>

typedef _Float16 f16;
typedef _Float16 f16x8 __attribute__((ext_vector_type(8)));
typedef _Float16 f16x4 __attribute__((ext_vector_type(4)));
typedef _Float16 h2 __attribute__((ext_vector_type(2)));
typedef float f32x4 __attribute__((ext_vector_type(4)));
typedef unsigned short u16;
typedef unsigned int u32;

#define DEVI __device__ __forceinline__

DEVI u16 f2h(float f) { f16 h = (f16)f; return __builtin_bit_cast(u16, h); }
DEVI float h2f(u16 u) { f16 h = __builtin_bit_cast(f16, u); return (float)h; }

// ============================ weight prep ============================
__launch_bounds__(256)
__global__ void prep_wconv_k(const float* __restrict__ src, u16* __restrict__ dst, int nf_sh) {
    int i = blockIdx.x * 256 + threadIdx.x;
    int j = i & 7, lane = (i >> 3) & 63;
    int q = i >> 9;
    int f = q & ((1 << nf_sh) - 1); q >>= nf_sh;
    int pl = q & 1; q >>= 1;
    int icc = q & 1; int tap = q >> 1;
    int oc = (f << 4) + (lane & 15);
    int ic = icc * 32 + ((lane >> 4) << 3) + j;
    float w = src[(oc * 64 + ic) * 25 + tap];
    if (pl == 0) dst[i] = f2h(w);
    else         dst[i] = f2h((w - h2f(f2h(w))) * 4096.f);
}
__launch_bounds__(256)
__global__ void prep_wdec_k(const float* __restrict__ src, u16* __restrict__ dst, int icc_sh) {
    int i = blockIdx.x * 256 + threadIdx.x;
    int j = i & 7, lane = (i >> 3) & 63;
    int f = (i >> 9) & 3;
    int q = i >> 11;
    int icc = q & ((1 << icc_sh) - 1); int tap = q >> icc_sh;
    int oc = (f << 4) + (lane & 15);
    int ic = icc * 32 + ((lane >> 4) << 3) + j;
    dst[i] = f2h(src[(ic * 64 + oc) * 16 + tap]);
}
__launch_bounds__(256)
__global__ void prep_cb_k(const float* __restrict__ cb, u16* __restrict__ dst) {
    int i = blockIdx.x * 256 + threadIdx.x;   // 524288
    int j = i & 7, lane = (i >> 3) & 63;
    int f = (i >> 9) & 63;
    int q = i >> 15;
    int pl = q & 1; int ks = q >> 1;
    int n = (f << 4) + (lane & 15);
    int k = ks * 32 + ((lane >> 4) << 3) + j;
    float w = cb[n * 256 + k];
    if (pl == 0) dst[i] = f2h(w);
    else         dst[i] = f2h((w - h2f(f2h(w))) * 4096.f);
}
__launch_bounds__(256)
__global__ void prep_cbn_k(const float* __restrict__ cb, float* __restrict__ cbn) {
    int row = blockIdx.x * 256 + threadIdx.x;          // 1024
    float s = 0.f;
    for (int c = 0; c < 256; c += 4) {
        f32x4 v = *(const f32x4*)&cb[row * 256 + c];
        s = fmaf(v.x, v.x, s); s = fmaf(v.y, v.y, s);
        s = fmaf(v.z, v.z, s); s = fmaf(v.w, v.w, s);
    }
    cbn[row] = s;
}

// ============================ conv1: 1->64, 5x5 s2 p2, relu, split-fp16 out ============================
__launch_bounds__(256)
__global__ void conv1_k(const float* __restrict__ x, const float* __restrict__ w,
                        const float* __restrict__ b, u16* __restrict__ oh, u16* __restrict__ ol) {
    __shared__ float wl[25 * 64];
    __shared__ float bl[64];
    int t = threadIdx.x;
    for (int i = t; i < 1600; i += 256) wl[(i % 25) * 64 + i / 25] = w[i];
    if (t < 64) bl[t] = b[t];
    __syncthreads();
    int p = blockIdx.x * 256 + t;                       // 262144 pixels
    int ox = p & 63, oy = (p >> 6) & 63, n = p >> 12;
    f32x4 acc[16];
    #pragma unroll
    for (int c = 0; c < 16; ++c) acc[c] = *(f32x4*)&bl[c * 4];
    for (int dy = 0; dy < 5; ++dy) {
        int iy = 2 * oy - 2 + dy;
        if ((unsigned)iy >= 128u) continue;
        for (int dx = 0; dx < 5; ++dx) {
            int ix = 2 * ox - 2 + dx;
            if ((unsigned)ix >= 128u) continue;
            float v = x[(n * 128 + iy) * 128 + ix];
            const float* wp = &wl[(dy * 5 + dx) * 64];
            #pragma unroll
            for (int c = 0; c < 16; ++c) {
                f32x4 w4 = *(const f32x4*)&wp[c * 4];
                acc[c].x = fmaf(v, w4.x, acc[c].x); acc[c].y = fmaf(v, w4.y, acc[c].y);
                acc[c].z = fmaf(v, w4.z, acc[c].z); acc[c].w = fmaf(v, w4.w, acc[c].w);
            }
        }
    }
    #pragma unroll
    for (int c = 0; c < 16; ++c) {
        ushort4 uh, ul;
        float vv[4] = {acc[c].x, acc[c].y, acc[c].z, acc[c].w};
        u16 rh[4], rl[4];
        #pragma unroll
        for (int k = 0; k < 4; ++k) {
            float v = fmaxf(vv[k], 0.f);
            f16 hh = (f16)v;
            rh[k] = __builtin_bit_cast(u16, hh);
            rl[k] = f2h((v - (float)hh) * 4096.f);
        }
        uh.x = rh[0]; uh.y = rh[1]; uh.z = rh[2]; uh.w = rh[3];
        ul.x = rl[0]; ul.y = rl[1]; ul.z = rl[2]; ul.w = rl[3];
        *(ushort4*)&oh[p * 64 + c * 4] = uh;
        *(ushort4*)&ol[p * 64 + c * 4] = ul;
    }
}

// ============================ split-fp16 MFMA 5x5 conv, hoisted staging + A pipeline ============================
// LDS: pixel pair P=pp>>1 owns a 64-half line; chunk c of parity r at slot (P+2c+r)&7.
// Staging addresses precomputed once; A fragments double-buffered one tap ahead.
template<int S, int OCT, int NI, bool RELU>
__launch_bounds__(256)
__global__ void conv5_k(const u16* __restrict__ Ah_g, const u16* __restrict__ Al_g,
                        const u16* __restrict__ wBf, const float* __restrict__ bias,
                        u16* __restrict__ Oh, u16* __restrict__ Ol,
                        int IH, int IW, int OH, int OW) {
    constexpr int PATCH = 7 * S + 5;
    constexpr int NPIX = PATCH * PATCH;
    constexpr int NPAIR = (NPIX + 1) / 2;
    constexpr int PLSZ = NPAIR * 64;
    constexpr int NF = OCT / 16;
    constexpr int BN = NI * 32;
    constexpr int OCB = OCT / BN;
    constexpr int NITER = (NPIX * 8 + 255) / 256;
    constexpr int REM = NPIX * 8 - (NITER - 1) * 256;
    __shared__ u16 patch[2 * PLSZ];

    int t = threadIdx.x, l = t & 63, wv = t >> 6;
    int wm = wv >> 1, wn = wv & 1, g = l >> 4;

    int bi = blockIdx.x;
    int ocb = bi % OCB; int rest = bi / OCB;
    int tw = OW >> 3, th = OH >> 3;
    int txi = rest % tw; rest /= tw;
    int tyi = rest % th; int n = rest / th;
    int iy0 = S * (tyi << 3) - 2, ix0 = S * (txi << 3) - 2;

    int ppb[2];
    #pragma unroll
    for (int mi = 0; mi < 2; ++mi) {
        int m = wm * 32 + mi * 16 + (l & 15);
        ppb[mi] = (S * (m >> 3)) * PATCH + S * (m & 7);
    }

    // ---- hoisted staging addresses (computed once) ----
    ptrdiff_t pd = Al_g - Ah_g;
    int goff[NITER], loff[NITER];
    #pragma unroll
    for (int j = 0; j < NITER; ++j) {
        goff[j] = -1; loff[j] = 0;
        int i = t + j * 256;
        if (j < NITER - 1 || i < NPIX * 8) {
            int c = i & 3; int r2 = i >> 2;
            int pl = (r2 >= NPIX); int pp = r2 - pl * NPIX;
            int py = pp / PATCH, px = pp - py * PATCH;
            int iy = iy0 + py, ix = ix0 + px;
            int P = pp >> 1, r = pp & 1;
            loff[j] = pl * PLSZ + (P << 6) + (((P + (c << 1) + r) & 7) << 3);
            if ((unsigned)iy < (unsigned)IH && (unsigned)ix < (unsigned)IW)
                goff[j] = (((n * IH + iy) * IW + ix) << 6) + c * 8;
        }
    }

    f32x4 acc0[2][NI], acc1[2][NI];
    f32x4 z4 = {0.f, 0.f, 0.f, 0.f};
    #pragma unroll
    for (int mi = 0; mi < 2; ++mi)
        #pragma unroll
        for (int ni = 0; ni < NI; ++ni) { acc0[mi][ni] = z4; acc1[mi][ni] = z4; }

    int tap0 = bi % 25;
    int dy0 = tap0 / 5, dx0 = tap0 - 5 * dy0;
    int tadd0 = dy0 * PATCH + dx0;
    int iccr = bi & 1;
    int fg = ocb * (BN / 16) + wn * NI;
    const size_t tstride = (size_t)(4 * NF) * 512;

    for (int icci = 0; icci < 2; ++icci) {
        int icc = icci ^ iccr;
        __syncthreads();
        #pragma unroll
        for (int j = 0; j < NITER; ++j) {
            if (j < NITER - 1 || t < REM) {
                uint4 v = make_uint4(0u, 0u, 0u, 0u);
                int go = goff[j];
                if (go >= 0) {
                    const u16* gp = Ah_g + go + icc * 32;
                    if (loff[j] >= PLSZ) gp += pd;
                    v = *(const uint4*)gp;
                }
                *(uint4*)&patch[loff[j]] = v;
            }
        }
        __syncthreads();

        const u16* pB = wBf + (size_t)((tap0 * 4 + icc * 2) * NF + fg) * 512 + l * 8;
        // load A for tap0
        f16x8 ah0[2], al0[2], ah1[2], al1[2];
        #pragma unroll
        for (int mi = 0; mi < 2; ++mi) {
            int pp = ppb[mi] + tadd0;
            int P = pp >> 1, r = pp & 1;
            int offs = (P << 6) + (((P + (g << 1) + r) & 7) << 3);
            ah0[mi] = *(const f16x8*)&patch[offs];
            al0[mi] = *(const f16x8*)&patch[PLSZ + offs];
        }
        int tap = tap0, dx = dx0, tadd = tadd0;
        for (int tapi = 0; tapi < 25; ++tapi) {
            // next-tap bookkeeping + A prefetch
            int ntap, ndx, ntadd;
            if (tap == 24) { ntap = 0; ndx = 0; ntadd = 0; }
            else {
                ntap = tap + 1; ndx = dx + 1; ntadd = tadd + 1;
                if (ndx == 5) { ndx = 0; ntadd = tadd + (PATCH - 4); }
            }
            if (tapi < 24) {
                #pragma unroll
                for (int mi = 0; mi < 2; ++mi) {
                    int pp = ppb[mi] + ntadd;
                    int P = pp >> 1, r = pp & 1;
                    int offs = (P << 6) + (((P + (g << 1) + r) & 7) << 3);
                    ah1[mi] = *(const f16x8*)&patch[offs];
                    al1[mi] = *(const f16x8*)&patch[PLSZ + offs];
                }
            }
            // B at use
            f16x8 Bh[NI], Bl[NI];
            #pragma unroll
            for (int ni = 0; ni < NI; ++ni) {
                Bh[ni] = *(const f16x8*)&pB[ni * 512];
                Bl[ni] = *(const f16x8*)&pB[(NF + ni) * 512];
            }
            #pragma unroll
            for (int mi = 0; mi < 2; ++mi) {
                #pragma unroll
                for (int ni = 0; ni < NI; ++ni) {
                    acc0[mi][ni] = __builtin_amdgcn_mfma_f32_16x16x32_f16(ah0[mi], Bh[ni], acc0[mi][ni], 0, 0, 0);
                    acc1[mi][ni] = __builtin_amdgcn_mfma_f32_16x16x32_f16(ah0[mi], Bl[ni], acc1[mi][ni], 0, 0, 0);
                    acc1[mi][ni] = __builtin_amdgcn_mfma_f32_16x16x32_f16(al0[mi], Bh[ni], acc1[mi][ni], 0, 0, 0);
                }
            }
            #pragma unroll
            for (int mi = 0; mi < 2; ++mi) { ah0[mi] = ah1[mi]; al0[mi] = al1[mi]; }
            pB = (tap == 24) ? (pB - 24 * tstride) : (pB + tstride);
            tap = ntap; dx = ndx; tadd = ntadd;
        }
    }
    #pragma unroll
    for (int mi = 0; mi < 2; ++mi)
        #pragma unroll
        for (int ni = 0; ni < NI; ++ni) {
            int oc = ocb * BN + wn * (NI * 16) + ni * 16 + (l & 15);
            float bv = bias[oc];
            #pragma unroll
            for (int reg = 0; reg < 4; ++reg) {
                float v = acc0[mi][ni][reg] + acc1[mi][ni][reg] * (1.f / 4096.f) + bv;
                if (RELU) v = fmaxf(v, 0.f);
                int pix = wm * 32 + mi * 16 + g * 4 + reg;
                int oy = (tyi << 3) + (pix >> 3), ox = (txi << 3) + (pix & 7);
                int idx = ((n * OH + oy) * OW + ox) * OCT + oc;
                f16 hh = (f16)v;
                Oh[idx] = __builtin_bit_cast(u16, hh);
                Ol[idx] = f2h((v - (float)hh) * 4096.f);
            }
        }
}

// ============================ quantize v4: A-in-registers, B via LDS double-buffer ============================
__launch_bounds__(256, 2)
__global__ void quant_k(const u16* __restrict__ zh, const u16* __restrict__ zl,
                        const u16* __restrict__ cbf, const float* __restrict__ cbn,
                        const float* __restrict__ cb, u16* __restrict__ e,
                        float* __restrict__ diff) {
    __shared__ u16 Bbuf[2 * 32 * 512];     // [buf][ks*4+pl*2+nf][lane*8]
    __shared__ float cbn_l[1024];
    __shared__ float zn_l[128];
    __shared__ float bd_l[128];
    __shared__ int   wi_l[128];

    int t = threadIdx.x, l = t & 63, wv = t >> 6, g = l >> 4;
    int bi = blockIdx.x;
    int row0 = bi << 7;

    {
        f32x4 v = *(const f32x4*)&cbn[t * 4];
        *(f32x4*)&cbn_l[t * 4] = v;
    }

    f16x8 Ah[2][8], Al[2][8];
    int rbase = row0 + wv * 32 + (l & 15);
    #pragma unroll
    for (int mi = 0; mi < 2; ++mi)
        #pragma unroll
        for (int ks = 0; ks < 8; ++ks) {
            size_t off = (size_t)(rbase + mi * 16) * 256 + ks * 32 + g * 8;
            Ah[mi][ks] = *(const f16x8*)&zh[off];
            Al[mi][ks] = *(const f16x8*)&zl[off];
        }

    #pragma unroll
    for (int mi = 0; mi < 2; ++mi) {
        float s = 0.f;
        #pragma unroll
        for (int ks = 0; ks < 8; ++ks)
            #pragma unroll
            for (int j = 0; j < 8; ++j) {
                float v = (float)Ah[mi][ks][j] + (float)Al[mi][ks][j] * (1.f / 4096.f);
                s = fmaf(v, v, s);
            }
        s += __shfl_xor(s, 16);
        s += __shfl_xor(s, 32);
        if (g == 0) zn_l[wv * 32 + mi * 16 + (l & 15)] = s;
    }

    float rd[8]; int rc[8];
    #pragma unroll
    for (int s = 0; s < 8; ++s) { rd[s] = 1e30f; rc[s] = 0; }

    int fi = wv * 8;
    {
        int no0 = bi & 31;
        #pragma unroll
        for (int q = 0; q < 8; ++q) {
            int f2 = fi + q;
            int ks = f2 >> 2, pl = (f2 >> 1) & 1, nf = f2 & 1;
            f16x8 v = *(const f16x8*)&cbf[(size_t)(((ks * 2 + pl) * 64) + no0 * 2 + nf) * 512 + l * 8];
            *(uint4*)&Bbuf[(size_t)f2 * 512 + l * 8] = __builtin_bit_cast(uint4, v);
        }
    }
    __syncthreads();

    for (int noi = 0; noi < 32; ++noi) {
        int b = noi & 1;
        int no_cur = (noi + bi) & 31;

        f16x8 pf[8];
        if (noi < 31) {
            int no_n = (noi + 1 + bi) & 31;
            #pragma unroll
            for (int q = 0; q < 8; ++q) {
                int f2 = fi + q;
                int ks = f2 >> 2, pl = (f2 >> 1) & 1, nf = f2 & 1;
                pf[q] = *(const f16x8*)&cbf[(size_t)(((ks * 2 + pl) * 64) + no_n * 2 + nf) * 512 + l * 8];
            }
        }

        f32x4 acc0[2][2], acc1[2][2];
        f32x4 z4 = {0.f, 0.f, 0.f, 0.f};
        #pragma unroll
        for (int mi = 0; mi < 2; ++mi)
            #pragma unroll
            for (int nf = 0; nf < 2; ++nf) { acc0[mi][nf] = z4; acc1[mi][nf] = z4; }

        #pragma unroll
        for (int ks = 0; ks < 8; ++ks) {
            const u16* bb = &Bbuf[(size_t)(b * 32 + ks * 4) * 512 + l * 8];
            f16x8 Bh0 = *(const f16x8*)&bb[0 * 512];
            f16x8 Bh1 = *(const f16x8*)&bb[1 * 512];
            f16x8 Bl0 = *(const f16x8*)&bb[2 * 512];
            f16x8 Bl1 = *(const f16x8*)&bb[3 * 512];
            #pragma unroll
            for (int mi = 0; mi < 2; ++mi) {
                acc0[mi][0] = __builtin_amdgcn_mfma_f32_16x16x32_f16(Ah[mi][ks], Bh0, acc0[mi][0], 0, 0, 0);
                acc0[mi][1] = __builtin_amdgcn_mfma_f32_16x16x32_f16(Ah[mi][ks], Bh1, acc0[mi][1], 0, 0, 0);
                acc1[mi][0] = __builtin_amdgcn_mfma_f32_16x16x32_f16(Ah[mi][ks], Bl0, acc1[mi][0], 0, 0, 0);
                acc1[mi][0] = __builtin_amdgcn_mfma_f32_16x16x32_f16(Al[mi][ks], Bh0, acc1[mi][0], 0, 0, 0);
                acc1[mi][1] = __builtin_amdgcn_mfma_f32_16x16x32_f16(Ah[mi][ks], Bl1, acc1[mi][1], 0, 0, 0);
                acc1[mi][1] = __builtin_amdgcn_mfma_f32_16x16x32_f16(Al[mi][ks], Bh1, acc1[mi][1], 0, 0, 0);
            }
        }

        #pragma unroll
        for (int nf = 0; nf < 2; ++nf) {
            int col = no_cur * 32 + nf * 16 + (l & 15);
            float cn = cbn_l[col];
            #pragma unroll
            for (int mi = 0; mi < 2; ++mi)
                #pragma unroll
                for (int reg = 0; reg < 4; ++reg) {
                    float d = cn - 2.f * (acc0[mi][nf][reg] + acc1[mi][nf][reg] * (1.f / 4096.f));
                    int slot = mi * 4 + reg;
                    if (d < rd[slot] || (d == rd[slot] && col < rc[slot])) { rd[slot] = d; rc[slot] = col; }
                }
        }

        if (noi < 31) {
            #pragma unroll
            for (int q = 0; q < 8; ++q)
                *(uint4*)&Bbuf[(size_t)((1 - b) * 32 + fi + q) * 512 + l * 8] = __builtin_bit_cast(uint4, pf[q]);
        }
        __syncthreads();
    }

    #pragma unroll
    for (int step = 1; step < 16; step <<= 1) {
        #pragma unroll
        for (int s = 0; s < 8; ++s) {
            float od = __shfl_xor(rd[s], step);
            int ocl = __shfl_xor(rc[s], step);
            if (od < rd[s] || (od == rd[s] && ocl < rc[s])) { rd[s] = od; rc[s] = ocl; }
        }
    }
    if ((l & 15) == 0) {
        #pragma unroll
        for (int s = 0; s < 8; ++s) {
            int mi = s >> 2, reg = s & 3;
            int row = wv * 32 + mi * 16 + g * 4 + reg;
            bd_l[row] = rd[s]; wi_l[row] = rc[s];
        }
    }
    __syncthreads();
    if (t < 64) {
        float dval = (zn_l[t] + bd_l[t]) + (zn_l[t + 64] + bd_l[t + 64]);
        #pragma unroll
        for (int step = 1; step < 64; step <<= 1) dval += __shfl_xor(dval, step);
        if (t == 0) atomicAdd(diff, dval * (1.f / 16777216.f));
    }
    __syncthreads();
    for (int r = 0; r < 128; ++r) {
        int wi = wi_l[r];
        e[(size_t)(row0 + r) * 256 + t] = f2h(cb[wi * 256 + t]);
    }
}

// ============================ plain-fp16 MFMA deconv k4 s2 p1, B prefetched ============================
template<int ICT>
__launch_bounds__(256)
__global__ void deconv4_k(const u16* __restrict__ in, const u16* __restrict__ wdf,
                          const float* __restrict__ bias, u16* __restrict__ out,
                          int IH, int IW) {
    constexpr int RST = 40;
    constexpr int ICC = ICT / 32;
    constexpr int PLSZ = 81 * RST;
    __shared__ u16 patch[PLSZ];

    int t = threadIdx.x, l = t & 63, wv = t >> 6;
    int wm = wv >> 1, wn = wv & 1, g = l >> 4;

    int bi = blockIdx.x;
    int par = bi & 3; int ry = par >> 1, rx = par & 1;
    int rest = bi >> 2;
    int tw = IW >> 3, th = IH >> 3;
    int txi = rest % tw; rest /= tw;
    int tyi = rest % th; int n = rest / th;
    int a0 = tyi << 3, b0 = txi << 3;
    int by0 = ry ? 0 : -1, bx0 = rx ? 0 : -1;
    int OH = IH << 1, OW = IW << 1;

    int pb0[2];
    #pragma unroll
    for (int mi = 0; mi < 2; ++mi) {
        int m = wm * 32 + mi * 16 + (l & 15);
        int pa = m >> 3, pb_ = m & 7;
        pb0[mi] = (pa * 9 + pb_) * RST + g * 8;
    }

    f32x4 acc[2][2];
    f32x4 z4 = {0.f, 0.f, 0.f, 0.f};
    #pragma unroll
    for (int mi = 0; mi < 2; ++mi)
        #pragma unroll
        for (int ni = 0; ni < 2; ++ni) acc[mi][ni] = z4;

    auto ldB = [&](int icc, int tt, f16x8* B) {
        int tty = tt >> 1, ttx = tt & 1;
        int ky = 1 - ry + 2 * tty, kx = 1 - rx + 2 * ttx;
        int tap = ky * 4 + kx;
        #pragma unroll
        for (int ni = 0; ni < 2; ++ni)
            B[ni] = *(const f16x8*)&wdf[(size_t)((tap * ICC + icc) * 4 + wn * 2 + ni) * 512 + l * 8];
    };

    f16x8 B0[2], B1[2];
    {
        int icc0 = (bi >> 2) & (ICC - 1);
        ldB(icc0, bi & 3, B0);
    }

    for (int icci = 0; icci < ICC; ++icci) {
        int icc = (icci + (bi >> 2)) & (ICC - 1);
        __syncthreads();
        for (int i = t; i < 324; i += 256) {
            int c = i & 3; int pp = i >> 2;
            int pr = pp / 9, pc = pp - pr * 9;
            int ar = a0 + by0 + pr, ac = b0 + bx0 + pc;
            uint4 v = make_uint4(0u, 0u, 0u, 0u);
            if ((unsigned)ar < (unsigned)IH && (unsigned)ac < (unsigned)IW)
                v = *(const uint4*)&in[((n * IH + ar) * IW + ac) * ICT + icc * 32 + c * 8];
            *(uint4*)&patch[(pr * 9 + pc) * RST + c * 8] = v;
        }
        __syncthreads();
        #pragma unroll
        for (int tti = 0; tti < 4; ++tti) {
            int tt = (tti + bi) & 3;
            if (!(icci == ICC - 1 && tti == 3)) {
                int nicci = (tti == 3) ? icci + 1 : icci;
                int ntti = (tti == 3) ? 0 : tti + 1;
                int nicc = (nicci + (bi >> 2)) & (ICC - 1);
                ldB(nicc, (ntti + bi) & 3, B1);
            }
            int tty = tt >> 1, ttx = tt & 1;
            int shift = ((1 - tty) * 9 + (1 - ttx)) * RST;
            #pragma unroll
            for (int mi = 0; mi < 2; ++mi) {
                f16x8 a = *(const f16x8*)&patch[pb0[mi] + shift];
                #pragma unroll
                for (int ni = 0; ni < 2; ++ni)
                    acc[mi][ni] = __builtin_amdgcn_mfma_f32_16x16x32_f16(a, B0[ni], acc[mi][ni], 0, 0, 0);
            }
            B0[0] = B1[0]; B0[1] = B1[1];
        }
    }
    #pragma unroll
    for (int mi = 0; mi < 2; ++mi)
        #pragma unroll
        for (int ni = 0; ni < 2; ++ni) {
            int oc = wn * 32 + ni * 16 + (l & 15);
            float bv = bias[oc];
            #pragma unroll
            for (int reg = 0; reg < 4; ++reg) {
                float v = fmaxf(acc[mi][ni][reg] + bv, 0.f);
                int pix = wm * 32 + mi * 16 + g * 4 + reg;
                int oy = ((a0 + (pix >> 3)) << 1) + ry;
                int ox = ((b0 + (pix & 7)) << 1) + rx;
                out[((n * OH + oy) * OW + ox) * 64 + oc] = f2h(v);
            }
        }
}

// ============================ final conv 3x3 64->1, p1, tanh (LDS-tiled, v_dot2) ============================
__launch_bounds__(256)
__global__ void conv3x3_tanh_k(const u16* __restrict__ in, const float* __restrict__ w,
                               const float* __restrict__ b, float* __restrict__ out) {
    __shared__ u16 tile[18 * 18 * 72];
    __shared__ u32 wpk[288];   // [tap][icp] half2-packed weights
    int t = threadIdx.x;
    int bi = blockIdx.x;
    int n = bi >> 6;
    int tile6 = bi & 63;
    int ty0 = (tile6 >> 3) << 4, tx0 = (tile6 & 7) << 4;

    for (int i = t; i < 288; i += 256) {
        int tap = i >> 5, icp = i & 31;
        h2 p;
        p.x = (f16)w[(2 * icp) * 9 + tap];
        p.y = (f16)w[(2 * icp + 1) * 9 + tap];
        wpk[tap * 32 + icp] = __builtin_bit_cast(u32, p);
    }
    for (int i = t; i < 2592; i += 256) {
        int ch = i & 7, pix = i >> 3;
        int pr = pix / 18, pc = pix - pr * 18;
        int gy = ty0 - 1 + pr, gx = tx0 - 1 + pc;
        uint4 v = make_uint4(0u, 0u, 0u, 0u);
        if ((unsigned)gy < 128u && (unsigned)gx < 128u)
            v = *(const uint4*)&in[(((n << 7) + gy) * 128 + gx) * 64 + ch * 8];
        *(uint4*)&tile[pix * 72 + ch * 8] = v;
    }
    __syncthreads();

    int ty = t >> 4, tx = t & 15;
    float acc = b[0];
    #pragma unroll
    for (int dy = 0; dy < 3; ++dy) {
        #pragma unroll
        for (int dx = 0; dx < 3; ++dx) {
            int base = ((ty + dy) * 18 + (tx + dx)) * 72;
            const u32* wp = &wpk[(dy * 3 + dx) * 32];
            #pragma unroll
            for (int c8 = 0; c8 < 8; ++c8) {
                uint4 v = *(const uint4*)&tile[base + c8 * 8];
                acc = __builtin_amdgcn_fdot2(__builtin_bit_cast(h2, v.x),
                        __builtin_bit_cast(h2, wp[c8 * 4 + 0]), acc, false);
                acc = __builtin_amdgcn_fdot2(__builtin_bit_cast(h2, v.y),
                        __builtin_bit_cast(h2, wp[c8 * 4 + 1]), acc, false);
                acc = __builtin_amdgcn_fdot2(__builtin_bit_cast(h2, v.z),
                        __builtin_bit_cast(h2, wp[c8 * 4 + 2]), acc, false);
                acc = __builtin_amdgcn_fdot2(__builtin_bit_cast(h2, v.w),
                        __builtin_bit_cast(h2, wp[c8 * 4 + 3]), acc, false);
            }
        }
    }
    int oy = ty0 + ty, ox = tx0 + tx;
    out[(n << 14) + (oy << 7) + ox] = tanhf(acc);
}

extern "C" void kernel_launch(void* const* d_in, const int* in_sizes, int n_in,
                              void* d_out, int out_size, void* d_ws, size_t ws_size,
                              hipStream_t stream) {
    (void)in_sizes; (void)n_in; (void)out_size; (void)ws_size;
    const float* x   = (const float*)d_in[0];
    const float* ew1 = (const float*)d_in[1];
    const float* eb1 = (const float*)d_in[2];
    const float* ew2 = (const float*)d_in[3];
    const float* eb2 = (const float*)d_in[4];
    const float* ew3 = (const float*)d_in[5];
    const float* eb3 = (const float*)d_in[6];
    const float* cb  = (const float*)d_in[7];
    const float* dw1 = (const float*)d_in[8];
    const float* db1 = (const float*)d_in[9];
    const float* dw2 = (const float*)d_in[10];
    const float* db2 = (const float*)d_in[11];
    const float* dw3 = (const float*)d_in[12];
    const float* db3 = (const float*)d_in[13];
    float* out = (float*)d_out;

    u16* ws = (u16*)d_ws;
    u16* a1h = ws;             u16* a1l = ws + 16777216;
    u16* zh  = ws;             u16* zl  = ws + 16777216;
    u16* a2h = ws + 33554432;  u16* a2l = ws + 50331648;
    u16* e   = ws + 33554432;
    u16* y1  = ws + 67108864;
    u16* y2  = ws;
    u16* wBf2 = ws + 83886080;          // 204800
    u16* wBf3 = wBf2 + 204800;          // 819200
    u16* wd1f = wBf3 + 819200;          // 262144
    u16* wd2f = wd1f + 262144;          // 65536
    u16* cbf  = wd2f + 65536;           // 524288
    float* cbn = (float*)(cbf + 524288);

    hipMemsetAsync(out + 1048576, 0, 4, stream);  // diff accumulator

    prep_wconv_k<<<800, 256, 0, stream>>>(ew2, wBf2, 2);   // NF=4
    prep_wconv_k<<<3200, 256, 0, stream>>>(ew3, wBf3, 4);  // NF=16
    prep_wdec_k<<<1024, 256, 0, stream>>>(dw1, wd1f, 3);   // ICC=8
    prep_wdec_k<<<256, 256, 0, stream>>>(dw2, wd2f, 1);    // ICC=2
    prep_cb_k<<<2048, 256, 0, stream>>>(cb, cbf);
    prep_cbn_k<<<4, 256, 0, stream>>>(cb, cbn);

    conv1_k<<<1024, 256, 0, stream>>>(x, ew1, eb1, a1h, a1l);
    conv5_k<1, 64, 2, true><<<4096, 256, 0, stream>>>(a1h, a1l, wBf2, eb2, a2h, a2l, 64, 64, 64, 64);
    conv5_k<2, 256, 4, false><<<2048, 256, 0, stream>>>(a2h, a2l, wBf3, eb3, zh, zl, 64, 64, 32, 32);
    quant_k<<<512, 256, 0, stream>>>(zh, zl, cbf, cbn, cb, e, out + 1048576);
    deconv4_k<256><<<4096, 256, 0, stream>>>(e, wd1f, db1, y1, 32, 32);
    deconv4_k<64><<<16384, 256, 0, stream>>>(y1, wd2f, db2, y2, 64, 64);
    conv3x3_tanh_k<<<4096, 256, 0, stream>>>(y2, dw3, db3, out);
}

// Round 10
// 708.205 us; speedup vs baseline: 1.3429x; 1.0174x over previous
//
#include <hip/hip_runtime.h>

typedef _Float16 f16;
typedef _Float16 f16x8 __attribute__((ext_vector_type(8)));
typedef _Float16 f16x4 __attribute__((ext_vector_type(4)));
typedef _Float16 h2 __attribute__((ext_vector_type(2)));
typedef float f32x4 __attribute__((ext_vector_type(4)));
typedef unsigned short u16;
typedef unsigned int u32;

#define DEVI __device__ __forceinline__

DEVI u16 f2h(float f) { f16 h = (f16)f; return __builtin_bit_cast(u16, h); }
DEVI float h2f(u16 u) { f16 h = __builtin_bit_cast(f16, u); return (float)h; }

// ============================ weight prep ============================
__launch_bounds__(256)
__global__ void prep_wconv_k(const float* __restrict__ src, u16* __restrict__ dst, int nf_sh) {
    int i = blockIdx.x * 256 + threadIdx.x;
    int j = i & 7, lane = (i >> 3) & 63;
    int q = i >> 9;
    int f = q & ((1 << nf_sh) - 1); q >>= nf_sh;
    int pl = q & 1; q >>= 1;
    int icc = q & 1; int tap = q >> 1;
    int oc = (f << 4) + (lane & 15);
    int ic = icc * 32 + ((lane >> 4) << 3) + j;
    float w = src[(oc * 64 + ic) * 25 + tap];
    if (pl == 0) dst[i] = f2h(w);
    else         dst[i] = f2h((w - h2f(f2h(w))) * 4096.f);
}
__launch_bounds__(256)
__global__ void prep_wdec_k(const float* __restrict__ src, u16* __restrict__ dst, int icc_sh) {
    int i = blockIdx.x * 256 + threadIdx.x;
    int j = i & 7, lane = (i >> 3) & 63;
    int f = (i >> 9) & 3;
    int q = i >> 11;
    int icc = q & ((1 << icc_sh) - 1); int tap = q >> icc_sh;
    int oc = (f << 4) + (lane & 15);
    int ic = icc * 32 + ((lane >> 4) << 3) + j;
    dst[i] = f2h(src[(ic * 64 + oc) * 16 + tap]);
}
__launch_bounds__(256)
__global__ void prep_cb_k(const float* __restrict__ cb, u16* __restrict__ dst) {
    int i = blockIdx.x * 256 + threadIdx.x;   // 524288
    int j = i & 7, lane = (i >> 3) & 63;
    int f = (i >> 9) & 63;
    int q = i >> 15;
    int pl = q & 1; int ks = q >> 1;
    int n = (f << 4) + (lane & 15);
    int k = ks * 32 + ((lane >> 4) << 3) + j;
    float w = cb[n * 256 + k];
    if (pl == 0) dst[i] = f2h(w);
    else         dst[i] = f2h((w - h2f(f2h(w))) * 4096.f);
}
__launch_bounds__(256)
__global__ void prep_cbn_k(const float* __restrict__ cb, float* __restrict__ cbn) {
    int row = blockIdx.x * 256 + threadIdx.x;          // 1024
    float s = 0.f;
    for (int c = 0; c < 256; c += 4) {
        f32x4 v = *(const f32x4*)&cb[row * 256 + c];
        s = fmaf(v.x, v.x, s); s = fmaf(v.y, v.y, s);
        s = fmaf(v.z, v.z, s); s = fmaf(v.w, v.w, s);
    }
    cbn[row] = s;
}

// ============================ conv1: 1->64, 5x5 s2 p2, relu, split-fp16 out ============================
__launch_bounds__(256)
__global__ void conv1_k(const float* __restrict__ x, const float* __restrict__ w,
                        const float* __restrict__ b, u16* __restrict__ oh, u16* __restrict__ ol) {
    __shared__ float wl[25 * 64];
    __shared__ float bl[64];
    int t = threadIdx.x;
    for (int i = t; i < 1600; i += 256) wl[(i % 25) * 64 + i / 25] = w[i];
    if (t < 64) bl[t] = b[t];
    __syncthreads();
    int p = blockIdx.x * 256 + t;                       // 262144 pixels
    int ox = p & 63, oy = (p >> 6) & 63, n = p >> 12;
    f32x4 acc[16];
    #pragma unroll
    for (int c = 0; c < 16; ++c) acc[c] = *(f32x4*)&bl[c * 4];
    for (int dy = 0; dy < 5; ++dy) {
        int iy = 2 * oy - 2 + dy;
        if ((unsigned)iy >= 128u) continue;
        for (int dx = 0; dx < 5; ++dx) {
            int ix = 2 * ox - 2 + dx;
            if ((unsigned)ix >= 128u) continue;
            float v = x[(n * 128 + iy) * 128 + ix];
            const float* wp = &wl[(dy * 5 + dx) * 64];
            #pragma unroll
            for (int c = 0; c < 16; ++c) {
                f32x4 w4 = *(const f32x4*)&wp[c * 4];
                acc[c].x = fmaf(v, w4.x, acc[c].x); acc[c].y = fmaf(v, w4.y, acc[c].y);
                acc[c].z = fmaf(v, w4.z, acc[c].z); acc[c].w = fmaf(v, w4.w, acc[c].w);
            }
        }
    }
    #pragma unroll
    for (int c = 0; c < 16; ++c) {
        ushort4 uh, ul;
        float vv[4] = {acc[c].x, acc[c].y, acc[c].z, acc[c].w};
        u16 rh[4], rl[4];
        #pragma unroll
        for (int k = 0; k < 4; ++k) {
            float v = fmaxf(vv[k], 0.f);
            f16 hh = (f16)v;
            rh[k] = __builtin_bit_cast(u16, hh);
            rl[k] = f2h((v - (float)hh) * 4096.f);
        }
        uh.x = rh[0]; uh.y = rh[1]; uh.z = rh[2]; uh.w = rh[3];
        ul.x = rl[0]; ul.y = rl[1]; ul.z = rl[2]; ul.w = rl[3];
        *(ushort4*)&oh[p * 64 + c * 4] = uh;
        *(ushort4*)&ol[p * 64 + c * 4] = ul;
    }
}

// ============================ split-fp16 MFMA 5x5 conv, XCD-slab swizzle ============================
// XCD = bi&7 (round-robin assumption): w = xcd*(grid/8) + (bi>>3) gives each XCD a
// contiguous tile slab; ocb pairs + halo neighbors stay on one XCD's L2.
template<int S, int OCT, int NI, bool RELU>
__launch_bounds__(256)
__global__ void conv5_k(const u16* __restrict__ Ah_g, const u16* __restrict__ Al_g,
                        const u16* __restrict__ wBf, const float* __restrict__ bias,
                        u16* __restrict__ Oh, u16* __restrict__ Ol,
                        int IH, int IW, int OH, int OW) {
    constexpr int PATCH = 7 * S + 5;
    constexpr int NPIX = PATCH * PATCH;
    constexpr int NPAIR = (NPIX + 1) / 2;
    constexpr int PLSZ = NPAIR * 64;
    constexpr int NF = OCT / 16;
    constexpr int BN = NI * 32;
    constexpr int OCB = OCT / BN;
    constexpr int NITER = (NPIX * 8 + 255) / 256;
    constexpr int REM = NPIX * 8 - (NITER - 1) * 256;
    __shared__ u16 patch[2 * PLSZ];

    int t = threadIdx.x, l = t & 63, wv = t >> 6;
    int wm = wv >> 1, wn = wv & 1, g = l >> 4;

    int bi = blockIdx.x;
    // XCD-aware remap
    int wlin = (bi & 7) * ((int)gridDim.x >> 3) + (bi >> 3);
    int ocb = wlin % OCB; int rest = wlin / OCB;
    int tw = OW >> 3, th = OH >> 3;
    int txi = rest % tw; rest /= tw;
    int tyi = rest % th; int n = rest / th;
    int iy0 = S * (tyi << 3) - 2, ix0 = S * (txi << 3) - 2;

    int ppb[2];
    #pragma unroll
    for (int mi = 0; mi < 2; ++mi) {
        int m = wm * 32 + mi * 16 + (l & 15);
        ppb[mi] = (S * (m >> 3)) * PATCH + S * (m & 7);
    }

    // ---- hoisted staging addresses (computed once) ----
    ptrdiff_t pd = Al_g - Ah_g;
    int goff[NITER], loff[NITER];
    #pragma unroll
    for (int j = 0; j < NITER; ++j) {
        goff[j] = -1; loff[j] = 0;
        int i = t + j * 256;
        if (j < NITER - 1 || i < NPIX * 8) {
            int c = i & 3; int r2 = i >> 2;
            int pl = (r2 >= NPIX); int pp = r2 - pl * NPIX;
            int py = pp / PATCH, px = pp - py * PATCH;
            int iy = iy0 + py, ix = ix0 + px;
            int P = pp >> 1, r = pp & 1;
            loff[j] = pl * PLSZ + (P << 6) + (((P + (c << 1) + r) & 7) << 3);
            if ((unsigned)iy < (unsigned)IH && (unsigned)ix < (unsigned)IW)
                goff[j] = (((n * IH + iy) * IW + ix) << 6) + c * 8;
        }
    }

    f32x4 acc0[2][NI], acc1[2][NI];
    f32x4 z4 = {0.f, 0.f, 0.f, 0.f};
    #pragma unroll
    for (int mi = 0; mi < 2; ++mi)
        #pragma unroll
        for (int ni = 0; ni < NI; ++ni) { acc0[mi][ni] = z4; acc1[mi][ni] = z4; }

    int tap0 = bi % 25;
    int dy0 = tap0 / 5, dx0 = tap0 - 5 * dy0;
    int tadd0 = dy0 * PATCH + dx0;
    int iccr = bi & 1;
    int fg = ocb * (BN / 16) + wn * NI;
    const size_t tstride = (size_t)(4 * NF) * 512;

    for (int icci = 0; icci < 2; ++icci) {
        int icc = icci ^ iccr;
        __syncthreads();
        #pragma unroll
        for (int j = 0; j < NITER; ++j) {
            if (j < NITER - 1 || t < REM) {
                uint4 v = make_uint4(0u, 0u, 0u, 0u);
                int go = goff[j];
                if (go >= 0) {
                    const u16* gp = Ah_g + go + icc * 32;
                    if (loff[j] >= PLSZ) gp += pd;
                    v = *(const uint4*)gp;
                }
                *(uint4*)&patch[loff[j]] = v;
            }
        }
        __syncthreads();

        const u16* pB = wBf + (size_t)((tap0 * 4 + icc * 2) * NF + fg) * 512 + l * 8;
        // load A for tap0
        f16x8 ah0[2], al0[2], ah1[2], al1[2];
        #pragma unroll
        for (int mi = 0; mi < 2; ++mi) {
            int pp = ppb[mi] + tadd0;
            int P = pp >> 1, r = pp & 1;
            int offs = (P << 6) + (((P + (g << 1) + r) & 7) << 3);
            ah0[mi] = *(const f16x8*)&patch[offs];
            al0[mi] = *(const f16x8*)&patch[PLSZ + offs];
        }
        int tap = tap0, dx = dx0, tadd = tadd0;
        for (int tapi = 0; tapi < 25; ++tapi) {
            int ntap, ndx, ntadd;
            if (tap == 24) { ntap = 0; ndx = 0; ntadd = 0; }
            else {
                ntap = tap + 1; ndx = dx + 1; ntadd = tadd + 1;
                if (ndx == 5) { ndx = 0; ntadd = tadd + (PATCH - 4); }
            }
            if (tapi < 24) {
                #pragma unroll
                for (int mi = 0; mi < 2; ++mi) {
                    int pp = ppb[mi] + ntadd;
                    int P = pp >> 1, r = pp & 1;
                    int offs = (P << 6) + (((P + (g << 1) + r) & 7) << 3);
                    ah1[mi] = *(const f16x8*)&patch[offs];
                    al1[mi] = *(const f16x8*)&patch[PLSZ + offs];
                }
            }
            f16x8 Bh[NI], Bl[NI];
            #pragma unroll
            for (int ni = 0; ni < NI; ++ni) {
                Bh[ni] = *(const f16x8*)&pB[ni * 512];
                Bl[ni] = *(const f16x8*)&pB[(NF + ni) * 512];
            }
            #pragma unroll
            for (int mi = 0; mi < 2; ++mi) {
                #pragma unroll
                for (int ni = 0; ni < NI; ++ni) {
                    acc0[mi][ni] = __builtin_amdgcn_mfma_f32_16x16x32_f16(ah0[mi], Bh[ni], acc0[mi][ni], 0, 0, 0);
                    acc1[mi][ni] = __builtin_amdgcn_mfma_f32_16x16x32_f16(ah0[mi], Bl[ni], acc1[mi][ni], 0, 0, 0);
                    acc1[mi][ni] = __builtin_amdgcn_mfma_f32_16x16x32_f16(al0[mi], Bh[ni], acc1[mi][ni], 0, 0, 0);
                }
            }
            #pragma unroll
            for (int mi = 0; mi < 2; ++mi) { ah0[mi] = ah1[mi]; al0[mi] = al1[mi]; }
            pB = (tap == 24) ? (pB - 24 * tstride) : (pB + tstride);
            tap = ntap; dx = ndx; tadd = ntadd;
        }
    }
    #pragma unroll
    for (int mi = 0; mi < 2; ++mi)
        #pragma unroll
        for (int ni = 0; ni < NI; ++ni) {
            int oc = ocb * BN + wn * (NI * 16) + ni * 16 + (l & 15);
            float bv = bias[oc];
            #pragma unroll
            for (int reg = 0; reg < 4; ++reg) {
                float v = acc0[mi][ni][reg] + acc1[mi][ni][reg] * (1.f / 4096.f) + bv;
                if (RELU) v = fmaxf(v, 0.f);
                int pix = wm * 32 + mi * 16 + g * 4 + reg;
                int oy = (tyi << 3) + (pix >> 3), ox = (txi << 3) + (pix & 7);
                int idx = ((n * OH + oy) * OW + ox) * OCT + oc;
                f16 hh = (f16)v;
                Oh[idx] = __builtin_bit_cast(u16, hh);
                Ol[idx] = f2h((v - (float)hh) * 4096.f);
            }
        }
}

// ============================ quantize v4: A-in-registers, B via LDS double-buffer ============================
__launch_bounds__(256, 2)
__global__ void quant_k(const u16* __restrict__ zh, const u16* __restrict__ zl,
                        const u16* __restrict__ cbf, const float* __restrict__ cbn,
                        const float* __restrict__ cb, u16* __restrict__ e,
                        float* __restrict__ diff) {
    __shared__ u16 Bbuf[2 * 32 * 512];     // [buf][ks*4+pl*2+nf][lane*8]
    __shared__ float cbn_l[1024];
    __shared__ float zn_l[128];
    __shared__ float bd_l[128];
    __shared__ int   wi_l[128];

    int t = threadIdx.x, l = t & 63, wv = t >> 6, g = l >> 4;
    int bi = blockIdx.x;
    int row0 = bi << 7;

    {
        f32x4 v = *(const f32x4*)&cbn[t * 4];
        *(f32x4*)&cbn_l[t * 4] = v;
    }

    f16x8 Ah[2][8], Al[2][8];
    int rbase = row0 + wv * 32 + (l & 15);
    #pragma unroll
    for (int mi = 0; mi < 2; ++mi)
        #pragma unroll
        for (int ks = 0; ks < 8; ++ks) {
            size_t off = (size_t)(rbase + mi * 16) * 256 + ks * 32 + g * 8;
            Ah[mi][ks] = *(const f16x8*)&zh[off];
            Al[mi][ks] = *(const f16x8*)&zl[off];
        }

    #pragma unroll
    for (int mi = 0; mi < 2; ++mi) {
        float s = 0.f;
        #pragma unroll
        for (int ks = 0; ks < 8; ++ks)
            #pragma unroll
            for (int j = 0; j < 8; ++j) {
                float v = (float)Ah[mi][ks][j] + (float)Al[mi][ks][j] * (1.f / 4096.f);
                s = fmaf(v, v, s);
            }
        s += __shfl_xor(s, 16);
        s += __shfl_xor(s, 32);
        if (g == 0) zn_l[wv * 32 + mi * 16 + (l & 15)] = s;
    }

    float rd[8]; int rc[8];
    #pragma unroll
    for (int s = 0; s < 8; ++s) { rd[s] = 1e30f; rc[s] = 0; }

    int fi = wv * 8;
    {
        int no0 = bi & 31;
        #pragma unroll
        for (int q = 0; q < 8; ++q) {
            int f2 = fi + q;
            int ks = f2 >> 2, pl = (f2 >> 1) & 1, nf = f2 & 1;
            f16x8 v = *(const f16x8*)&cbf[(size_t)(((ks * 2 + pl) * 64) + no0 * 2 + nf) * 512 + l * 8];
            *(uint4*)&Bbuf[(size_t)f2 * 512 + l * 8] = __builtin_bit_cast(uint4, v);
        }
    }
    __syncthreads();

    for (int noi = 0; noi < 32; ++noi) {
        int b = noi & 1;
        int no_cur = (noi + bi) & 31;

        f16x8 pf[8];
        if (noi < 31) {
            int no_n = (noi + 1 + bi) & 31;
            #pragma unroll
            for (int q = 0; q < 8; ++q) {
                int f2 = fi + q;
                int ks = f2 >> 2, pl = (f2 >> 1) & 1, nf = f2 & 1;
                pf[q] = *(const f16x8*)&cbf[(size_t)(((ks * 2 + pl) * 64) + no_n * 2 + nf) * 512 + l * 8];
            }
        }

        f32x4 acc0[2][2], acc1[2][2];
        f32x4 z4 = {0.f, 0.f, 0.f, 0.f};
        #pragma unroll
        for (int mi = 0; mi < 2; ++mi)
            #pragma unroll
            for (int nf = 0; nf < 2; ++nf) { acc0[mi][nf] = z4; acc1[mi][nf] = z4; }

        #pragma unroll
        for (int ks = 0; ks < 8; ++ks) {
            const u16* bb = &Bbuf[(size_t)(b * 32 + ks * 4) * 512 + l * 8];
            f16x8 Bh0 = *(const f16x8*)&bb[0 * 512];
            f16x8 Bh1 = *(const f16x8*)&bb[1 * 512];
            f16x8 Bl0 = *(const f16x8*)&bb[2 * 512];
            f16x8 Bl1 = *(const f16x8*)&bb[3 * 512];
            #pragma unroll
            for (int mi = 0; mi < 2; ++mi) {
                acc0[mi][0] = __builtin_amdgcn_mfma_f32_16x16x32_f16(Ah[mi][ks], Bh0, acc0[mi][0], 0, 0, 0);
                acc0[mi][1] = __builtin_amdgcn_mfma_f32_16x16x32_f16(Ah[mi][ks], Bh1, acc0[mi][1], 0, 0, 0);
                acc1[mi][0] = __builtin_amdgcn_mfma_f32_16x16x32_f16(Ah[mi][ks], Bl0, acc1[mi][0], 0, 0, 0);
                acc1[mi][0] = __builtin_amdgcn_mfma_f32_16x16x32_f16(Al[mi][ks], Bh0, acc1[mi][0], 0, 0, 0);
                acc1[mi][1] = __builtin_amdgcn_mfma_f32_16x16x32_f16(Ah[mi][ks], Bl1, acc1[mi][1], 0, 0, 0);
                acc1[mi][1] = __builtin_amdgcn_mfma_f32_16x16x32_f16(Al[mi][ks], Bh1, acc1[mi][1], 0, 0, 0);
            }
        }

        #pragma unroll
        for (int nf = 0; nf < 2; ++nf) {
            int col = no_cur * 32 + nf * 16 + (l & 15);
            float cn = cbn_l[col];
            #pragma unroll
            for (int mi = 0; mi < 2; ++mi)
                #pragma unroll
                for (int reg = 0; reg < 4; ++reg) {
                    float d = cn - 2.f * (acc0[mi][nf][reg] + acc1[mi][nf][reg] * (1.f / 4096.f));
                    int slot = mi * 4 + reg;
                    if (d < rd[slot] || (d == rd[slot] && col < rc[slot])) { rd[slot] = d; rc[slot] = col; }
                }
        }

        if (noi < 31) {
            #pragma unroll
            for (int q = 0; q < 8; ++q)
                *(uint4*)&Bbuf[(size_t)((1 - b) * 32 + fi + q) * 512 + l * 8] = __builtin_bit_cast(uint4, pf[q]);
        }
        __syncthreads();
    }

    #pragma unroll
    for (int step = 1; step < 16; step <<= 1) {
        #pragma unroll
        for (int s = 0; s < 8; ++s) {
            float od = __shfl_xor(rd[s], step);
            int ocl = __shfl_xor(rc[s], step);
            if (od < rd[s] || (od == rd[s] && ocl < rc[s])) { rd[s] = od; rc[s] = ocl; }
        }
    }
    if ((l & 15) == 0) {
        #pragma unroll
        for (int s = 0; s < 8; ++s) {
            int mi = s >> 2, reg = s & 3;
            int row = wv * 32 + mi * 16 + g * 4 + reg;
            bd_l[row] = rd[s]; wi_l[row] = rc[s];
        }
    }
    __syncthreads();
    if (t < 64) {
        float dval = (zn_l[t] + bd_l[t]) + (zn_l[t + 64] + bd_l[t + 64]);
        #pragma unroll
        for (int step = 1; step < 64; step <<= 1) dval += __shfl_xor(dval, step);
        if (t == 0) atomicAdd(diff, dval * (1.f / 16777216.f));
    }
    __syncthreads();
    for (int r = 0; r < 128; ++r) {
        int wi = wi_l[r];
        e[(size_t)(row0 + r) * 256 + t] = f2h(cb[wi * 256 + t]);
    }
}

// ============================ plain-fp16 MFMA deconv k4 s2 p1, B prefetched, XCD swizzle ============================
// parity quads of one tile kept adjacent on one XCD -> input patch 4x L2 reuse.
template<int ICT>
__launch_bounds__(256)
__global__ void deconv4_k(const u16* __restrict__ in, const u16* __restrict__ wdf,
                          const float* __restrict__ bias, u16* __restrict__ out,
                          int IH, int IW) {
    constexpr int RST = 40;
    constexpr int ICC = ICT / 32;
    constexpr int PLSZ = 81 * RST;
    __shared__ u16 patch[PLSZ];

    int t = threadIdx.x, l = t & 63, wv = t >> 6;
    int wm = wv >> 1, wn = wv & 1, g = l >> 4;

    int bi = blockIdx.x;
    int wlin = (bi & 7) * ((int)gridDim.x >> 3) + (bi >> 3);
    int par = wlin & 3; int ry = par >> 1, rx = par & 1;
    int rest = wlin >> 2;
    int tw = IW >> 3, th = IH >> 3;
    int txi = rest % tw; rest /= tw;
    int tyi = rest % th; int n = rest / th;
    int a0 = tyi << 3, b0 = txi << 3;
    int by0 = ry ? 0 : -1, bx0 = rx ? 0 : -1;
    int OH = IH << 1, OW = IW << 1;

    int pb0[2];
    #pragma unroll
    for (int mi = 0; mi < 2; ++mi) {
        int m = wm * 32 + mi * 16 + (l & 15);
        int pa = m >> 3, pb_ = m & 7;
        pb0[mi] = (pa * 9 + pb_) * RST + g * 8;
    }

    f32x4 acc[2][2];
    f32x4 z4 = {0.f, 0.f, 0.f, 0.f};
    #pragma unroll
    for (int mi = 0; mi < 2; ++mi)
        #pragma unroll
        for (int ni = 0; ni < 2; ++ni) acc[mi][ni] = z4;

    auto ldB = [&](int icc, int tt, f16x8* B) {
        int tty = tt >> 1, ttx = tt & 1;
        int ky = 1 - ry + 2 * tty, kx = 1 - rx + 2 * ttx;
        int tap = ky * 4 + kx;
        #pragma unroll
        for (int ni = 0; ni < 2; ++ni)
            B[ni] = *(const f16x8*)&wdf[(size_t)((tap * ICC + icc) * 4 + wn * 2 + ni) * 512 + l * 8];
    };

    f16x8 B0[2], B1[2];
    {
        int icc0 = (bi >> 2) & (ICC - 1);
        ldB(icc0, bi & 3, B0);
    }

    for (int icci = 0; icci < ICC; ++icci) {
        int icc = (icci + (bi >> 2)) & (ICC - 1);
        __syncthreads();
        for (int i = t; i < 324; i += 256) {
            int c = i & 3; int pp = i >> 2;
            int pr = pp / 9, pc = pp - pr * 9;
            int ar = a0 + by0 + pr, ac = b0 + bx0 + pc;
            uint4 v = make_uint4(0u, 0u, 0u, 0u);
            if ((unsigned)ar < (unsigned)IH && (unsigned)ac < (unsigned)IW)
                v = *(const uint4*)&in[((n * IH + ar) * IW + ac) * ICT + icc * 32 + c * 8];
            *(uint4*)&patch[(pr * 9 + pc) * RST + c * 8] = v;
        }
        __syncthreads();
        #pragma unroll
        for (int tti = 0; tti < 4; ++tti) {
            int tt = (tti + bi) & 3;
            if (!(icci == ICC - 1 && tti == 3)) {
                int nicci = (tti == 3) ? icci + 1 : icci;
                int ntti = (tti == 3) ? 0 : tti + 1;
                int nicc = (nicci + (bi >> 2)) & (ICC - 1);
                ldB(nicc, (ntti + bi) & 3, B1);
            }
            int tty = tt >> 1, ttx = tt & 1;
            int shift = ((1 - tty) * 9 + (1 - ttx)) * RST;
            #pragma unroll
            for (int mi = 0; mi < 2; ++mi) {
                f16x8 a = *(const f16x8*)&patch[pb0[mi] + shift];
                #pragma unroll
                for (int ni = 0; ni < 2; ++ni)
                    acc[mi][ni] = __builtin_amdgcn_mfma_f32_16x16x32_f16(a, B0[ni], acc[mi][ni], 0, 0, 0);
            }
            B0[0] = B1[0]; B0[1] = B1[1];
        }
    }
    #pragma unroll
    for (int mi = 0; mi < 2; ++mi)
        #pragma unroll
        for (int ni = 0; ni < 2; ++ni) {
            int oc = wn * 32 + ni * 16 + (l & 15);
            float bv = bias[oc];
            #pragma unroll
            for (int reg = 0; reg < 4; ++reg) {
                float v = fmaxf(acc[mi][ni][reg] + bv, 0.f);
                int pix = wm * 32 + mi * 16 + g * 4 + reg;
                int oy = ((a0 + (pix >> 3)) << 1) + ry;
                int ox = ((b0 + (pix & 7)) << 1) + rx;
                out[((n * OH + oy) * OW + ox) * 64 + oc] = f2h(v);
            }
        }
}

// ============================ final conv 3x3 64->1, p1, tanh (LDS-tiled, v_dot2) ============================
__launch_bounds__(256)
__global__ void conv3x3_tanh_k(const u16* __restrict__ in, const float* __restrict__ w,
                               const float* __restrict__ b, float* __restrict__ out) {
    __shared__ u16 tile[18 * 18 * 72];
    __shared__ u32 wpk[288];   // [tap][icp] half2-packed weights
    int t = threadIdx.x;
    int bi = blockIdx.x;
    int wlin = (bi & 7) * ((int)gridDim.x >> 3) + (bi >> 3);
    int n = wlin >> 6;
    int tile6 = wlin & 63;
    int ty0 = (tile6 >> 3) << 4, tx0 = (tile6 & 7) << 4;

    for (int i = t; i < 288; i += 256) {
        int tap = i >> 5, icp = i & 31;
        h2 p;
        p.x = (f16)w[(2 * icp) * 9 + tap];
        p.y = (f16)w[(2 * icp + 1) * 9 + tap];
        wpk[tap * 32 + icp] = __builtin_bit_cast(u32, p);
    }
    for (int i = t; i < 2592; i += 256) {
        int ch = i & 7, pix = i >> 3;
        int pr = pix / 18, pc = pix - pr * 18;
        int gy = ty0 - 1 + pr, gx = tx0 - 1 + pc;
        uint4 v = make_uint4(0u, 0u, 0u, 0u);
        if ((unsigned)gy < 128u && (unsigned)gx < 128u)
            v = *(const uint4*)&in[(((n << 7) + gy) * 128 + gx) * 64 + ch * 8];
        *(uint4*)&tile[pix * 72 + ch * 8] = v;
    }
    __syncthreads();

    int ty = t >> 4, tx = t & 15;
    float acc = b[0];
    #pragma unroll
    for (int dy = 0; dy < 3; ++dy) {
        #pragma unroll
        for (int dx = 0; dx < 3; ++dx) {
            int base = ((ty + dy) * 18 + (tx + dx)) * 72;
            const u32* wp = &wpk[(dy * 3 + dx) * 32];
            #pragma unroll
            for (int c8 = 0; c8 < 8; ++c8) {
                uint4 v = *(const uint4*)&tile[base + c8 * 8];
                acc = __builtin_amdgcn_fdot2(__builtin_bit_cast(h2, v.x),
                        __builtin_bit_cast(h2, wp[c8 * 4 + 0]), acc, false);
                acc = __builtin_amdgcn_fdot2(__builtin_bit_cast(h2, v.y),
                        __builtin_bit_cast(h2, wp[c8 * 4 + 1]), acc, false);
                acc = __builtin_amdgcn_fdot2(__builtin_bit_cast(h2, v.z),
                        __builtin_bit_cast(h2, wp[c8 * 4 + 2]), acc, false);
                acc = __builtin_amdgcn_fdot2(__builtin_bit_cast(h2, v.w),
                        __builtin_bit_cast(h2, wp[c8 * 4 + 3]), acc, false);
            }
        }
    }
    int oy = ty0 + ty, ox = tx0 + tx;
    out[(n << 14) + (oy << 7) + ox] = tanhf(acc);
}

extern "C" void kernel_launch(void* const* d_in, const int* in_sizes, int n_in,
                              void* d_out, int out_size, void* d_ws, size_t ws_size,
                              hipStream_t stream) {
    (void)in_sizes; (void)n_in; (void)out_size; (void)ws_size;
    const float* x   = (const float*)d_in[0];
    const float* ew1 = (const float*)d_in[1];
    const float* eb1 = (const float*)d_in[2];
    const float* ew2 = (const float*)d_in[3];
    const float* eb2 = (const float*)d_in[4];
    const float* ew3 = (const float*)d_in[5];
    const float* eb3 = (const float*)d_in[6];
    const float* cb  = (const float*)d_in[7];
    const float* dw1 = (const float*)d_in[8];
    const float* db1 = (const float*)d_in[9];
    const float* dw2 = (const float*)d_in[10];
    const float* db2 = (const float*)d_in[11];
    const float* dw3 = (const float*)d_in[12];
    const float* db3 = (const float*)d_in[13];
    float* out = (float*)d_out;

    u16* ws = (u16*)d_ws;
    u16* a1h = ws;             u16* a1l = ws + 16777216;
    u16* zh  = ws;             u16* zl  = ws + 16777216;
    u16* a2h = ws + 33554432;  u16* a2l = ws + 50331648;
    u16* e   = ws + 33554432;
    u16* y1  = ws + 67108864;
    u16* y2  = ws;
    u16* wBf2 = ws + 83886080;          // 204800
    u16* wBf3 = wBf2 + 204800;          // 819200
    u16* wd1f = wBf3 + 819200;          // 262144
    u16* wd2f = wd1f + 262144;          // 65536
    u16* cbf  = wd2f + 65536;           // 524288
    float* cbn = (float*)(cbf + 524288);

    hipMemsetAsync(out + 1048576, 0, 4, stream);  // diff accumulator

    prep_wconv_k<<<800, 256, 0, stream>>>(ew2, wBf2, 2);   // NF=4
    prep_wconv_k<<<3200, 256, 0, stream>>>(ew3, wBf3, 4);  // NF=16
    prep_wdec_k<<<1024, 256, 0, stream>>>(dw1, wd1f, 3);   // ICC=8
    prep_wdec_k<<<256, 256, 0, stream>>>(dw2, wd2f, 1);    // ICC=2
    prep_cb_k<<<2048, 256, 0, stream>>>(cb, cbf);
    prep_cbn_k<<<4, 256, 0, stream>>>(cb, cbn);

    conv1_k<<<1024, 256, 0, stream>>>(x, ew1, eb1, a1h, a1l);
    conv5_k<1, 64, 2, true><<<4096, 256, 0, stream>>>(a1h, a1l, wBf2, eb2, a2h, a2l, 64, 64, 64, 64);
    conv5_k<2, 256, 4, false><<<2048, 256, 0, stream>>>(a2h, a2l, wBf3, eb3, zh, zl, 64, 64, 32, 32);
    quant_k<<<512, 256, 0, stream>>>(zh, zl, cbf, cbn, cb, e, out + 1048576);
    deconv4_k<256><<<4096, 256, 0, stream>>>(e, wd1f, db1, y1, 32, 32);
    deconv4_k<64><<<16384, 256, 0, stream>>>(y1, wd2f, db2, y2, 64, 64);
    conv3x3_tanh_k<<<4096, 256, 0, stream>>>(y2, dw3, db3, out);
}

// Round 11
// 702.839 us; speedup vs baseline: 1.3531x; 1.0076x over previous
//
#include <hip/hip_runtime.h>

typedef _Float16 f16;
typedef _Float16 f16x8 __attribute__((ext_vector_type(8)));
typedef _Float16 f16x4 __attribute__((ext_vector_type(4)));
typedef _Float16 h2 __attribute__((ext_vector_type(2)));
typedef float f32x4 __attribute__((ext_vector_type(4)));
typedef unsigned short u16;
typedef unsigned int u32;

#define DEVI __device__ __forceinline__

DEVI u16 f2h(float f) { f16 h = (f16)f; return __builtin_bit_cast(u16, h); }
DEVI float h2f(u16 u) { f16 h = __builtin_bit_cast(f16, u); return (float)h; }

// ============================ weight prep ============================
__launch_bounds__(256)
__global__ void prep_wconv_k(const float* __restrict__ src, u16* __restrict__ dst, int nf_sh) {
    int i = blockIdx.x * 256 + threadIdx.x;
    int j = i & 7, lane = (i >> 3) & 63;
    int q = i >> 9;
    int f = q & ((1 << nf_sh) - 1); q >>= nf_sh;
    int pl = q & 1; q >>= 1;
    int icc = q & 1; int tap = q >> 1;
    int oc = (f << 4) + (lane & 15);
    int ic = icc * 32 + ((lane >> 4) << 3) + j;
    float w = src[(oc * 64 + ic) * 25 + tap];
    if (pl == 0) dst[i] = f2h(w);
    else         dst[i] = f2h((w - h2f(f2h(w))) * 4096.f);
}
__launch_bounds__(256)
__global__ void prep_wdec_k(const float* __restrict__ src, u16* __restrict__ dst, int icc_sh) {
    int i = blockIdx.x * 256 + threadIdx.x;
    int j = i & 7, lane = (i >> 3) & 63;
    int f = (i >> 9) & 3;
    int q = i >> 11;
    int icc = q & ((1 << icc_sh) - 1); int tap = q >> icc_sh;
    int oc = (f << 4) + (lane & 15);
    int ic = icc * 32 + ((lane >> 4) << 3) + j;
    dst[i] = f2h(src[(ic * 64 + oc) * 16 + tap]);
}
__launch_bounds__(256)
__global__ void prep_cb_k(const float* __restrict__ cb, u16* __restrict__ dst) {
    int i = blockIdx.x * 256 + threadIdx.x;   // 524288
    int j = i & 7, lane = (i >> 3) & 63;
    int f = (i >> 9) & 63;
    int q = i >> 15;
    int pl = q & 1; int ks = q >> 1;
    int n = (f << 4) + (lane & 15);
    int k = ks * 32 + ((lane >> 4) << 3) + j;
    float w = cb[n * 256 + k];
    if (pl == 0) dst[i] = f2h(w);
    else         dst[i] = f2h((w - h2f(f2h(w))) * 4096.f);
}
__launch_bounds__(256)
__global__ void prep_cbn_k(const float* __restrict__ cb, float* __restrict__ cbn) {
    int row = blockIdx.x * 256 + threadIdx.x;          // 1024
    float s = 0.f;
    for (int c = 0; c < 256; c += 4) {
        f32x4 v = *(const f32x4*)&cb[row * 256 + c];
        s = fmaf(v.x, v.x, s); s = fmaf(v.y, v.y, s);
        s = fmaf(v.z, v.z, s); s = fmaf(v.w, v.w, s);
    }
    cbn[row] = s;
}

// ============================ conv1: 1->64, 5x5 s2 p2, relu, split-fp16 out ============================
__launch_bounds__(256)
__global__ void conv1_k(const float* __restrict__ x, const float* __restrict__ w,
                        const float* __restrict__ b, u16* __restrict__ oh, u16* __restrict__ ol) {
    __shared__ float wl[25 * 64];
    __shared__ float bl[64];
    int t = threadIdx.x;
    for (int i = t; i < 1600; i += 256) wl[(i % 25) * 64 + i / 25] = w[i];
    if (t < 64) bl[t] = b[t];
    __syncthreads();
    int p = blockIdx.x * 256 + t;                       // 262144 pixels
    int ox = p & 63, oy = (p >> 6) & 63, n = p >> 12;
    f32x4 acc[16];
    #pragma unroll
    for (int c = 0; c < 16; ++c) acc[c] = *(f32x4*)&bl[c * 4];
    for (int dy = 0; dy < 5; ++dy) {
        int iy = 2 * oy - 2 + dy;
        if ((unsigned)iy >= 128u) continue;
        for (int dx = 0; dx < 5; ++dx) {
            int ix = 2 * ox - 2 + dx;
            if ((unsigned)ix >= 128u) continue;
            float v = x[(n * 128 + iy) * 128 + ix];
            const float* wp = &wl[(dy * 5 + dx) * 64];
            #pragma unroll
            for (int c = 0; c < 16; ++c) {
                f32x4 w4 = *(const f32x4*)&wp[c * 4];
                acc[c].x = fmaf(v, w4.x, acc[c].x); acc[c].y = fmaf(v, w4.y, acc[c].y);
                acc[c].z = fmaf(v, w4.z, acc[c].z); acc[c].w = fmaf(v, w4.w, acc[c].w);
            }
        }
    }
    #pragma unroll
    for (int c = 0; c < 16; ++c) {
        ushort4 uh, ul;
        float vv[4] = {acc[c].x, acc[c].y, acc[c].z, acc[c].w};
        u16 rh[4], rl[4];
        #pragma unroll
        for (int k = 0; k < 4; ++k) {
            float v = fmaxf(vv[k], 0.f);
            f16 hh = (f16)v;
            rh[k] = __builtin_bit_cast(u16, hh);
            rl[k] = f2h((v - (float)hh) * 4096.f);
        }
        uh.x = rh[0]; uh.y = rh[1]; uh.z = rh[2]; uh.w = rh[3];
        ul.x = rl[0]; ul.y = rl[1]; ul.z = rl[2]; ul.w = rl[3];
        *(ushort4*)&oh[p * 64 + c * 4] = uh;
        *(ushort4*)&ol[p * 64 + c * 4] = ul;
    }
}

// ============================ split-fp16 MFMA 5x5 conv, mi=4 (64 pix/wave) ============================
// Wave = 64 pixels x 64 oc (mi=4, ni=4, 48 MFMAs/tap) -> B bytes per FLOP halved vs mi=2.
// PARTOC=true (conv3): 8x8 tile, waves partition oc (wv*64).
// PARTOC=false (conv2): 16x16 tile, waves partition pixels (rows wv*4..wv*4+3); all
//   waves read identical B fragments in lockstep -> L1 broadcast.
// LDS: pixel pair P=pp>>1 owns a 64-half line; chunk c of parity r at slot (P+2c+r)&7.
template<int S, int OCT, bool PARTOC, int TH, int TW, bool RELU>
__launch_bounds__(256)
__global__ void conv5_k(const u16* __restrict__ Ah_g, const u16* __restrict__ Al_g,
                        const u16* __restrict__ wBf, const float* __restrict__ bias,
                        u16* __restrict__ Oh, u16* __restrict__ Ol,
                        int IH, int IW, int OH, int OW) {
    constexpr int PATCH_H = S * (TH - 1) + 5;
    constexpr int PATCH_W = S * (TW - 1) + 5;
    constexpr int NPIX = PATCH_H * PATCH_W;
    constexpr int NPAIR = (NPIX + 1) / 2;
    constexpr int PLSZ = NPAIR * 64;
    constexpr int NF = OCT / 16;
    __shared__ u16 patch[2 * PLSZ];

    int t = threadIdx.x, l = t & 63, wv = t >> 6, g = l >> 4;

    int bi = blockIdx.x;
    int wlin = (bi & 7) * ((int)gridDim.x >> 3) + (bi >> 3);   // XCD slab
    int tw = OW / TW, th = OH / TH;
    int rest = wlin;
    int txi = rest % tw; rest /= tw;
    int tyi = rest % th; int n = rest / th;
    int iy0 = S * (tyi * TH) - 2, ix0 = S * (txi * TW) - 2;

    int ppb[4];
    #pragma unroll
    for (int mi = 0; mi < 4; ++mi) {
        if (PARTOC) {
            int m = mi * 16 + (l & 15);
            ppb[mi] = (S * (m >> 3)) * PATCH_W + S * (m & 7);
        } else {
            ppb[mi] = (S * (wv * 4 + mi)) * PATCH_W + S * (l & 15);
        }
    }

    f32x4 acc0[4][4], acc1[4][4];
    f32x4 z4 = {0.f, 0.f, 0.f, 0.f};
    #pragma unroll
    for (int mi = 0; mi < 4; ++mi)
        #pragma unroll
        for (int ni = 0; ni < 4; ++ni) { acc0[mi][ni] = z4; acc1[mi][ni] = z4; }

    int tap0 = bi % 25;
    int dy0 = tap0 / 5, dx0 = tap0 - 5 * dy0;
    int tadd0 = dy0 * PATCH_W + dx0;
    int iccr = bi & 1;
    int fgbase = PARTOC ? (wv * 4) : 0;
    const size_t tstride = (size_t)(4 * NF) * 512;

    for (int icci = 0; icci < 2; ++icci) {
        int icc = icci ^ iccr;
        __syncthreads();
        for (int i = t; i < NPIX * 8; i += 256) {
            int c = i & 3; int r2 = i >> 2;
            int pl = (r2 >= NPIX); int pp = r2 - pl * NPIX;
            int py = pp / PATCH_W, px = pp - py * PATCH_W;
            int iy = iy0 + py, ix = ix0 + px;
            uint4 v = make_uint4(0u, 0u, 0u, 0u);
            if ((unsigned)iy < (unsigned)IH && (unsigned)ix < (unsigned)IW)
                v = *(const uint4*)&(pl ? Al_g : Ah_g)[(((n * IH + iy) * IW + ix)) * 64 + icc * 32 + c * 8];
            int P = pp >> 1, r = pp & 1;
            *(uint4*)&patch[pl * PLSZ + (P << 6) + (((P + (c << 1) + r) & 7) << 3)] = v;
        }
        __syncthreads();

        const u16* pB = wBf + (size_t)((tap0 * 4 + icc * 2) * NF + fgbase) * 512 + l * 8;
        int tap = tap0, dx = dx0, tadd = tadd0;
        for (int tapi = 0; tapi < 25; ++tapi) {
            f16x8 Bh[4], Bl[4];
            #pragma unroll
            for (int ni = 0; ni < 4; ++ni) {
                Bh[ni] = *(const f16x8*)&pB[ni * 512];
                Bl[ni] = *(const f16x8*)&pB[(NF + ni) * 512];
            }
            f16x8 ah[4], al[4];
            #pragma unroll
            for (int mi = 0; mi < 4; ++mi) {
                int pp = ppb[mi] + tadd;
                int P = pp >> 1, r = pp & 1;
                int offs = (P << 6) + (((P + (g << 1) + r) & 7) << 3);
                ah[mi] = *(const f16x8*)&patch[offs];
                al[mi] = *(const f16x8*)&patch[PLSZ + offs];
            }
            #pragma unroll
            for (int mi = 0; mi < 4; ++mi)
                #pragma unroll
                for (int ni = 0; ni < 4; ++ni) {
                    acc0[mi][ni] = __builtin_amdgcn_mfma_f32_16x16x32_f16(ah[mi], Bh[ni], acc0[mi][ni], 0, 0, 0);
                    acc1[mi][ni] = __builtin_amdgcn_mfma_f32_16x16x32_f16(ah[mi], Bl[ni], acc1[mi][ni], 0, 0, 0);
                    acc1[mi][ni] = __builtin_amdgcn_mfma_f32_16x16x32_f16(al[mi], Bh[ni], acc1[mi][ni], 0, 0, 0);
                }
            pB = (tap == 24) ? (pB - 24 * tstride) : (pB + tstride);
            if (tap == 24) { tap = 0; dx = 0; tadd = 0; }
            else {
                tap++; dx++; tadd++;
                if (dx == 5) { dx = 0; tadd += PATCH_W - 5; }
            }
        }
    }
    #pragma unroll
    for (int mi = 0; mi < 4; ++mi)
        #pragma unroll
        for (int ni = 0; ni < 4; ++ni) {
            int oc = fgbase * 16 + ni * 16 + (l & 15);
            float bv = bias[oc];
            #pragma unroll
            for (int reg = 0; reg < 4; ++reg) {
                float v = acc0[mi][ni][reg] + acc1[mi][ni][reg] * (1.f / 4096.f) + bv;
                if (RELU) v = fmaxf(v, 0.f);
                int oy, ox;
                if (PARTOC) {
                    int pix = mi * 16 + g * 4 + reg;
                    oy = tyi * TH + (pix >> 3); ox = txi * TW + (pix & 7);
                } else {
                    oy = tyi * TH + wv * 4 + mi; ox = txi * TW + g * 4 + reg;
                }
                int idx = ((n * OH + oy) * OW + ox) * OCT + oc;
                f16 hh = (f16)v;
                Oh[idx] = __builtin_bit_cast(u16, hh);
                Ol[idx] = f2h((v - (float)hh) * 4096.f);
            }
        }
}

// ============================ quantize v4: A-in-registers, B via LDS double-buffer ============================
__launch_bounds__(256, 2)
__global__ void quant_k(const u16* __restrict__ zh, const u16* __restrict__ zl,
                        const u16* __restrict__ cbf, const float* __restrict__ cbn,
                        const float* __restrict__ cb, u16* __restrict__ e,
                        float* __restrict__ diff) {
    __shared__ u16 Bbuf[2 * 32 * 512];     // [buf][ks*4+pl*2+nf][lane*8]
    __shared__ float cbn_l[1024];
    __shared__ float zn_l[128];
    __shared__ float bd_l[128];
    __shared__ int   wi_l[128];

    int t = threadIdx.x, l = t & 63, wv = t >> 6, g = l >> 4;
    int bi = blockIdx.x;
    int row0 = bi << 7;

    {
        f32x4 v = *(const f32x4*)&cbn[t * 4];
        *(f32x4*)&cbn_l[t * 4] = v;
    }

    f16x8 Ah[2][8], Al[2][8];
    int rbase = row0 + wv * 32 + (l & 15);
    #pragma unroll
    for (int mi = 0; mi < 2; ++mi)
        #pragma unroll
        for (int ks = 0; ks < 8; ++ks) {
            size_t off = (size_t)(rbase + mi * 16) * 256 + ks * 32 + g * 8;
            Ah[mi][ks] = *(const f16x8*)&zh[off];
            Al[mi][ks] = *(const f16x8*)&zl[off];
        }

    #pragma unroll
    for (int mi = 0; mi < 2; ++mi) {
        float s = 0.f;
        #pragma unroll
        for (int ks = 0; ks < 8; ++ks)
            #pragma unroll
            for (int j = 0; j < 8; ++j) {
                float v = (float)Ah[mi][ks][j] + (float)Al[mi][ks][j] * (1.f / 4096.f);
                s = fmaf(v, v, s);
            }
        s += __shfl_xor(s, 16);
        s += __shfl_xor(s, 32);
        if (g == 0) zn_l[wv * 32 + mi * 16 + (l & 15)] = s;
    }

    float rd[8]; int rc[8];
    #pragma unroll
    for (int s = 0; s < 8; ++s) { rd[s] = 1e30f; rc[s] = 0; }

    int fi = wv * 8;
    {
        int no0 = bi & 31;
        #pragma unroll
        for (int q = 0; q < 8; ++q) {
            int f2 = fi + q;
            int ks = f2 >> 2, pl = (f2 >> 1) & 1, nf = f2 & 1;
            f16x8 v = *(const f16x8*)&cbf[(size_t)(((ks * 2 + pl) * 64) + no0 * 2 + nf) * 512 + l * 8];
            *(uint4*)&Bbuf[(size_t)f2 * 512 + l * 8] = __builtin_bit_cast(uint4, v);
        }
    }
    __syncthreads();

    for (int noi = 0; noi < 32; ++noi) {
        int b = noi & 1;
        int no_cur = (noi + bi) & 31;

        f16x8 pf[8];
        if (noi < 31) {
            int no_n = (noi + 1 + bi) & 31;
            #pragma unroll
            for (int q = 0; q < 8; ++q) {
                int f2 = fi + q;
                int ks = f2 >> 2, pl = (f2 >> 1) & 1, nf = f2 & 1;
                pf[q] = *(const f16x8*)&cbf[(size_t)(((ks * 2 + pl) * 64) + no_n * 2 + nf) * 512 + l * 8];
            }
        }

        f32x4 acc0[2][2], acc1[2][2];
        f32x4 z4 = {0.f, 0.f, 0.f, 0.f};
        #pragma unroll
        for (int mi = 0; mi < 2; ++mi)
            #pragma unroll
            for (int nf = 0; nf < 2; ++nf) { acc0[mi][nf] = z4; acc1[mi][nf] = z4; }

        #pragma unroll
        for (int ks = 0; ks < 8; ++ks) {
            const u16* bb = &Bbuf[(size_t)(b * 32 + ks * 4) * 512 + l * 8];
            f16x8 Bh0 = *(const f16x8*)&bb[0 * 512];
            f16x8 Bh1 = *(const f16x8*)&bb[1 * 512];
            f16x8 Bl0 = *(const f16x8*)&bb[2 * 512];
            f16x8 Bl1 = *(const f16x8*)&bb[3 * 512];
            #pragma unroll
            for (int mi = 0; mi < 2; ++mi) {
                acc0[mi][0] = __builtin_amdgcn_mfma_f32_16x16x32_f16(Ah[mi][ks], Bh0, acc0[mi][0], 0, 0, 0);
                acc0[mi][1] = __builtin_amdgcn_mfma_f32_16x16x32_f16(Ah[mi][ks], Bh1, acc0[mi][1], 0, 0, 0);
                acc1[mi][0] = __builtin_amdgcn_mfma_f32_16x16x32_f16(Ah[mi][ks], Bl0, acc1[mi][0], 0, 0, 0);
                acc1[mi][0] = __builtin_amdgcn_mfma_f32_16x16x32_f16(Al[mi][ks], Bh0, acc1[mi][0], 0, 0, 0);
                acc1[mi][1] = __builtin_amdgcn_mfma_f32_16x16x32_f16(Ah[mi][ks], Bl1, acc1[mi][1], 0, 0, 0);
                acc1[mi][1] = __builtin_amdgcn_mfma_f32_16x16x32_f16(Al[mi][ks], Bh1, acc1[mi][1], 0, 0, 0);
            }
        }

        #pragma unroll
        for (int nf = 0; nf < 2; ++nf) {
            int col = no_cur * 32 + nf * 16 + (l & 15);
            float cn = cbn_l[col];
            #pragma unroll
            for (int mi = 0; mi < 2; ++mi)
                #pragma unroll
                for (int reg = 0; reg < 4; ++reg) {
                    float d = cn - 2.f * (acc0[mi][nf][reg] + acc1[mi][nf][reg] * (1.f / 4096.f));
                    int slot = mi * 4 + reg;
                    if (d < rd[slot] || (d == rd[slot] && col < rc[slot])) { rd[slot] = d; rc[slot] = col; }
                }
        }

        if (noi < 31) {
            #pragma unroll
            for (int q = 0; q < 8; ++q)
                *(uint4*)&Bbuf[(size_t)((1 - b) * 32 + fi + q) * 512 + l * 8] = __builtin_bit_cast(uint4, pf[q]);
        }
        __syncthreads();
    }

    #pragma unroll
    for (int step = 1; step < 16; step <<= 1) {
        #pragma unroll
        for (int s = 0; s < 8; ++s) {
            float od = __shfl_xor(rd[s], step);
            int ocl = __shfl_xor(rc[s], step);
            if (od < rd[s] || (od == rd[s] && ocl < rc[s])) { rd[s] = od; rc[s] = ocl; }
        }
    }
    if ((l & 15) == 0) {
        #pragma unroll
        for (int s = 0; s < 8; ++s) {
            int mi = s >> 2, reg = s & 3;
            int row = wv * 32 + mi * 16 + g * 4 + reg;
            bd_l[row] = rd[s]; wi_l[row] = rc[s];
        }
    }
    __syncthreads();
    if (t < 64) {
        float dval = (zn_l[t] + bd_l[t]) + (zn_l[t + 64] + bd_l[t + 64]);
        #pragma unroll
        for (int step = 1; step < 64; step <<= 1) dval += __shfl_xor(dval, step);
        if (t == 0) atomicAdd(diff, dval * (1.f / 16777216.f));
    }
    __syncthreads();
    for (int r = 0; r < 128; ++r) {
        int wi = wi_l[r];
        e[(size_t)(row0 + r) * 256 + t] = f2h(cb[wi * 256 + t]);
    }
}

// ============================ plain-fp16 MFMA deconv k4 s2 p1, B prefetched, XCD swizzle ============================
template<int ICT>
__launch_bounds__(256)
__global__ void deconv4_k(const u16* __restrict__ in, const u16* __restrict__ wdf,
                          const float* __restrict__ bias, u16* __restrict__ out,
                          int IH, int IW) {
    constexpr int RST = 40;
    constexpr int ICC = ICT / 32;
    constexpr int PLSZ = 81 * RST;
    __shared__ u16 patch[PLSZ];

    int t = threadIdx.x, l = t & 63, wv = t >> 6;
    int wm = wv >> 1, wn = wv & 1, g = l >> 4;

    int bi = blockIdx.x;
    int wlin = (bi & 7) * ((int)gridDim.x >> 3) + (bi >> 3);
    int par = wlin & 3; int ry = par >> 1, rx = par & 1;
    int rest = wlin >> 2;
    int tw = IW >> 3, th = IH >> 3;
    int txi = rest % tw; rest /= tw;
    int tyi = rest % th; int n = rest / th;
    int a0 = tyi << 3, b0 = txi << 3;
    int by0 = ry ? 0 : -1, bx0 = rx ? 0 : -1;
    int OH = IH << 1, OW = IW << 1;

    int pb0[2];
    #pragma unroll
    for (int mi = 0; mi < 2; ++mi) {
        int m = wm * 32 + mi * 16 + (l & 15);
        int pa = m >> 3, pb_ = m & 7;
        pb0[mi] = (pa * 9 + pb_) * RST + g * 8;
    }

    f32x4 acc[2][2];
    f32x4 z4 = {0.f, 0.f, 0.f, 0.f};
    #pragma unroll
    for (int mi = 0; mi < 2; ++mi)
        #pragma unroll
        for (int ni = 0; ni < 2; ++ni) acc[mi][ni] = z4;

    auto ldB = [&](int icc, int tt, f16x8* B) {
        int tty = tt >> 1, ttx = tt & 1;
        int ky = 1 - ry + 2 * tty, kx = 1 - rx + 2 * ttx;
        int tap = ky * 4 + kx;
        #pragma unroll
        for (int ni = 0; ni < 2; ++ni)
            B[ni] = *(const f16x8*)&wdf[(size_t)((tap * ICC + icc) * 4 + wn * 2 + ni) * 512 + l * 8];
    };

    f16x8 B0[2], B1[2];
    {
        int icc0 = (bi >> 2) & (ICC - 1);
        ldB(icc0, bi & 3, B0);
    }

    for (int icci = 0; icci < ICC; ++icci) {
        int icc = (icci + (bi >> 2)) & (ICC - 1);
        __syncthreads();
        for (int i = t; i < 324; i += 256) {
            int c = i & 3; int pp = i >> 2;
            int pr = pp / 9, pc = pp - pr * 9;
            int ar = a0 + by0 + pr, ac = b0 + bx0 + pc;
            uint4 v = make_uint4(0u, 0u, 0u, 0u);
            if ((unsigned)ar < (unsigned)IH && (unsigned)ac < (unsigned)IW)
                v = *(const uint4*)&in[((n * IH + ar) * IW + ac) * ICT + icc * 32 + c * 8];
            *(uint4*)&patch[(pr * 9 + pc) * RST + c * 8] = v;
        }
        __syncthreads();
        #pragma unroll
        for (int tti = 0; tti < 4; ++tti) {
            int tt = (tti + bi) & 3;
            if (!(icci == ICC - 1 && tti == 3)) {
                int nicci = (tti == 3) ? icci + 1 : icci;
                int ntti = (tti == 3) ? 0 : tti + 1;
                int nicc = (nicci + (bi >> 2)) & (ICC - 1);
                ldB(nicc, (ntti + bi) & 3, B1);
            }
            int tty = tt >> 1, ttx = tt & 1;
            int shift = ((1 - tty) * 9 + (1 - ttx)) * RST;
            #pragma unroll
            for (int mi = 0; mi < 2; ++mi) {
                f16x8 a = *(const f16x8*)&patch[pb0[mi] + shift];
                #pragma unroll
                for (int ni = 0; ni < 2; ++ni)
                    acc[mi][ni] = __builtin_amdgcn_mfma_f32_16x16x32_f16(a, B0[ni], acc[mi][ni], 0, 0, 0);
            }
            B0[0] = B1[0]; B0[1] = B1[1];
        }
    }
    #pragma unroll
    for (int mi = 0; mi < 2; ++mi)
        #pragma unroll
        for (int ni = 0; ni < 2; ++ni) {
            int oc = wn * 32 + ni * 16 + (l & 15);
            float bv = bias[oc];
            #pragma unroll
            for (int reg = 0; reg < 4; ++reg) {
                float v = fmaxf(acc[mi][ni][reg] + bv, 0.f);
                int pix = wm * 32 + mi * 16 + g * 4 + reg;
                int oy = ((a0 + (pix >> 3)) << 1) + ry;
                int ox = ((b0 + (pix & 7)) << 1) + rx;
                out[((n * OH + oy) * OW + ox) * 64 + oc] = f2h(v);
            }
        }
}

// ============================ final conv 3x3 64->1, p1, tanh (LDS-tiled, v_dot2) ============================
__launch_bounds__(256)
__global__ void conv3x3_tanh_k(const u16* __restrict__ in, const float* __restrict__ w,
                               const float* __restrict__ b, float* __restrict__ out) {
    __shared__ u16 tile[18 * 18 * 72];
    __shared__ u32 wpk[288];   // [tap][icp] half2-packed weights
    int t = threadIdx.x;
    int bi = blockIdx.x;
    int wlin = (bi & 7) * ((int)gridDim.x >> 3) + (bi >> 3);
    int n = wlin >> 6;
    int tile6 = wlin & 63;
    int ty0 = (tile6 >> 3) << 4, tx0 = (tile6 & 7) << 4;

    for (int i = t; i < 288; i += 256) {
        int tap = i >> 5, icp = i & 31;
        h2 p;
        p.x = (f16)w[(2 * icp) * 9 + tap];
        p.y = (f16)w[(2 * icp + 1) * 9 + tap];
        wpk[tap * 32 + icp] = __builtin_bit_cast(u32, p);
    }
    for (int i = t; i < 2592; i += 256) {
        int ch = i & 7, pix = i >> 3;
        int pr = pix / 18, pc = pix - pr * 18;
        int gy = ty0 - 1 + pr, gx = tx0 - 1 + pc;
        uint4 v = make_uint4(0u, 0u, 0u, 0u);
        if ((unsigned)gy < 128u && (unsigned)gx < 128u)
            v = *(const uint4*)&in[(((n << 7) + gy) * 128 + gx) * 64 + ch * 8];
        *(uint4*)&tile[pix * 72 + ch * 8] = v;
    }
    __syncthreads();

    int ty = t >> 4, tx = t & 15;
    float acc = b[0];
    #pragma unroll
    for (int dy = 0; dy < 3; ++dy) {
        #pragma unroll
        for (int dx = 0; dx < 3; ++dx) {
            int base = ((ty + dy) * 18 + (tx + dx)) * 72;
            const u32* wp = &wpk[(dy * 3 + dx) * 32];
            #pragma unroll
            for (int c8 = 0; c8 < 8; ++c8) {
                uint4 v = *(const uint4*)&tile[base + c8 * 8];
                acc = __builtin_amdgcn_fdot2(__builtin_bit_cast(h2, v.x),
                        __builtin_bit_cast(h2, wp[c8 * 4 + 0]), acc, false);
                acc = __builtin_amdgcn_fdot2(__builtin_bit_cast(h2, v.y),
                        __builtin_bit_cast(h2, wp[c8 * 4 + 1]), acc, false);
                acc = __builtin_amdgcn_fdot2(__builtin_bit_cast(h2, v.z),
                        __builtin_bit_cast(h2, wp[c8 * 4 + 2]), acc, false);
                acc = __builtin_amdgcn_fdot2(__builtin_bit_cast(h2, v.w),
                        __builtin_bit_cast(h2, wp[c8 * 4 + 3]), acc, false);
            }
        }
    }
    int oy = ty0 + ty, ox = tx0 + tx;
    out[(n << 14) + (oy << 7) + ox] = tanhf(acc);
}

extern "C" void kernel_launch(void* const* d_in, const int* in_sizes, int n_in,
                              void* d_out, int out_size, void* d_ws, size_t ws_size,
                              hipStream_t stream) {
    (void)in_sizes; (void)n_in; (void)out_size; (void)ws_size;
    const float* x   = (const float*)d_in[0];
    const float* ew1 = (const float*)d_in[1];
    const float* eb1 = (const float*)d_in[2];
    const float* ew2 = (const float*)d_in[3];
    const float* eb2 = (const float*)d_in[4];
    const float* ew3 = (const float*)d_in[5];
    const float* eb3 = (const float*)d_in[6];
    const float* cb  = (const float*)d_in[7];
    const float* dw1 = (const float*)d_in[8];
    const float* db1 = (const float*)d_in[9];
    const float* dw2 = (const float*)d_in[10];
    const float* db2 = (const float*)d_in[11];
    const float* dw3 = (const float*)d_in[12];
    const float* db3 = (const float*)d_in[13];
    float* out = (float*)d_out;

    u16* ws = (u16*)d_ws;
    u16* a1h = ws;             u16* a1l = ws + 16777216;
    u16* zh  = ws;             u16* zl  = ws + 16777216;
    u16* a2h = ws + 33554432;  u16* a2l = ws + 50331648;
    u16* e   = ws + 33554432;
    u16* y1  = ws + 67108864;
    u16* y2  = ws;
    u16* wBf2 = ws + 83886080;          // 204800
    u16* wBf3 = wBf2 + 204800;          // 819200
    u16* wd1f = wBf3 + 819200;          // 262144
    u16* wd2f = wd1f + 262144;          // 65536
    u16* cbf  = wd2f + 65536;           // 524288
    float* cbn = (float*)(cbf + 524288);

    hipMemsetAsync(out + 1048576, 0, 4, stream);  // diff accumulator

    prep_wconv_k<<<800, 256, 0, stream>>>(ew2, wBf2, 2);   // NF=4
    prep_wconv_k<<<3200, 256, 0, stream>>>(ew3, wBf3, 4);  // NF=16
    prep_wdec_k<<<1024, 256, 0, stream>>>(dw1, wd1f, 3);   // ICC=8
    prep_wdec_k<<<256, 256, 0, stream>>>(dw2, wd2f, 1);    // ICC=2
    prep_cb_k<<<2048, 256, 0, stream>>>(cb, cbf);
    prep_cbn_k<<<4, 256, 0, stream>>>(cb, cbn);

    conv1_k<<<1024, 256, 0, stream>>>(x, ew1, eb1, a1h, a1l);
    conv5_k<1, 64, false, 16, 16, true><<<1024, 256, 0, stream>>>(a1h, a1l, wBf2, eb2, a2h, a2l, 64, 64, 64, 64);
    conv5_k<2, 256, true, 8, 8, false><<<1024, 256, 0, stream>>>(a2h, a2l, wBf3, eb3, zh, zl, 64, 64, 32, 32);
    quant_k<<<512, 256, 0, stream>>>(zh, zl, cbf, cbn, cb, e, out + 1048576);
    deconv4_k<256><<<4096, 256, 0, stream>>>(e, wd1f, db1, y1, 32, 32);
    deconv4_k<64><<<16384, 256, 0, stream>>>(y1, wd2f, db2, y2, 64, 64);
    conv3x3_tanh_k<<<4096, 256, 0, stream>>>(y2, dw3, db3, out);
}

// Round 12
// 698.320 us; speedup vs baseline: 1.3619x; 1.0065x over previous
//
#include <hip/hip_runtime.h>

typedef _Float16 f16;
typedef _Float16 f16x8 __attribute__((ext_vector_type(8)));
typedef _Float16 f16x4 __attribute__((ext_vector_type(4)));
typedef _Float16 h2 __attribute__((ext_vector_type(2)));
typedef float f32x4 __attribute__((ext_vector_type(4)));
typedef unsigned short u16;
typedef unsigned int u32;

#define DEVI __device__ __forceinline__

DEVI u16 f2h(float f) { f16 h = (f16)f; return __builtin_bit_cast(u16, h); }
DEVI float h2f(u16 u) { f16 h = __builtin_bit_cast(f16, u); return (float)h; }

// ============================ weight prep ============================
__launch_bounds__(256)
__global__ void prep_wconv_k(const float* __restrict__ src, u16* __restrict__ dst, int nf_sh) {
    int i = blockIdx.x * 256 + threadIdx.x;
    int j = i & 7, lane = (i >> 3) & 63;
    int q = i >> 9;
    int f = q & ((1 << nf_sh) - 1); q >>= nf_sh;
    int pl = q & 1; q >>= 1;
    int icc = q & 1; int tap = q >> 1;
    int oc = (f << 4) + (lane & 15);
    int ic = icc * 32 + ((lane >> 4) << 3) + j;
    float w = src[(oc * 64 + ic) * 25 + tap];
    if (pl == 0) dst[i] = f2h(w);
    else         dst[i] = f2h((w - h2f(f2h(w))) * 4096.f);
}
__launch_bounds__(256)
__global__ void prep_wdec_k(const float* __restrict__ src, u16* __restrict__ dst, int icc_sh) {
    int i = blockIdx.x * 256 + threadIdx.x;
    int j = i & 7, lane = (i >> 3) & 63;
    int f = (i >> 9) & 3;
    int q = i >> 11;
    int icc = q & ((1 << icc_sh) - 1); int tap = q >> icc_sh;
    int oc = (f << 4) + (lane & 15);
    int ic = icc * 32 + ((lane >> 4) << 3) + j;
    dst[i] = f2h(src[(ic * 64 + oc) * 16 + tap]);
}
__launch_bounds__(256)
__global__ void prep_cb_k(const float* __restrict__ cb, u16* __restrict__ dst) {
    int i = blockIdx.x * 256 + threadIdx.x;   // 524288
    int j = i & 7, lane = (i >> 3) & 63;
    int f = (i >> 9) & 63;
    int q = i >> 15;
    int pl = q & 1; int ks = q >> 1;
    int n = (f << 4) + (lane & 15);
    int k = ks * 32 + ((lane >> 4) << 3) + j;
    float w = cb[n * 256 + k];
    if (pl == 0) dst[i] = f2h(w);
    else         dst[i] = f2h((w - h2f(f2h(w))) * 4096.f);
}
__launch_bounds__(256)
__global__ void prep_cbn_k(const float* __restrict__ cb, float* __restrict__ cbn) {
    int row = blockIdx.x * 256 + threadIdx.x;          // 1024
    float s = 0.f;
    for (int c = 0; c < 256; c += 4) {
        f32x4 v = *(const f32x4*)&cb[row * 256 + c];
        s = fmaf(v.x, v.x, s); s = fmaf(v.y, v.y, s);
        s = fmaf(v.z, v.z, s); s = fmaf(v.w, v.w, s);
    }
    cbn[row] = s;
}

// ============================ conv1: 1->64, 5x5 s2 p2, relu, split-fp16 out ============================
__launch_bounds__(256)
__global__ void conv1_k(const float* __restrict__ x, const float* __restrict__ w,
                        const float* __restrict__ b, u16* __restrict__ oh, u16* __restrict__ ol) {
    __shared__ float wl[25 * 64];
    __shared__ float bl[64];
    int t = threadIdx.x;
    for (int i = t; i < 1600; i += 256) wl[(i % 25) * 64 + i / 25] = w[i];
    if (t < 64) bl[t] = b[t];
    __syncthreads();
    int p = blockIdx.x * 256 + t;                       // 262144 pixels
    int ox = p & 63, oy = (p >> 6) & 63, n = p >> 12;
    f32x4 acc[16];
    #pragma unroll
    for (int c = 0; c < 16; ++c) acc[c] = *(f32x4*)&bl[c * 4];
    for (int dy = 0; dy < 5; ++dy) {
        int iy = 2 * oy - 2 + dy;
        if ((unsigned)iy >= 128u) continue;
        for (int dx = 0; dx < 5; ++dx) {
            int ix = 2 * ox - 2 + dx;
            if ((unsigned)ix >= 128u) continue;
            float v = x[(n * 128 + iy) * 128 + ix];
            const float* wp = &wl[(dy * 5 + dx) * 64];
            #pragma unroll
            for (int c = 0; c < 16; ++c) {
                f32x4 w4 = *(const f32x4*)&wp[c * 4];
                acc[c].x = fmaf(v, w4.x, acc[c].x); acc[c].y = fmaf(v, w4.y, acc[c].y);
                acc[c].z = fmaf(v, w4.z, acc[c].z); acc[c].w = fmaf(v, w4.w, acc[c].w);
            }
        }
    }
    #pragma unroll
    for (int c = 0; c < 16; ++c) {
        ushort4 uh, ul;
        float vv[4] = {acc[c].x, acc[c].y, acc[c].z, acc[c].w};
        u16 rh[4], rl[4];
        #pragma unroll
        for (int k = 0; k < 4; ++k) {
            float v = fmaxf(vv[k], 0.f);
            f16 hh = (f16)v;
            rh[k] = __builtin_bit_cast(u16, hh);
            rl[k] = f2h((v - (float)hh) * 4096.f);
        }
        uh.x = rh[0]; uh.y = rh[1]; uh.z = rh[2]; uh.w = rh[3];
        ul.x = rl[0]; ul.y = rl[1]; ul.z = rl[2]; ul.w = rl[3];
        *(ushort4*)&oh[p * 64 + c * 4] = uh;
        *(ushort4*)&ol[p * 64 + c * 4] = ul;
    }
}

// ============================ split-fp16 MFMA 5x5 conv: mi=4, waves partition oc ============================
// 8x8 pixel tile (64 pix = all 4 A-fragments per wave), wave owns NI*16 oc.
// B bytes/MFMA set by mi (=4); acc = 32*NI regs -> 3 waves/SIMD at NI<=2.
// LDS: pixel pair P=pp>>1 owns a 64-half line; chunk c of parity r at slot (P+2c+r)&7.
template<int S, int OCT, int NI, bool RELU>
__launch_bounds__(256)
__global__ void conv5_k(const u16* __restrict__ Ah_g, const u16* __restrict__ Al_g,
                        const u16* __restrict__ wBf, const float* __restrict__ bias,
                        u16* __restrict__ Oh, u16* __restrict__ Ol,
                        int IH, int IW, int OH, int OW) {
    constexpr int PATCH = 7 * S + 5;
    constexpr int NPIX = PATCH * PATCH;
    constexpr int NPAIR = (NPIX + 1) / 2;
    constexpr int PLSZ = NPAIR * 64;
    constexpr int NF = OCT / 16;
    constexpr int OCB = OCT / (NI * 64);          // blocks per tile along oc
    __shared__ u16 patch[2 * PLSZ];

    int t = threadIdx.x, l = t & 63, wv = t >> 6, g = l >> 4;

    int bi = blockIdx.x;
    int wlin = (bi & 7) * ((int)gridDim.x >> 3) + (bi >> 3);   // XCD slab
    int ocb = wlin % OCB; int rest = wlin / OCB;
    int tw = OW >> 3, th = OH >> 3;
    int txi = rest % tw; rest /= tw;
    int tyi = rest % th; int n = rest / th;
    int iy0 = S * (tyi << 3) - 2, ix0 = S * (txi << 3) - 2;

    int ppb[4];
    #pragma unroll
    for (int mi = 0; mi < 4; ++mi) {
        int m = mi * 16 + (l & 15);
        ppb[mi] = (S * (m >> 3)) * PATCH + S * (m & 7);
    }

    f32x4 acc0[4][NI], acc1[4][NI];
    f32x4 z4 = {0.f, 0.f, 0.f, 0.f};
    #pragma unroll
    for (int mi = 0; mi < 4; ++mi)
        #pragma unroll
        for (int ni = 0; ni < NI; ++ni) { acc0[mi][ni] = z4; acc1[mi][ni] = z4; }

    int tap0 = bi % 25;
    int dy0 = tap0 / 5, dx0 = tap0 - 5 * dy0;
    int tadd0 = dy0 * PATCH + dx0;
    int iccr = bi & 1;
    int fg = ocb * (4 * NI) + wv * NI;
    const size_t tstride = (size_t)(4 * NF) * 512;

    for (int icci = 0; icci < 2; ++icci) {
        int icc = icci ^ iccr;
        __syncthreads();
        for (int i = t; i < NPIX * 8; i += 256) {
            int c = i & 3; int r2 = i >> 2;
            int pl = (r2 >= NPIX); int pp = r2 - pl * NPIX;
            int py = pp / PATCH, px = pp - py * PATCH;
            int iy = iy0 + py, ix = ix0 + px;
            uint4 v = make_uint4(0u, 0u, 0u, 0u);
            if ((unsigned)iy < (unsigned)IH && (unsigned)ix < (unsigned)IW)
                v = *(const uint4*)&(pl ? Al_g : Ah_g)[(((n * IH + iy) * IW + ix)) * 64 + icc * 32 + c * 8];
            int P = pp >> 1, r = pp & 1;
            *(uint4*)&patch[pl * PLSZ + (P << 6) + (((P + (c << 1) + r) & 7) << 3)] = v;
        }
        __syncthreads();

        const u16* pB = wBf + (size_t)((tap0 * 4 + icc * 2) * NF + fg) * 512 + l * 8;
        int tap = tap0, dx = dx0, tadd = tadd0;
        for (int tapi = 0; tapi < 25; ++tapi) {
            f16x8 Bh[NI], Bl[NI];
            #pragma unroll
            for (int ni = 0; ni < NI; ++ni) {
                Bh[ni] = *(const f16x8*)&pB[ni * 512];
                Bl[ni] = *(const f16x8*)&pB[(NF + ni) * 512];
            }
            f16x8 ah[4], al[4];
            #pragma unroll
            for (int mi = 0; mi < 4; ++mi) {
                int pp = ppb[mi] + tadd;
                int P = pp >> 1, r = pp & 1;
                int offs = (P << 6) + (((P + (g << 1) + r) & 7) << 3);
                ah[mi] = *(const f16x8*)&patch[offs];
                al[mi] = *(const f16x8*)&patch[PLSZ + offs];
            }
            #pragma unroll
            for (int mi = 0; mi < 4; ++mi)
                #pragma unroll
                for (int ni = 0; ni < NI; ++ni) {
                    acc0[mi][ni] = __builtin_amdgcn_mfma_f32_16x16x32_f16(ah[mi], Bh[ni], acc0[mi][ni], 0, 0, 0);
                    acc1[mi][ni] = __builtin_amdgcn_mfma_f32_16x16x32_f16(ah[mi], Bl[ni], acc1[mi][ni], 0, 0, 0);
                    acc1[mi][ni] = __builtin_amdgcn_mfma_f32_16x16x32_f16(al[mi], Bh[ni], acc1[mi][ni], 0, 0, 0);
                }
            pB = (tap == 24) ? (pB - 24 * tstride) : (pB + tstride);
            if (tap == 24) { tap = 0; dx = 0; tadd = 0; }
            else {
                tap++; dx++; tadd++;
                if (dx == 5) { dx = 0; tadd += PATCH - 5; }
            }
        }
    }
    #pragma unroll
    for (int mi = 0; mi < 4; ++mi)
        #pragma unroll
        for (int ni = 0; ni < NI; ++ni) {
            int oc = (fg + ni) * 16 + (l & 15);
            float bv = bias[oc];
            #pragma unroll
            for (int reg = 0; reg < 4; ++reg) {
                float v = acc0[mi][ni][reg] + acc1[mi][ni][reg] * (1.f / 4096.f) + bv;
                if (RELU) v = fmaxf(v, 0.f);
                int pix = mi * 16 + g * 4 + reg;
                int oy = (tyi << 3) + (pix >> 3), ox = (txi << 3) + (pix & 7);
                int idx = ((n * OH + oy) * OW + ox) * OCT + oc;
                f16 hh = (f16)v;
                Oh[idx] = __builtin_bit_cast(u16, hh);
                Ol[idx] = f2h((v - (float)hh) * 4096.f);
            }
        }
}

// ============================ quantize v4: A-in-registers, B via LDS double-buffer ============================
__launch_bounds__(256, 2)
__global__ void quant_k(const u16* __restrict__ zh, const u16* __restrict__ zl,
                        const u16* __restrict__ cbf, const float* __restrict__ cbn,
                        const float* __restrict__ cb, u16* __restrict__ e,
                        float* __restrict__ diff) {
    __shared__ u16 Bbuf[2 * 32 * 512];     // [buf][ks*4+pl*2+nf][lane*8]
    __shared__ float cbn_l[1024];
    __shared__ float zn_l[128];
    __shared__ float bd_l[128];
    __shared__ int   wi_l[128];

    int t = threadIdx.x, l = t & 63, wv = t >> 6, g = l >> 4;
    int bi = blockIdx.x;
    int row0 = bi << 7;

    {
        f32x4 v = *(const f32x4*)&cbn[t * 4];
        *(f32x4*)&cbn_l[t * 4] = v;
    }

    f16x8 Ah[2][8], Al[2][8];
    int rbase = row0 + wv * 32 + (l & 15);
    #pragma unroll
    for (int mi = 0; mi < 2; ++mi)
        #pragma unroll
        for (int ks = 0; ks < 8; ++ks) {
            size_t off = (size_t)(rbase + mi * 16) * 256 + ks * 32 + g * 8;
            Ah[mi][ks] = *(const f16x8*)&zh[off];
            Al[mi][ks] = *(const f16x8*)&zl[off];
        }

    #pragma unroll
    for (int mi = 0; mi < 2; ++mi) {
        float s = 0.f;
        #pragma unroll
        for (int ks = 0; ks < 8; ++ks)
            #pragma unroll
            for (int j = 0; j < 8; ++j) {
                float v = (float)Ah[mi][ks][j] + (float)Al[mi][ks][j] * (1.f / 4096.f);
                s = fmaf(v, v, s);
            }
        s += __shfl_xor(s, 16);
        s += __shfl_xor(s, 32);
        if (g == 0) zn_l[wv * 32 + mi * 16 + (l & 15)] = s;
    }

    float rd[8]; int rc[8];
    #pragma unroll
    for (int s = 0; s < 8; ++s) { rd[s] = 1e30f; rc[s] = 0; }

    int fi = wv * 8;
    {
        int no0 = bi & 31;
        #pragma unroll
        for (int q = 0; q < 8; ++q) {
            int f2 = fi + q;
            int ks = f2 >> 2, pl = (f2 >> 1) & 1, nf = f2 & 1;
            f16x8 v = *(const f16x8*)&cbf[(size_t)(((ks * 2 + pl) * 64) + no0 * 2 + nf) * 512 + l * 8];
            *(uint4*)&Bbuf[(size_t)f2 * 512 + l * 8] = __builtin_bit_cast(uint4, v);
        }
    }
    __syncthreads();

    for (int noi = 0; noi < 32; ++noi) {
        int b = noi & 1;
        int no_cur = (noi + bi) & 31;

        f16x8 pf[8];
        if (noi < 31) {
            int no_n = (noi + 1 + bi) & 31;
            #pragma unroll
            for (int q = 0; q < 8; ++q) {
                int f2 = fi + q;
                int ks = f2 >> 2, pl = (f2 >> 1) & 1, nf = f2 & 1;
                pf[q] = *(const f16x8*)&cbf[(size_t)(((ks * 2 + pl) * 64) + no_n * 2 + nf) * 512 + l * 8];
            }
        }

        f32x4 acc0[2][2], acc1[2][2];
        f32x4 z4 = {0.f, 0.f, 0.f, 0.f};
        #pragma unroll
        for (int mi = 0; mi < 2; ++mi)
            #pragma unroll
            for (int nf = 0; nf < 2; ++nf) { acc0[mi][nf] = z4; acc1[mi][nf] = z4; }

        #pragma unroll
        for (int ks = 0; ks < 8; ++ks) {
            const u16* bb = &Bbuf[(size_t)(b * 32 + ks * 4) * 512 + l * 8];
            f16x8 Bh0 = *(const f16x8*)&bb[0 * 512];
            f16x8 Bh1 = *(const f16x8*)&bb[1 * 512];
            f16x8 Bl0 = *(const f16x8*)&bb[2 * 512];
            f16x8 Bl1 = *(const f16x8*)&bb[3 * 512];
            #pragma unroll
            for (int mi = 0; mi < 2; ++mi) {
                acc0[mi][0] = __builtin_amdgcn_mfma_f32_16x16x32_f16(Ah[mi][ks], Bh0, acc0[mi][0], 0, 0, 0);
                acc0[mi][1] = __builtin_amdgcn_mfma_f32_16x16x32_f16(Ah[mi][ks], Bh1, acc0[mi][1], 0, 0, 0);
                acc1[mi][0] = __builtin_amdgcn_mfma_f32_16x16x32_f16(Ah[mi][ks], Bl0, acc1[mi][0], 0, 0, 0);
                acc1[mi][0] = __builtin_amdgcn_mfma_f32_16x16x32_f16(Al[mi][ks], Bh0, acc1[mi][0], 0, 0, 0);
                acc1[mi][1] = __builtin_amdgcn_mfma_f32_16x16x32_f16(Ah[mi][ks], Bl1, acc1[mi][1], 0, 0, 0);
                acc1[mi][1] = __builtin_amdgcn_mfma_f32_16x16x32_f16(Al[mi][ks], Bh1, acc1[mi][1], 0, 0, 0);
            }
        }

        #pragma unroll
        for (int nf = 0; nf < 2; ++nf) {
            int col = no_cur * 32 + nf * 16 + (l & 15);
            float cn = cbn_l[col];
            #pragma unroll
            for (int mi = 0; mi < 2; ++mi)
                #pragma unroll
                for (int reg = 0; reg < 4; ++reg) {
                    float d = cn - 2.f * (acc0[mi][nf][reg] + acc1[mi][nf][reg] * (1.f / 4096.f));
                    int slot = mi * 4 + reg;
                    if (d < rd[slot] || (d == rd[slot] && col < rc[slot])) { rd[slot] = d; rc[slot] = col; }
                }
        }

        if (noi < 31) {
            #pragma unroll
            for (int q = 0; q < 8; ++q)
                *(uint4*)&Bbuf[(size_t)((1 - b) * 32 + fi + q) * 512 + l * 8] = __builtin_bit_cast(uint4, pf[q]);
        }
        __syncthreads();
    }

    #pragma unroll
    for (int step = 1; step < 16; step <<= 1) {
        #pragma unroll
        for (int s = 0; s < 8; ++s) {
            float od = __shfl_xor(rd[s], step);
            int ocl = __shfl_xor(rc[s], step);
            if (od < rd[s] || (od == rd[s] && ocl < rc[s])) { rd[s] = od; rc[s] = ocl; }
        }
    }
    if ((l & 15) == 0) {
        #pragma unroll
        for (int s = 0; s < 8; ++s) {
            int mi = s >> 2, reg = s & 3;
            int row = wv * 32 + mi * 16 + g * 4 + reg;
            bd_l[row] = rd[s]; wi_l[row] = rc[s];
        }
    }
    __syncthreads();
    if (t < 64) {
        float dval = (zn_l[t] + bd_l[t]) + (zn_l[t + 64] + bd_l[t + 64]);
        #pragma unroll
        for (int step = 1; step < 64; step <<= 1) dval += __shfl_xor(dval, step);
        if (t == 0) atomicAdd(diff, dval * (1.f / 16777216.f));
    }
    __syncthreads();
    for (int r = 0; r < 128; ++r) {
        int wi = wi_l[r];
        e[(size_t)(row0 + r) * 256 + t] = f2h(cb[wi * 256 + t]);
    }
}

// ============================ plain-fp16 MFMA deconv k4 s2 p1, B prefetched, XCD swizzle ============================
template<int ICT>
__launch_bounds__(256)
__global__ void deconv4_k(const u16* __restrict__ in, const u16* __restrict__ wdf,
                          const float* __restrict__ bias, u16* __restrict__ out,
                          int IH, int IW) {
    constexpr int RST = 40;
    constexpr int ICC = ICT / 32;
    constexpr int PLSZ = 81 * RST;
    __shared__ u16 patch[PLSZ];

    int t = threadIdx.x, l = t & 63, wv = t >> 6;
    int wm = wv >> 1, wn = wv & 1, g = l >> 4;

    int bi = blockIdx.x;
    int wlin = (bi & 7) * ((int)gridDim.x >> 3) + (bi >> 3);
    int par = wlin & 3; int ry = par >> 1, rx = par & 1;
    int rest = wlin >> 2;
    int tw = IW >> 3, th = IH >> 3;
    int txi = rest % tw; rest /= tw;
    int tyi = rest % th; int n = rest / th;
    int a0 = tyi << 3, b0 = txi << 3;
    int by0 = ry ? 0 : -1, bx0 = rx ? 0 : -1;
    int OH = IH << 1, OW = IW << 1;

    int pb0[2];
    #pragma unroll
    for (int mi = 0; mi < 2; ++mi) {
        int m = wm * 32 + mi * 16 + (l & 15);
        int pa = m >> 3, pb_ = m & 7;
        pb0[mi] = (pa * 9 + pb_) * RST + g * 8;
    }

    f32x4 acc[2][2];
    f32x4 z4 = {0.f, 0.f, 0.f, 0.f};
    #pragma unroll
    for (int mi = 0; mi < 2; ++mi)
        #pragma unroll
        for (int ni = 0; ni < 2; ++ni) acc[mi][ni] = z4;

    auto ldB = [&](int icc, int tt, f16x8* B) {
        int tty = tt >> 1, ttx = tt & 1;
        int ky = 1 - ry + 2 * tty, kx = 1 - rx + 2 * ttx;
        int tap = ky * 4 + kx;
        #pragma unroll
        for (int ni = 0; ni < 2; ++ni)
            B[ni] = *(const f16x8*)&wdf[(size_t)((tap * ICC + icc) * 4 + wn * 2 + ni) * 512 + l * 8];
    };

    f16x8 B0[2], B1[2];
    {
        int icc0 = (bi >> 2) & (ICC - 1);
        ldB(icc0, bi & 3, B0);
    }

    for (int icci = 0; icci < ICC; ++icci) {
        int icc = (icci + (bi >> 2)) & (ICC - 1);
        __syncthreads();
        for (int i = t; i < 324; i += 256) {
            int c = i & 3; int pp = i >> 2;
            int pr = pp / 9, pc = pp - pr * 9;
            int ar = a0 + by0 + pr, ac = b0 + bx0 + pc;
            uint4 v = make_uint4(0u, 0u, 0u, 0u);
            if ((unsigned)ar < (unsigned)IH && (unsigned)ac < (unsigned)IW)
                v = *(const uint4*)&in[((n * IH + ar) * IW + ac) * ICT + icc * 32 + c * 8];
            *(uint4*)&patch[(pr * 9 + pc) * RST + c * 8] = v;
        }
        __syncthreads();
        #pragma unroll
        for (int tti = 0; tti < 4; ++tti) {
            int tt = (tti + bi) & 3;
            if (!(icci == ICC - 1 && tti == 3)) {
                int nicci = (tti == 3) ? icci + 1 : icci;
                int ntti = (tti == 3) ? 0 : tti + 1;
                int nicc = (nicci + (bi >> 2)) & (ICC - 1);
                ldB(nicc, (ntti + bi) & 3, B1);
            }
            int tty = tt >> 1, ttx = tt & 1;
            int shift = ((1 - tty) * 9 + (1 - ttx)) * RST;
            #pragma unroll
            for (int mi = 0; mi < 2; ++mi) {
                f16x8 a = *(const f16x8*)&patch[pb0[mi] + shift];
                #pragma unroll
                for (int ni = 0; ni < 2; ++ni)
                    acc[mi][ni] = __builtin_amdgcn_mfma_f32_16x16x32_f16(a, B0[ni], acc[mi][ni], 0, 0, 0);
            }
            B0[0] = B1[0]; B0[1] = B1[1];
        }
    }
    #pragma unroll
    for (int mi = 0; mi < 2; ++mi)
        #pragma unroll
        for (int ni = 0; ni < 2; ++ni) {
            int oc = wn * 32 + ni * 16 + (l & 15);
            float bv = bias[oc];
            #pragma unroll
            for (int reg = 0; reg < 4; ++reg) {
                float v = fmaxf(acc[mi][ni][reg] + bv, 0.f);
                int pix = wm * 32 + mi * 16 + g * 4 + reg;
                int oy = ((a0 + (pix >> 3)) << 1) + ry;
                int ox = ((b0 + (pix & 7)) << 1) + rx;
                out[((n * OH + oy) * OW + ox) * 64 + oc] = f2h(v);
            }
        }
}

// ============================ final conv 3x3 64->1, p1, tanh (LDS-tiled, v_dot2) ============================
__launch_bounds__(256)
__global__ void conv3x3_tanh_k(const u16* __restrict__ in, const float* __restrict__ w,
                               const float* __restrict__ b, float* __restrict__ out) {
    __shared__ u16 tile[18 * 18 * 72];
    __shared__ u32 wpk[288];   // [tap][icp] half2-packed weights
    int t = threadIdx.x;
    int bi = blockIdx.x;
    int wlin = (bi & 7) * ((int)gridDim.x >> 3) + (bi >> 3);
    int n = wlin >> 6;
    int tile6 = wlin & 63;
    int ty0 = (tile6 >> 3) << 4, tx0 = (tile6 & 7) << 4;

    for (int i = t; i < 288; i += 256) {
        int tap = i >> 5, icp = i & 31;
        h2 p;
        p.x = (f16)w[(2 * icp) * 9 + tap];
        p.y = (f16)w[(2 * icp + 1) * 9 + tap];
        wpk[tap * 32 + icp] = __builtin_bit_cast(u32, p);
    }
    for (int i = t; i < 2592; i += 256) {
        int ch = i & 7, pix = i >> 3;
        int pr = pix / 18, pc = pix - pr * 18;
        int gy = ty0 - 1 + pr, gx = tx0 - 1 + pc;
        uint4 v = make_uint4(0u, 0u, 0u, 0u);
        if ((unsigned)gy < 128u && (unsigned)gx < 128u)
            v = *(const uint4*)&in[(((n << 7) + gy) * 128 + gx) * 64 + ch * 8];
        *(uint4*)&tile[pix * 72 + ch * 8] = v;
    }
    __syncthreads();

    int ty = t >> 4, tx = t & 15;
    float acc = b[0];
    #pragma unroll
    for (int dy = 0; dy < 3; ++dy) {
        #pragma unroll
        for (int dx = 0; dx < 3; ++dx) {
            int base = ((ty + dy) * 18 + (tx + dx)) * 72;
            const u32* wp = &wpk[(dy * 3 + dx) * 32];
            #pragma unroll
            for (int c8 = 0; c8 < 8; ++c8) {
                uint4 v = *(const uint4*)&tile[base + c8 * 8];
                acc = __builtin_amdgcn_fdot2(__builtin_bit_cast(h2, v.x),
                        __builtin_bit_cast(h2, wp[c8 * 4 + 0]), acc, false);
                acc = __builtin_amdgcn_fdot2(__builtin_bit_cast(h2, v.y),
                        __builtin_bit_cast(h2, wp[c8 * 4 + 1]), acc, false);
                acc = __builtin_amdgcn_fdot2(__builtin_bit_cast(h2, v.z),
                        __builtin_bit_cast(h2, wp[c8 * 4 + 2]), acc, false);
                acc = __builtin_amdgcn_fdot2(__builtin_bit_cast(h2, v.w),
                        __builtin_bit_cast(h2, wp[c8 * 4 + 3]), acc, false);
            }
        }
    }
    int oy = ty0 + ty, ox = tx0 + tx;
    out[(n << 14) + (oy << 7) + ox] = tanhf(acc);
}

extern "C" void kernel_launch(void* const* d_in, const int* in_sizes, int n_in,
                              void* d_out, int out_size, void* d_ws, size_t ws_size,
                              hipStream_t stream) {
    (void)in_sizes; (void)n_in; (void)out_size; (void)ws_size;
    const float* x   = (const float*)d_in[0];
    const float* ew1 = (const float*)d_in[1];
    const float* eb1 = (const float*)d_in[2];
    const float* ew2 = (const float*)d_in[3];
    const float* eb2 = (const float*)d_in[4];
    const float* ew3 = (const float*)d_in[5];
    const float* eb3 = (const float*)d_in[6];
    const float* cb  = (const float*)d_in[7];
    const float* dw1 = (const float*)d_in[8];
    const float* db1 = (const float*)d_in[9];
    const float* dw2 = (const float*)d_in[10];
    const float* db2 = (const float*)d_in[11];
    const float* dw3 = (const float*)d_in[12];
    const float* db3 = (const float*)d_in[13];
    float* out = (float*)d_out;

    u16* ws = (u16*)d_ws;
    u16* a1h = ws;             u16* a1l = ws + 16777216;
    u16* zh  = ws;             u16* zl  = ws + 16777216;
    u16* a2h = ws + 33554432;  u16* a2l = ws + 50331648;
    u16* e   = ws + 33554432;
    u16* y1  = ws + 67108864;
    u16* y2  = ws;
    u16* wBf2 = ws + 83886080;          // 204800
    u16* wBf3 = wBf2 + 204800;          // 819200
    u16* wd1f = wBf3 + 819200;          // 262144
    u16* wd2f = wd1f + 262144;          // 65536
    u16* cbf  = wd2f + 65536;           // 524288
    float* cbn = (float*)(cbf + 524288);

    hipMemsetAsync(out + 1048576, 0, 4, stream);  // diff accumulator

    prep_wconv_k<<<800, 256, 0, stream>>>(ew2, wBf2, 2);   // NF=4
    prep_wconv_k<<<3200, 256, 0, stream>>>(ew3, wBf3, 4);  // NF=16
    prep_wdec_k<<<1024, 256, 0, stream>>>(dw1, wd1f, 3);   // ICC=8
    prep_wdec_k<<<256, 256, 0, stream>>>(dw2, wd2f, 1);    // ICC=2
    prep_cb_k<<<2048, 256, 0, stream>>>(cb, cbf);
    prep_cbn_k<<<4, 256, 0, stream>>>(cb, cbn);

    conv1_k<<<1024, 256, 0, stream>>>(x, ew1, eb1, a1h, a1l);
    conv5_k<1, 64, 1, true><<<4096, 256, 0, stream>>>(a1h, a1l, wBf2, eb2, a2h, a2l, 64, 64, 64, 64);
    conv5_k<2, 256, 2, false><<<2048, 256, 0, stream>>>(a2h, a2l, wBf3, eb3, zh, zl, 64, 64, 32, 32);
    quant_k<<<512, 256, 0, stream>>>(zh, zl, cbf, cbn, cb, e, out + 1048576);
    deconv4_k<256><<<4096, 256, 0, stream>>>(e, wd1f, db1, y1, 32, 32);
    deconv4_k<64><<<16384, 256, 0, stream>>>(y1, wd2f, db2, y2, 64, 64);
    conv3x3_tanh_k<<<4096, 256, 0, stream>>>(y2, dw3, db3, out);
}